// Round 1
// baseline (4678.467 us; speedup 1.0000x reference)
//
#include <hip/hip_runtime.h>
#include <math.h>

// Problem constants (match reference)
#define Bb 4
#define Tt 512
#define Ee 1024
#define Hh 16
#define Dd 64
#define Ff 4096
#define Mm (Bb*Tt)   // 2048
static constexpr float EPS = 1e-5f;

// ---------------------------------------------------------------------------
// Generic fp32 GEMM: C[m, n0+j] = sum_k A[m,k] * W(k, n) (+bias) (+relu)
// Tiles: BM=BN=64, BK=16, 256 threads, 4x4 per thread.
// W addressing: Wp = W + blockIdx.x * wcolstride; element (k, nl) = Wp[k*wld + nl]
//   - normal [K,N] row-major:   wcolstride = 64,     wld = N
//   - per-head [H][K][64]:      wcolstride = K*64,   wld = 64
// CONCAT: A element for k >= ka1 comes from A2 at column (k - ka1), same lda.
// ---------------------------------------------------------------------------
template<bool RELU, bool CONCAT>
__global__ __launch_bounds__(256)
void gemm64(const float* __restrict__ A, const float* __restrict__ A2, int ka1,
            int lda,
            const float* __restrict__ W, size_t wcolstride, int wld,
            const float* __restrict__ bias,
            float* __restrict__ C, int ldc, int K)
{
  __shared__ float As[16][68];   // [k][m], padded (68: keeps 16B align, breaks bank stride)
  __shared__ float Ws[16][64];   // [k][n]
  const int tid = threadIdx.x;
  const int n0 = blockIdx.x * 64;
  const int m0 = blockIdx.y * 64;
  const float* Wp = W + (size_t)blockIdx.x * wcolstride;
  const int ty = tid >> 4, tx = tid & 15;
  const int a_m = tid >> 2, a_k4 = (tid & 3) << 2;
  const int w_k = tid >> 4, w_n4 = (tid & 15) << 2;
  float acc[4][4] = {};
  for (int k0 = 0; k0 < K; k0 += 16) {
    float4 av;
    if (CONCAT && k0 >= ka1) {
      av = *(const float4*)&A2[(size_t)(m0 + a_m) * lda + (k0 - ka1) + a_k4];
    } else {
      av = *(const float4*)&A[(size_t)(m0 + a_m) * lda + k0 + a_k4];
    }
    As[a_k4+0][a_m] = av.x;
    As[a_k4+1][a_m] = av.y;
    As[a_k4+2][a_m] = av.z;
    As[a_k4+3][a_m] = av.w;
    *(float4*)&Ws[w_k][w_n4] = *(const float4*)&Wp[(size_t)(k0 + w_k) * wld + w_n4];
    __syncthreads();
#pragma unroll
    for (int kk = 0; kk < 16; ++kk) {
      float4 a = *(const float4*)&As[kk][ty << 2];
      float4 b = *(const float4*)&Ws[kk][tx << 2];
      float avv[4] = {a.x, a.y, a.z, a.w};
      float bvv[4] = {b.x, b.y, b.z, b.w};
#pragma unroll
      for (int i = 0; i < 4; ++i)
#pragma unroll
        for (int j = 0; j < 4; ++j)
          acc[i][j] = fmaf(avv[i], bvv[j], acc[i][j]);
    }
    __syncthreads();
  }
  float bv[4] = {0.f, 0.f, 0.f, 0.f};
  if (bias) {
#pragma unroll
    for (int j = 0; j < 4; ++j) bv[j] = bias[n0 + (tx << 2) + j];
  }
#pragma unroll
  for (int i = 0; i < 4; ++i) {
    float* crow = C + (size_t)(m0 + (ty << 2) + i) * ldc + n0 + (tx << 2);
#pragma unroll
    for (int j = 0; j < 4; ++j) {
      float v = acc[i][j] + bv[j];
      if (RELU) v = fmaxf(v, 0.f);
      crow[j] = v;
    }
  }
}

// ---------------------------------------------------------------------------
// Flash-style causal attention, fp32, D=64, no 1/sqrt(d) scaling (per reference).
// Q,K,V,O layout: [B,T,H,D] == [M,E] rows. Grid: (T/64, B*H). Block: 256.
// ---------------------------------------------------------------------------
__global__ __launch_bounds__(256)
void attn64(const float* __restrict__ Q, const float* __restrict__ Kp,
            const float* __restrict__ V, float* __restrict__ O)
{
  __shared__ float Qs[64][68], Ks[64][68], Vs[64][68], Ps[64][68];
  const int tid = threadIdx.x;
  const int q0 = blockIdx.x * 64;
  const int bh = blockIdx.y;
  const int b = bh >> 4, h = bh & 15;
  const int ty = tid >> 4, tx = tid & 15;
  const size_t base = (size_t)b * Tt * Ee + (size_t)h * Dd;

  // load Q tile [64][64]
#pragma unroll
  for (int rr = 0; rr < 4; ++rr) {
    int row = rr * 16 + (tid >> 4);
    int c4 = (tid & 15) << 2;
    *(float4*)&Qs[row][c4] = *(const float4*)&Q[base + (size_t)(q0 + row) * Ee + c4];
  }
  float m_run[4], l_run[4], oacc[4][4];
#pragma unroll
  for (int i = 0; i < 4; ++i) {
    m_run[i] = -INFINITY; l_run[i] = 0.f;
#pragma unroll
    for (int j = 0; j < 4; ++j) oacc[i][j] = 0.f;
  }
  __syncthreads();

  for (int s0 = 0; s0 <= q0; s0 += 64) {
    // load K,V tiles
#pragma unroll
    for (int rr = 0; rr < 4; ++rr) {
      int row = rr * 16 + (tid >> 4);
      int c4 = (tid & 15) << 2;
      size_t g = base + (size_t)(s0 + row) * Ee + c4;
      *(float4*)&Ks[row][c4] = *(const float4*)&Kp[g];
      *(float4*)&Vs[row][c4] = *(const float4*)&V[g];
    }
    __syncthreads();

    // S = Q K^T  (4x4 per thread: rows ty*4+i, cols tx*4+j)
    float s[4][4] = {};
#pragma unroll
    for (int d4 = 0; d4 < 64; d4 += 4) {
      float4 qv[4], kv[4];
#pragma unroll
      for (int i = 0; i < 4; ++i) qv[i] = *(const float4*)&Qs[(ty << 2) + i][d4];
#pragma unroll
      for (int j = 0; j < 4; ++j) kv[j] = *(const float4*)&Ks[(tx << 2) + j][d4];
#pragma unroll
      for (int i = 0; i < 4; ++i)
#pragma unroll
        for (int j = 0; j < 4; ++j)
          s[i][j] = fmaf(qv[i].x, kv[j].x, fmaf(qv[i].y, kv[j].y,
                    fmaf(qv[i].z, kv[j].z, fmaf(qv[i].w, kv[j].w, s[i][j]))));
    }
    // causal mask (only diagonal tile can clip)
    if (s0 == q0) {
#pragma unroll
      for (int i = 0; i < 4; ++i)
#pragma unroll
        for (int j = 0; j < 4; ++j)
          if (((tx << 2) + j) > ((ty << 2) + i)) s[i][j] = -INFINITY;
    }
    // online softmax update
    float p[4][4];
#pragma unroll
    for (int i = 0; i < 4; ++i) {
      float mt = fmaxf(fmaxf(s[i][0], s[i][1]), fmaxf(s[i][2], s[i][3]));
#pragma unroll
      for (int off = 1; off < 16; off <<= 1) mt = fmaxf(mt, __shfl_xor(mt, off));
      float mn = fmaxf(m_run[i], mt);
      float sc = expf(m_run[i] - mn);
      float rs = 0.f;
#pragma unroll
      for (int j = 0; j < 4; ++j) { p[i][j] = expf(s[i][j] - mn); rs += p[i][j]; }
#pragma unroll
      for (int off = 1; off < 16; off <<= 1) rs += __shfl_xor(rs, off);
      l_run[i] = l_run[i] * sc + rs;
      m_run[i] = mn;
#pragma unroll
      for (int j = 0; j < 4; ++j) oacc[i][j] *= sc;
    }
#pragma unroll
    for (int i = 0; i < 4; ++i)
      *(float4*)&Ps[(ty << 2) + i][tx << 2] = make_float4(p[i][0], p[i][1], p[i][2], p[i][3]);
    __syncthreads();

    // O += P V   (rows ty*4+i, cols tx*4+j over d)
#pragma unroll
    for (int s4 = 0; s4 < 64; s4 += 4) {
      float4 pv[4], vv[4];
#pragma unroll
      for (int i = 0; i < 4; ++i) pv[i] = *(const float4*)&Ps[(ty << 2) + i][s4];
#pragma unroll
      for (int u = 0; u < 4; ++u) vv[u] = *(const float4*)&Vs[s4 + u][tx << 2];
#pragma unroll
      for (int i = 0; i < 4; ++i) {
        oacc[i][0] = fmaf(pv[i].x, vv[0].x, fmaf(pv[i].y, vv[1].x, fmaf(pv[i].z, vv[2].x, fmaf(pv[i].w, vv[3].x, oacc[i][0]))));
        oacc[i][1] = fmaf(pv[i].x, vv[0].y, fmaf(pv[i].y, vv[1].y, fmaf(pv[i].z, vv[2].y, fmaf(pv[i].w, vv[3].y, oacc[i][1]))));
        oacc[i][2] = fmaf(pv[i].x, vv[0].z, fmaf(pv[i].y, vv[1].z, fmaf(pv[i].z, vv[2].z, fmaf(pv[i].w, vv[3].z, oacc[i][2]))));
        oacc[i][3] = fmaf(pv[i].x, vv[0].w, fmaf(pv[i].y, vv[1].w, fmaf(pv[i].z, vv[2].w, fmaf(pv[i].w, vv[3].w, oacc[i][3]))));
      }
    }
    __syncthreads();
  }
  // epilogue: normalize and store
#pragma unroll
  for (int i = 0; i < 4; ++i) {
    float inv = 1.f / l_run[i];
    float4 o4 = make_float4(oacc[i][0] * inv, oacc[i][1] * inv,
                            oacc[i][2] * inv, oacc[i][3] * inv);
    *(float4*)&O[base + (size_t)(q0 + (ty << 2) + i) * Ee + (tx << 2)] = o4;
  }
}

// ---------------------------------------------------------------------------
// Per-head LayerNorm over D=64 + residual: Yout = Yin + LN(O)*g + b
// One wave per (row m, head h). Block 256 = 4 waves. Grid: M*H/4.
// ---------------------------------------------------------------------------
__global__ __launch_bounds__(256)
void attn_ln_res(const float* __restrict__ O, const float* __restrict__ Yin,
                 const float* __restrict__ g, const float* __restrict__ bta,
                 float* __restrict__ Yout)
{
  const int tid = threadIdx.x;
  const int w = (blockIdx.x << 2) + (tid >> 6);
  const int lane = tid & 63;
  const int m = w >> 4;
  const int h = w & 15;
  const size_t idx = (size_t)m * Ee + h * Dd + lane;
  float x = O[idx];
  float s = x, s2 = x * x;
#pragma unroll
  for (int off = 1; off < 64; off <<= 1) {
    s  += __shfl_xor(s, off);
    s2 += __shfl_xor(s2, off);
  }
  float mean = s * (1.f / 64.f);
  float var  = s2 * (1.f / 64.f) - mean * mean;
  float inv  = rsqrtf(var + EPS);
  Yout[idx] = Yin[idx] + (x - mean) * inv * g[h * Dd + lane] + bta[h * Dd + lane];
}

// ---------------------------------------------------------------------------
// Row LayerNorm over E=1024 + residual: Yout = Yin + LN(Tm)*g + bb
// One block (256 thr) per row; 4 floats/thread.
// ---------------------------------------------------------------------------
__global__ __launch_bounds__(256)
void ff_ln_res(const float* __restrict__ Tm, const float* __restrict__ Yin,
               const float* __restrict__ g, const float* __restrict__ bb,
               float* __restrict__ Yout)
{
  __shared__ float red[8];
  const int m = blockIdx.x;
  const int tid = threadIdx.x;
  const size_t basep = (size_t)m * Ee;
  float4 x = *(const float4*)&Tm[basep + (tid << 2)];
  float s  = x.x + x.y + x.z + x.w;
  float s2 = x.x * x.x + x.y * x.y + x.z * x.z + x.w * x.w;
#pragma unroll
  for (int off = 1; off < 64; off <<= 1) {
    s  += __shfl_xor(s, off);
    s2 += __shfl_xor(s2, off);
  }
  const int wid = tid >> 6;
  if ((tid & 63) == 0) { red[wid] = s; red[4 + wid] = s2; }
  __syncthreads();
  s  = red[0] + red[1] + red[2] + red[3];
  s2 = red[4] + red[5] + red[6] + red[7];
  float mean = s * (1.f / Ee);
  float var  = s2 * (1.f / Ee) - mean * mean;
  float inv  = rsqrtf(var + EPS);
  float4 y  = *(const float4*)&Yin[basep + (tid << 2)];
  float4 gg = *(const float4*)&g[tid << 2];
  float4 bv = *(const float4*)&bb[tid << 2];
  float4 o;
  o.x = y.x + (x.x - mean) * inv * gg.x + bv.x;
  o.y = y.y + (x.y - mean) * inv * gg.y + bv.y;
  o.z = y.z + (x.z - mean) * inv * gg.z + bv.z;
  o.w = y.w + (x.w - mean) * inv * gg.w + bv.w;
  *(float4*)&Yout[basep + (tid << 2)] = o;
}

// ---------------------------------------------------------------------------
extern "C" void kernel_launch(void* const* d_in, const int* in_sizes, int n_in,
                              void* d_out, int out_size, void* d_ws, size_t ws_size,
                              hipStream_t stream)
{
  const float* x     = (const float*)d_in[0];
  const float* mh_wq = (const float*)d_in[1];
  const float* mh_wk = (const float*)d_in[2];
  const float* mh_wv = (const float*)d_in[3];
  const float* mh_g  = (const float*)d_in[4];
  const float* mh_b  = (const float*)d_in[5];
  const float* ff_w1 = (const float*)d_in[6];
  const float* ff_b1 = (const float*)d_in[7];
  const float* ff_w2 = (const float*)d_in[8];
  const float* ff_b2 = (const float*)d_in[9];
  const float* ff_g  = (const float*)d_in[10];
  const float* ff_bb = (const float*)d_in[11];
  const float* lt_w  = (const float*)d_in[12];
  const float* lt_b  = (const float*)d_in[13];
  float* out = (float*)d_out;
  float* ws  = (float*)d_ws;

  const size_t ME = (size_t)Mm * Ee;
  float* bufA = ws;               // out_one stream  [M,E]
  float* bufB = bufA + ME;        // out_two stream  [M,E]
  float* qb   = bufB + ME;        // Q [B,T,H,D]=[M,E]
  float* kb   = qb + ME;
  float* vb   = kb + ME;
  float* ob   = vb + ME;          // attention output
  float* hid  = ob + ME;          // FF hidden [M,F]
  float* tmp  = hid + (size_t)Mm * Ff;  // FF out pre-LN [M,E]

  auto proj = [&](const float* src, const float* w, float* dst) {
    // per-head GEMM: grid.x = H (16), W stride per head = E*D, wld = D
    gemm64<false, false><<<dim3(Hh, Mm / 64), 256, 0, stream>>>(
        src, nullptr, 0, Ee, w, (size_t)Ee * Dd, Dd, nullptr, dst, Ee, Ee);
  };
  auto mh = [&](int i, const float* src, float* dst) {
    const size_t wo = (size_t)i * Hh * Ee * Dd;
    proj(src, mh_wq + wo, qb);
    proj(src, mh_wk + wo, kb);
    proj(src, mh_wv + wo, vb);
    attn64<<<dim3(Tt / 64, Bb * Hh), 256, 0, stream>>>(qb, kb, vb, ob);
    attn_ln_res<<<dim3(Mm * Hh / 4), 256, 0, stream>>>(
        ob, src, mh_g + (size_t)i * Hh * Dd, mh_b + (size_t)i * Hh * Dd, dst);
  };
  auto ff = [&](int i, const float* src, float* dst) {
    gemm64<true, false><<<dim3(Ff / 64, Mm / 64), 256, 0, stream>>>(
        src, nullptr, 0, Ee, ff_w1 + (size_t)i * Ee * Ff, 64, Ff,
        ff_b1 + (size_t)i * Ff, hid, Ff, Ee);
    gemm64<false, false><<<dim3(Ee / 64, Mm / 64), 256, 0, stream>>>(
        hid, nullptr, 0, Ff, ff_w2 + (size_t)i * Ff * Ee, 64, Ee,
        ff_b2 + (size_t)i * Ee, tmp, Ee, Ff);
    ff_ln_res<<<dim3(Mm), 256, 0, stream>>>(
        tmp, src, ff_g + (size_t)i * Ee, ff_bb + (size_t)i * Ee, dst);
  };

  // out_one branch: decoder(mh(0, x)) = ff(3, mh(4, mh(0, x)))
  mh(0, x, bufA);
  mh(4, bufA, bufA);
  ff(3, bufA, bufA);

  // out_two branch: 3 encoder blocks then decoder
  mh(1, x, bufB);
  ff(0, bufB, bufB);
  mh(2, bufB, bufB);
  ff(1, bufB, bufB);
  mh(3, bufB, bufB);
  ff(2, bufB, bufB);
  mh(4, bufB, bufB);
  ff(3, bufB, bufB);

  // final: out = concat(bufA, bufB) @ lt_w + lt_b
  gemm64<false, true><<<dim3(Ee / 64, Mm / 64), 256, 0, stream>>>(
      bufA, bufB, Ee, Ee, lt_w, 64, Ee, lt_b, out, Ee, 2 * Ee);
}

// Round 4
// 2698.535 us; speedup vs baseline: 1.7337x; 1.7337x over previous
//
#include <hip/hip_runtime.h>
#include <math.h>

#define Bb 4
#define Tt 512
#define Ee 1024
#define Hh 16
#define Dd 64
#define Ff 4096
#define Mm (Bb*Tt)   // 2048
static constexpr float EPS = 1e-5f;

typedef __attribute__((ext_vector_type(8))) short short8;   // 8 bf16 (4 VGPR)
typedef __attribute__((ext_vector_type(4))) float f32x4;
typedef unsigned short u16;

__device__ __forceinline__ u16 f2bf(float f) {
  unsigned u = __builtin_bit_cast(unsigned, f);
  return (u16)((u + 0x7fffu + ((u >> 16) & 1u)) >> 16);   // RNE
}
__device__ __forceinline__ float bf2f(u16 h) {
  unsigned u = (unsigned)h << 16;
  return __builtin_bit_cast(float, u);
}

// ---------------------------------------------------------------------------
// Split-bf16 MFMA GEMM: C[M,N] = A[M,K] * W[N,K]^T (+bias)(+relu), fp32 in/out.
// A fp32, split in-register to (hi,lo) bf16 during LDS staging.
// W pre-split to bf16 hi/lo [N][K] by cvtT_split.
// acc += Ah*Bh + Ah*Bl + Al*Bh  (3 MFMA passes -> ~2^-16 product rel error).
// BM x 128 tile, BK=32, 256 thr = 4 waves (2x2), wave tile (BM/2)x64.
// ---------------------------------------------------------------------------
template<int BM, bool CONCAT, bool RELU>
__global__ __launch_bounds__(256)
void gemm_split(const float* __restrict__ A, const float* __restrict__ A2,
                const u16* __restrict__ Wh, const u16* __restrict__ Wl,
                const float* __restrict__ bias,
                float* __restrict__ C, int ldc, int K)
{
  constexpr int MF = BM / 32;   // m-frags per wave
  __shared__ u16 Ah[BM][40], Al[BM][40];
  __shared__ u16 Bh[128][40], Bl[128][40];
  const int tid = threadIdx.x;
  const int lane = tid & 63;
  const int w = tid >> 6;
  const int wr = w >> 1, wc = w & 1;
  const int lhi = lane >> 4, llo = lane & 15;
  const int n0 = blockIdx.x * 128;
  const int m0 = blockIdx.y * BM;

  f32x4 acc[MF][4] = {};

  for (int k0 = 0; k0 < K; k0 += 32) {
    // stage A: fp32 -> hi/lo bf16
#pragma unroll
    for (int i = 0; i < (BM * 4) / 256; ++i) {
      int c = tid + 256 * i;
      int row = c >> 2, ko = (c & 3) * 8;
      int gk = k0 + ko;
      const float* src;
      if (CONCAT) {
        src = (gk < Ee) ? &A[(size_t)(m0 + row) * Ee + gk]
                        : &A2[(size_t)(m0 + row) * Ee + (gk - Ee)];
      } else {
        src = &A[(size_t)(m0 + row) * K + gk];
      }
      float4 v0 = *(const float4*)src;
      float4 v1 = *(const float4*)(src + 4);
      float f[8] = {v0.x, v0.y, v0.z, v0.w, v1.x, v1.y, v1.z, v1.w};
      short8 hi, lo;
#pragma unroll
      for (int j = 0; j < 8; ++j) {
        u16 h = f2bf(f[j]);
        hi[j] = (short)h;
        lo[j] = (short)f2bf(f[j] - bf2f(h));
      }
      *(short8*)&Ah[row][ko] = hi;
      *(short8*)&Al[row][ko] = lo;
    }
    // stage B: pre-split bf16 hi/lo
#pragma unroll
    for (int i = 0; i < 2; ++i) {
      int c = tid + 256 * i;
      int row = c >> 2, ko = (c & 3) * 8;
      size_t g = (size_t)(n0 + row) * K + k0 + ko;
      *(short8*)&Bh[row][ko] = *(const short8*)&Wh[g];
      *(short8*)&Bl[row][ko] = *(const short8*)&Wl[g];
    }
    __syncthreads();
    short8 ah[MF], al[MF], bh[4], bl[4];
#pragma unroll
    for (int m = 0; m < MF; ++m) {
      ah[m] = *(const short8*)&Ah[wr * (BM / 2) + m * 16 + llo][lhi * 8];
      al[m] = *(const short8*)&Al[wr * (BM / 2) + m * 16 + llo][lhi * 8];
    }
#pragma unroll
    for (int n = 0; n < 4; ++n) {
      bh[n] = *(const short8*)&Bh[wc * 64 + n * 16 + llo][lhi * 8];
      bl[n] = *(const short8*)&Bl[wc * 64 + n * 16 + llo][lhi * 8];
    }
#pragma unroll
    for (int m = 0; m < MF; ++m)
#pragma unroll
      for (int n = 0; n < 4; ++n) {
        acc[m][n] = __builtin_amdgcn_mfma_f32_16x16x32_bf16(ah[m], bh[n], acc[m][n], 0, 0, 0);
        acc[m][n] = __builtin_amdgcn_mfma_f32_16x16x32_bf16(ah[m], bl[n], acc[m][n], 0, 0, 0);
        acc[m][n] = __builtin_amdgcn_mfma_f32_16x16x32_bf16(al[m], bh[n], acc[m][n], 0, 0, 0);
      }
    __syncthreads();
  }

#pragma unroll
  for (int n = 0; n < 4; ++n) {
    const int col = n0 + wc * 64 + n * 16 + llo;
    const float bv = bias ? bias[col] : 0.f;
#pragma unroll
    for (int m = 0; m < MF; ++m) {
      const int rbase = m0 + wr * (BM / 2) + m * 16 + lhi * 4;
#pragma unroll
      for (int j = 0; j < 4; ++j) {
        float v = acc[m][n][j] + bv;
        if (RELU) v = fmaxf(v, 0.f);
        C[(size_t)(rbase + j) * ldc + col] = v;
      }
    }
  }
}

// ---------------------------------------------------------------------------
// Flash-style causal attention, fp32, D=64, no 1/sqrt(d) scaling (PROVEN r1).
// Q,K,V,O layout: [B,T,H,D] == [M,E] rows. Grid: (T/64, B*H). Block: 256.
// ---------------------------------------------------------------------------
__global__ __launch_bounds__(256)
void attn64(const float* __restrict__ Q, const float* __restrict__ Kp,
            const float* __restrict__ V, float* __restrict__ O)
{
  __shared__ float Qs[64][68], Ks[64][68], Vs[64][68], Ps[64][68];
  const int tid = threadIdx.x;
  const int q0 = blockIdx.x * 64;
  const int bh = blockIdx.y;
  const int b = bh >> 4, h = bh & 15;
  const int ty = tid >> 4, tx = tid & 15;
  const size_t base = (size_t)b * Tt * Ee + (size_t)h * Dd;

#pragma unroll
  for (int rr = 0; rr < 4; ++rr) {
    int row = rr * 16 + (tid >> 4);
    int c4 = (tid & 15) << 2;
    *(float4*)&Qs[row][c4] = *(const float4*)&Q[base + (size_t)(q0 + row) * Ee + c4];
  }
  float m_run[4], l_run[4], oacc[4][4];
#pragma unroll
  for (int i = 0; i < 4; ++i) {
    m_run[i] = -INFINITY; l_run[i] = 0.f;
#pragma unroll
    for (int j = 0; j < 4; ++j) oacc[i][j] = 0.f;
  }
  __syncthreads();

  for (int s0 = 0; s0 <= q0; s0 += 64) {
#pragma unroll
    for (int rr = 0; rr < 4; ++rr) {
      int row = rr * 16 + (tid >> 4);
      int c4 = (tid & 15) << 2;
      size_t g = base + (size_t)(s0 + row) * Ee + c4;
      *(float4*)&Ks[row][c4] = *(const float4*)&Kp[g];
      *(float4*)&Vs[row][c4] = *(const float4*)&V[g];
    }
    __syncthreads();

    float s[4][4] = {};
#pragma unroll
    for (int d4 = 0; d4 < 64; d4 += 4) {
      float4 qv[4], kv[4];
#pragma unroll
      for (int i = 0; i < 4; ++i) qv[i] = *(const float4*)&Qs[(ty << 2) + i][d4];
#pragma unroll
      for (int j = 0; j < 4; ++j) kv[j] = *(const float4*)&Ks[(tx << 2) + j][d4];
#pragma unroll
      for (int i = 0; i < 4; ++i)
#pragma unroll
        for (int j = 0; j < 4; ++j)
          s[i][j] = fmaf(qv[i].x, kv[j].x, fmaf(qv[i].y, kv[j].y,
                    fmaf(qv[i].z, kv[j].z, fmaf(qv[i].w, kv[j].w, s[i][j]))));
    }
    if (s0 == q0) {
#pragma unroll
      for (int i = 0; i < 4; ++i)
#pragma unroll
        for (int j = 0; j < 4; ++j)
          if (((tx << 2) + j) > ((ty << 2) + i)) s[i][j] = -INFINITY;
    }
    float p[4][4];
#pragma unroll
    for (int i = 0; i < 4; ++i) {
      float mt = fmaxf(fmaxf(s[i][0], s[i][1]), fmaxf(s[i][2], s[i][3]));
#pragma unroll
      for (int off = 1; off < 16; off <<= 1) mt = fmaxf(mt, __shfl_xor(mt, off));
      float mn = fmaxf(m_run[i], mt);
      float sc = expf(m_run[i] - mn);
      float rs = 0.f;
#pragma unroll
      for (int j = 0; j < 4; ++j) { p[i][j] = expf(s[i][j] - mn); rs += p[i][j]; }
#pragma unroll
      for (int off = 1; off < 16; off <<= 1) rs += __shfl_xor(rs, off);
      l_run[i] = l_run[i] * sc + rs;
      m_run[i] = mn;
#pragma unroll
      for (int j = 0; j < 4; ++j) oacc[i][j] *= sc;
    }
#pragma unroll
    for (int i = 0; i < 4; ++i)
      *(float4*)&Ps[(ty << 2) + i][tx << 2] = make_float4(p[i][0], p[i][1], p[i][2], p[i][3]);
    __syncthreads();

#pragma unroll
    for (int s4 = 0; s4 < 64; s4 += 4) {
      float4 pv[4], vv[4];
#pragma unroll
      for (int i = 0; i < 4; ++i) pv[i] = *(const float4*)&Ps[(ty << 2) + i][s4];
#pragma unroll
      for (int u = 0; u < 4; ++u) vv[u] = *(const float4*)&Vs[s4 + u][tx << 2];
#pragma unroll
      for (int i = 0; i < 4; ++i) {
        oacc[i][0] = fmaf(pv[i].x, vv[0].x, fmaf(pv[i].y, vv[1].x, fmaf(pv[i].z, vv[2].x, fmaf(pv[i].w, vv[3].x, oacc[i][0]))));
        oacc[i][1] = fmaf(pv[i].x, vv[0].y, fmaf(pv[i].y, vv[1].y, fmaf(pv[i].z, vv[2].y, fmaf(pv[i].w, vv[3].y, oacc[i][1]))));
        oacc[i][2] = fmaf(pv[i].x, vv[0].z, fmaf(pv[i].y, vv[1].z, fmaf(pv[i].z, vv[2].z, fmaf(pv[i].w, vv[3].z, oacc[i][2]))));
        oacc[i][3] = fmaf(pv[i].x, vv[0].w, fmaf(pv[i].y, vv[1].w, fmaf(pv[i].z, vv[2].w, fmaf(pv[i].w, vv[3].w, oacc[i][3]))));
      }
    }
    __syncthreads();
  }
#pragma unroll
  for (int i = 0; i < 4; ++i) {
    float inv = 1.f / l_run[i];
    float4 o4 = make_float4(oacc[i][0] * inv, oacc[i][1] * inv,
                            oacc[i][2] * inv, oacc[i][3] * inv);
    *(float4*)&O[base + (size_t)(q0 + (ty << 2) + i) * Ee + (tx << 2)] = o4;
  }
}

// ---------------------------------------------------------------------------
// Per-head LayerNorm over D=64 + residual (PROVEN r1): Yout = Yin + LN(O)*g + b
// ---------------------------------------------------------------------------
__global__ __launch_bounds__(256)
void attn_ln_res(const float* __restrict__ O, const float* __restrict__ Yin,
                 const float* __restrict__ g, const float* __restrict__ bta,
                 float* __restrict__ Yout)
{
  const int tid = threadIdx.x;
  const int w = (blockIdx.x << 2) + (tid >> 6);
  const int lane = tid & 63;
  const int m = w >> 4;
  const int h = w & 15;
  const size_t idx = (size_t)m * Ee + h * Dd + lane;
  float x = O[idx];
  float s = x, s2 = x * x;
#pragma unroll
  for (int off = 1; off < 64; off <<= 1) {
    s  += __shfl_xor(s, off);
    s2 += __shfl_xor(s2, off);
  }
  float mean = s * (1.f / 64.f);
  float var  = s2 * (1.f / 64.f) - mean * mean;
  float inv  = rsqrtf(var + EPS);
  Yout[idx] = Yin[idx] + (x - mean) * inv * g[h * Dd + lane] + bta[h * Dd + lane];
}

// ---------------------------------------------------------------------------
// Row LayerNorm over E=1024 + residual (PROVEN r1): Yout = Yin + LN(Tm)*g + bb
// ---------------------------------------------------------------------------
__global__ __launch_bounds__(256)
void ff_ln_res(const float* __restrict__ Tm, const float* __restrict__ Yin,
               const float* __restrict__ g, const float* __restrict__ bb,
               float* __restrict__ Yout)
{
  __shared__ float red[8];
  const int m = blockIdx.x;
  const int tid = threadIdx.x;
  const size_t basep = (size_t)m * Ee;
  float4 x = *(const float4*)&Tm[basep + (tid << 2)];
  float s  = x.x + x.y + x.z + x.w;
  float s2 = x.x * x.x + x.y * x.y + x.z * x.z + x.w * x.w;
#pragma unroll
  for (int off = 1; off < 64; off <<= 1) {
    s  += __shfl_xor(s, off);
    s2 += __shfl_xor(s2, off);
  }
  const int wid = tid >> 6;
  if ((tid & 63) == 0) { red[wid] = s; red[4 + wid] = s2; }
  __syncthreads();
  s  = red[0] + red[1] + red[2] + red[3];
  s2 = red[4] + red[5] + red[6] + red[7];
  float mean = s * (1.f / Ee);
  float var  = s2 * (1.f / Ee) - mean * mean;
  float inv  = rsqrtf(var + EPS);
  float4 y  = *(const float4*)&Yin[basep + (tid << 2)];
  float4 gg = *(const float4*)&g[tid << 2];
  float4 bv = *(const float4*)&bb[tid << 2];
  float4 o;
  o.x = y.x + (x.x - mean) * inv * gg.x + bv.x;
  o.y = y.y + (x.y - mean) * inv * gg.y + bv.y;
  o.z = y.z + (x.z - mean) * inv * gg.z + bv.z;
  o.w = y.w + (x.w - mean) * inv * gg.w + bv.w;
  *(float4*)&Yout[basep + (tid << 2)] = o;
}

// ---------------------------------------------------------------------------
// fp32 [R][C] -> bf16 hi/lo [C][R] transpose-split. 32x32 LDS tiles;
// blockIdx.z indexes independent matrices (per-head weights).
// ---------------------------------------------------------------------------
__global__ __launch_bounds__(256)
void cvtT_split(const float* __restrict__ in, u16* __restrict__ out_h,
                u16* __restrict__ out_l, int R, int C)
{
  __shared__ float tile[32][33];
  const size_t zo = (size_t)blockIdx.z * R * C;
  const int c0 = blockIdx.x * 32, r0 = blockIdx.y * 32;
  const int tid = threadIdx.x;
  const int ir = tid >> 3, ic = (tid & 7) * 4;
  float4 v = *(const float4*)&in[zo + (size_t)(r0 + ir) * C + c0 + ic];
  tile[ir][ic] = v.x; tile[ir][ic + 1] = v.y;
  tile[ir][ic + 2] = v.z; tile[ir][ic + 3] = v.w;
  __syncthreads();
  const int oc = tid >> 3, orr = (tid & 7) * 4;
  const size_t ob = zo + (size_t)(c0 + oc) * R + r0 + orr;
#pragma unroll
  for (int j = 0; j < 4; ++j) {
    float f = tile[orr + j][oc];
    u16 h = f2bf(f);
    out_h[ob + j] = h;
    out_l[ob + j] = f2bf(f - bf2f(h));
  }
}

// ---------------------------------------------------------------------------
extern "C" void kernel_launch(void* const* d_in, const int* in_sizes, int n_in,
                              void* d_out, int out_size, void* d_ws, size_t ws_size,
                              hipStream_t stream)
{
  const float* x     = (const float*)d_in[0];
  const float* mh_wq = (const float*)d_in[1];
  const float* mh_wk = (const float*)d_in[2];
  const float* mh_wv = (const float*)d_in[3];
  const float* mh_g  = (const float*)d_in[4];
  const float* mh_b  = (const float*)d_in[5];
  const float* ff_w1 = (const float*)d_in[6];
  const float* ff_b1 = (const float*)d_in[7];
  const float* ff_w2 = (const float*)d_in[8];
  const float* ff_b2 = (const float*)d_in[9];
  const float* ff_g  = (const float*)d_in[10];
  const float* ff_bb = (const float*)d_in[11];
  const float* lt_w  = (const float*)d_in[12];
  const float* lt_b  = (const float*)d_in[13];
  float* out = (float*)d_out;

  const size_t ME = (size_t)Mm * Ee;   // 2M elements
  char* p = (char*)d_ws;
  auto alloc = [&](size_t bytes) { void* r = (void*)p; p += (bytes + 255) & ~(size_t)255; return r; };
  float* bufA = (float*)alloc(ME * 4);                 // 8 MB
  float* bufB = (float*)alloc(ME * 4);                 // 8 MB
  u16* wt_h   = (u16*)alloc((size_t)Ff * Ee * 2);      // 8 MB
  u16* wt_l   = (u16*)alloc((size_t)Ff * Ee * 2);      // 8 MB
  float* reg  = (float*)alloc((size_t)10 * 1024 * 1024 * 4);  // 40 MB union
  float* qb   = reg;                // mh phase
  float* kb   = reg + 2 * 1024 * 1024;
  float* vb   = reg + 4 * 1024 * 1024;
  float* ob   = reg + 6 * 1024 * 1024;
  float* hid  = reg;                // ff phase (aliases qb..ob)
  float* tmp  = reg + 8 * 1024 * 1024;

  auto mh = [&](int i, const float* src, float* dst) {
    const size_t wo = (size_t)i * Hh * Ee * Dd;
    cvtT_split<<<dim3(Dd / 32, Ee / 32, Hh), 256, 0, stream>>>(mh_wq + wo, wt_h, wt_l, Ee, Dd);
    gemm_split<64, false, false><<<dim3(Ee / 128, Mm / 64), 256, 0, stream>>>(
        src, nullptr, wt_h, wt_l, nullptr, qb, Ee, Ee);
    cvtT_split<<<dim3(Dd / 32, Ee / 32, Hh), 256, 0, stream>>>(mh_wk + wo, wt_h, wt_l, Ee, Dd);
    gemm_split<64, false, false><<<dim3(Ee / 128, Mm / 64), 256, 0, stream>>>(
        src, nullptr, wt_h, wt_l, nullptr, kb, Ee, Ee);
    cvtT_split<<<dim3(Dd / 32, Ee / 32, Hh), 256, 0, stream>>>(mh_wv + wo, wt_h, wt_l, Ee, Dd);
    gemm_split<64, false, false><<<dim3(Ee / 128, Mm / 64), 256, 0, stream>>>(
        src, nullptr, wt_h, wt_l, nullptr, vb, Ee, Ee);
    attn64<<<dim3(Tt / 64, Bb * Hh), 256, 0, stream>>>(qb, kb, vb, ob);
    attn_ln_res<<<dim3(Mm * Hh / 4), 256, 0, stream>>>(
        ob, src, mh_g + (size_t)i * Hh * Dd, mh_b + (size_t)i * Hh * Dd, dst);
  };
  auto ff = [&](int i, const float* src, float* dst) {
    cvtT_split<<<dim3(Ff / 32, Ee / 32, 1), 256, 0, stream>>>(ff_w1 + (size_t)i * Ee * Ff, wt_h, wt_l, Ee, Ff);
    gemm_split<128, false, true><<<dim3(Ff / 128, Mm / 128), 256, 0, stream>>>(
        src, nullptr, wt_h, wt_l, ff_b1 + (size_t)i * Ff, hid, Ff, Ee);
    cvtT_split<<<dim3(Ee / 32, Ff / 32, 1), 256, 0, stream>>>(ff_w2 + (size_t)i * Ff * Ee, wt_h, wt_l, Ff, Ee);
    gemm_split<64, false, false><<<dim3(Ee / 128, Mm / 64), 256, 0, stream>>>(
        hid, nullptr, wt_h, wt_l, ff_b2 + (size_t)i * Ee, tmp, Ee, Ff);
    ff_ln_res<<<dim3(Mm), 256, 0, stream>>>(
        tmp, src, ff_g + (size_t)i * Ee, ff_bb + (size_t)i * Ee, dst);
  };

  // out_one branch: ff(3, mh(4, mh(0, x)))
  mh(0, x, bufA);
  mh(4, bufA, bufA);
  ff(3, bufA, bufA);

  // out_two branch: 3 encoder blocks then decoder
  mh(1, x, bufB);
  ff(0, bufB, bufB);
  mh(2, bufB, bufB);
  ff(1, bufB, bufB);
  mh(3, bufB, bufB);
  ff(2, bufB, bufB);
  mh(4, bufB, bufB);
  ff(3, bufB, bufB);

  // final: out = concat(bufA, bufB) @ lt_w + lt_b  (fp32 out)
  cvtT_split<<<dim3(Ee / 32, 2 * Ee / 32, 1), 256, 0, stream>>>(lt_w, wt_h, wt_l, 2 * Ee, Ee);
  gemm_split<64, true, false><<<dim3(Ee / 128, Mm / 64), 256, 0, stream>>>(
      bufA, bufB, wt_h, wt_l, lt_b, out, Ee, 2 * Ee);
}

// Round 5
// 2109.008 us; speedup vs baseline: 2.2183x; 1.2795x over previous
//
#include <hip/hip_runtime.h>
#include <math.h>

#define Bb 4
#define Tt 512
#define Ee 1024
#define Hh 16
#define Dd 64
#define Ff 4096
#define Mm (Bb*Tt)   // 2048
static constexpr float EPS = 1e-5f;

typedef __attribute__((ext_vector_type(8))) short short8;   // 8 bf16 (4 VGPR)
typedef __attribute__((ext_vector_type(4))) float f32x4;
typedef unsigned short u16;

__device__ __forceinline__ u16 f2bf(float f) {
  unsigned u = __builtin_bit_cast(unsigned, f);
  return (u16)((u + 0x7fffu + ((u >> 16) & 1u)) >> 16);   // RNE
}
__device__ __forceinline__ float bf2f(u16 h) {
  unsigned u = (unsigned)h << 16;
  return __builtin_bit_cast(float, u);
}

// ---------------------------------------------------------------------------
// Split-bf16 MFMA GEMM (PROVEN r4): C = A * W^T (+bias)(+relu), fp32 in/out.
// ---------------------------------------------------------------------------
template<int BM, bool CONCAT, bool RELU>
__global__ __launch_bounds__(256)
void gemm_split(const float* __restrict__ A, const float* __restrict__ A2,
                const u16* __restrict__ Wh, const u16* __restrict__ Wl,
                const float* __restrict__ bias,
                float* __restrict__ C, int ldc, int K)
{
  constexpr int MF = BM / 32;   // m-frags per wave
  __shared__ u16 Ah[BM][40], Al[BM][40];
  __shared__ u16 Bh[128][40], Bl[128][40];
  const int tid = threadIdx.x;
  const int lane = tid & 63;
  const int w = tid >> 6;
  const int wr = w >> 1, wc = w & 1;
  const int lhi = lane >> 4, llo = lane & 15;
  const int n0 = blockIdx.x * 128;
  const int m0 = blockIdx.y * BM;

  f32x4 acc[MF][4] = {};

  for (int k0 = 0; k0 < K; k0 += 32) {
#pragma unroll
    for (int i = 0; i < (BM * 4) / 256; ++i) {
      int c = tid + 256 * i;
      int row = c >> 2, ko = (c & 3) * 8;
      int gk = k0 + ko;
      const float* src;
      if (CONCAT) {
        src = (gk < Ee) ? &A[(size_t)(m0 + row) * Ee + gk]
                        : &A2[(size_t)(m0 + row) * Ee + (gk - Ee)];
      } else {
        src = &A[(size_t)(m0 + row) * K + gk];
      }
      float4 v0 = *(const float4*)src;
      float4 v1 = *(const float4*)(src + 4);
      float f[8] = {v0.x, v0.y, v0.z, v0.w, v1.x, v1.y, v1.z, v1.w};
      short8 hi, lo;
#pragma unroll
      for (int j = 0; j < 8; ++j) {
        u16 h = f2bf(f[j]);
        hi[j] = (short)h;
        lo[j] = (short)f2bf(f[j] - bf2f(h));
      }
      *(short8*)&Ah[row][ko] = hi;
      *(short8*)&Al[row][ko] = lo;
    }
#pragma unroll
    for (int i = 0; i < 2; ++i) {
      int c = tid + 256 * i;
      int row = c >> 2, ko = (c & 3) * 8;
      size_t g = (size_t)(n0 + row) * K + k0 + ko;
      *(short8*)&Bh[row][ko] = *(const short8*)&Wh[g];
      *(short8*)&Bl[row][ko] = *(const short8*)&Wl[g];
    }
    __syncthreads();
    short8 ah[MF], al[MF], bh[4], bl[4];
#pragma unroll
    for (int m = 0; m < MF; ++m) {
      ah[m] = *(const short8*)&Ah[wr * (BM / 2) + m * 16 + llo][lhi * 8];
      al[m] = *(const short8*)&Al[wr * (BM / 2) + m * 16 + llo][lhi * 8];
    }
#pragma unroll
    for (int n = 0; n < 4; ++n) {
      bh[n] = *(const short8*)&Bh[wc * 64 + n * 16 + llo][lhi * 8];
      bl[n] = *(const short8*)&Bl[wc * 64 + n * 16 + llo][lhi * 8];
    }
#pragma unroll
    for (int m = 0; m < MF; ++m)
#pragma unroll
      for (int n = 0; n < 4; ++n) {
        acc[m][n] = __builtin_amdgcn_mfma_f32_16x16x32_bf16(ah[m], bh[n], acc[m][n], 0, 0, 0);
        acc[m][n] = __builtin_amdgcn_mfma_f32_16x16x32_bf16(ah[m], bl[n], acc[m][n], 0, 0, 0);
        acc[m][n] = __builtin_amdgcn_mfma_f32_16x16x32_bf16(al[m], bh[n], acc[m][n], 0, 0, 0);
      }
    __syncthreads();
  }

#pragma unroll
  for (int n = 0; n < 4; ++n) {
    const int col = n0 + wc * 64 + n * 16 + llo;
    const float bv = bias ? bias[col] : 0.f;
#pragma unroll
    for (int m = 0; m < MF; ++m) {
      const int rbase = m0 + wr * (BM / 2) + m * 16 + lhi * 4;
#pragma unroll
      for (int j = 0; j < 4; ++j) {
        float v = acc[m][n][j] + bv;
        if (RELU) v = fmaxf(v, 0.f);
        C[(size_t)(rbase + j) * ldc + col] = v;
      }
    }
  }
}

// ---------------------------------------------------------------------------
// Split-bf16 MFMA flash attention, causal, no 1/sqrt(d) scaling.
// Q,K,V,O: fp32 [B,T,H,D]=[M,E]. Grid (T/64, B*H), 256 thr = 4 waves;
// wave w owns q rows [w*16, w*16+16). QK^T and PV via 3-pass hi/lo MFMA.
// V transposed into LDS during staging (b16 scalar writes).
// Fragment mappings identical to gemm_split (proven r4).
// ---------------------------------------------------------------------------
__global__ __launch_bounds__(256)
void attn_ms(const float* __restrict__ Q, const float* __restrict__ Kp,
             const float* __restrict__ V, float* __restrict__ O)
{
  __shared__ u16 Ksh[64][72], Ksl[64][72];   // [s][d]
  __shared__ u16 Vsh[64][72], Vsl[64][72];   // [d][s] (transposed)
  __shared__ u16 Pwh[4][16][72], Pwl[4][16][72];  // per-wave P [q_local][s]
  const int tid = threadIdx.x;
  const int lane = tid & 63, w = tid >> 6;
  const int lhi = lane >> 4, llo = lane & 15;
  const int q0 = blockIdx.x * 64;
  const int bh = blockIdx.y;
  const size_t base = (size_t)(bh >> 4) * Tt * Ee + (size_t)(bh & 15) * Dd;

  // Q fragments (rows w*16+llo), split hi/lo
  short8 qh[2], ql[2];
#pragma unroll
  for (int ks = 0; ks < 2; ++ks) {
    const float* qsrc = &Q[base + (size_t)(q0 + w * 16 + llo) * Ee + ks * 32 + lhi * 8];
    float4 a = *(const float4*)qsrc, b2 = *(const float4*)(qsrc + 4);
    float f[8] = {a.x, a.y, a.z, a.w, b2.x, b2.y, b2.z, b2.w};
#pragma unroll
    for (int j = 0; j < 8; ++j) {
      u16 h = f2bf(f[j]);
      qh[ks][j] = (short)h;
      ql[ks][j] = (short)f2bf(f[j] - bf2f(h));
    }
  }

  f32x4 oacc[4] = {};
  float m_run[4], l_run[4];
#pragma unroll
  for (int j = 0; j < 4; ++j) { m_run[j] = -INFINITY; l_run[j] = 0.f; }

  for (int s0 = 0; s0 <= q0; s0 += 64) {
    // stage K [s][d] and V^T [d][s], split hi/lo
#pragma unroll
    for (int pass = 0; pass < 2; ++pass) {
      int c = tid + 256 * pass;
      int row = c >> 3, d0 = (c & 7) * 8;
      const float* ksrc = &Kp[base + (size_t)(s0 + row) * Ee + d0];
      const float* vsrc = &V[base + (size_t)(s0 + row) * Ee + d0];
      float4 ka = *(const float4*)ksrc, kb2 = *(const float4*)(ksrc + 4);
      float4 va = *(const float4*)vsrc, vb2 = *(const float4*)(vsrc + 4);
      float kf[8] = {ka.x, ka.y, ka.z, ka.w, kb2.x, kb2.y, kb2.z, kb2.w};
      float vf[8] = {va.x, va.y, va.z, va.w, vb2.x, vb2.y, vb2.z, vb2.w};
      short8 khv, klv;
#pragma unroll
      for (int j = 0; j < 8; ++j) {
        u16 h = f2bf(kf[j]);
        khv[j] = (short)h;
        klv[j] = (short)f2bf(kf[j] - bf2f(h));
      }
      *(short8*)&Ksh[row][d0] = khv;
      *(short8*)&Ksl[row][d0] = klv;
#pragma unroll
      for (int j = 0; j < 8; ++j) {
        u16 h = f2bf(vf[j]);
        Vsh[d0 + j][row] = h;
        Vsl[d0 + j][row] = f2bf(vf[j] - bf2f(h));
      }
    }
    __syncthreads();

    // S = Q K^T (3-pass split)
    f32x4 sacc[4] = {};
#pragma unroll
    for (int ks = 0; ks < 2; ++ks)
#pragma unroll
      for (int n = 0; n < 4; ++n) {
        short8 kh = *(const short8*)&Ksh[n * 16 + llo][ks * 32 + lhi * 8];
        short8 kl = *(const short8*)&Ksl[n * 16 + llo][ks * 32 + lhi * 8];
        sacc[n] = __builtin_amdgcn_mfma_f32_16x16x32_bf16(qh[ks], kh, sacc[n], 0, 0, 0);
        sacc[n] = __builtin_amdgcn_mfma_f32_16x16x32_bf16(qh[ks], kl, sacc[n], 0, 0, 0);
        sacc[n] = __builtin_amdgcn_mfma_f32_16x16x32_bf16(ql[ks], kh, sacc[n], 0, 0, 0);
      }

    // causal mask (rows q = w*16+lhi*4+j, cols s = n*16+llo, block-local)
    if (s0 == q0) {
#pragma unroll
      for (int n = 0; n < 4; ++n)
#pragma unroll
        for (int j = 0; j < 4; ++j)
          if (n * 16 + llo > w * 16 + lhi * 4 + j) sacc[n][j] = -INFINITY;
    }

    // online softmax (per q row j; reduction across 16 llo lanes)
    float scj[4];
#pragma unroll
    for (int j = 0; j < 4; ++j) {
      float mt = fmaxf(fmaxf(sacc[0][j], sacc[1][j]), fmaxf(sacc[2][j], sacc[3][j]));
#pragma unroll
      for (int off = 1; off < 16; off <<= 1) mt = fmaxf(mt, __shfl_xor(mt, off));
      float mn = fmaxf(m_run[j], mt);
      scj[j] = __expf(m_run[j] - mn);
      m_run[j] = mn;
      float rs = 0.f;
#pragma unroll
      for (int n = 0; n < 4; ++n) {
        float pp = __expf(sacc[n][j] - mn);
        sacc[n][j] = pp;
        rs += pp;
      }
#pragma unroll
      for (int off = 1; off < 16; off <<= 1) rs += __shfl_xor(rs, off);
      l_run[j] = l_run[j] * scj[j] + rs;
    }

    // write P split to per-wave LDS (no barrier needed: same-wave use)
#pragma unroll
    for (int n = 0; n < 4; ++n)
#pragma unroll
      for (int j = 0; j < 4; ++j) {
        float pp = sacc[n][j];
        u16 h = f2bf(pp);
        Pwh[w][lhi * 4 + j][n * 16 + llo] = h;
        Pwl[w][lhi * 4 + j][n * 16 + llo] = f2bf(pp - bf2f(h));
      }
    // rescale O accumulator
#pragma unroll
    for (int df = 0; df < 4; ++df)
#pragma unroll
      for (int j = 0; j < 4; ++j)
        oacc[df][j] *= scj[j];

    // O += P V (3-pass split)
#pragma unroll
    for (int ks = 0; ks < 2; ++ks) {
      short8 ph = *(const short8*)&Pwh[w][llo][ks * 32 + lhi * 8];
      short8 pl = *(const short8*)&Pwl[w][llo][ks * 32 + lhi * 8];
#pragma unroll
      for (int df = 0; df < 4; ++df) {
        short8 vh = *(const short8*)&Vsh[df * 16 + llo][ks * 32 + lhi * 8];
        short8 vl = *(const short8*)&Vsl[df * 16 + llo][ks * 32 + lhi * 8];
        oacc[df] = __builtin_amdgcn_mfma_f32_16x16x32_bf16(ph, vh, oacc[df], 0, 0, 0);
        oacc[df] = __builtin_amdgcn_mfma_f32_16x16x32_bf16(ph, vl, oacc[df], 0, 0, 0);
        oacc[df] = __builtin_amdgcn_mfma_f32_16x16x32_bf16(pl, vh, oacc[df], 0, 0, 0);
      }
    }
    __syncthreads();
  }

  // epilogue: normalize and store fp32
#pragma unroll
  for (int j = 0; j < 4; ++j) {
    float inv = 1.f / l_run[j];
#pragma unroll
    for (int df = 0; df < 4; ++df)
      O[base + (size_t)(q0 + w * 16 + lhi * 4 + j) * Ee + df * 16 + llo] =
          oacc[df][j] * inv;
  }
}

// ---------------------------------------------------------------------------
// Per-head LayerNorm over D=64 + residual (PROVEN r1/r4).
// ---------------------------------------------------------------------------
__global__ __launch_bounds__(256)
void attn_ln_res(const float* __restrict__ O, const float* __restrict__ Yin,
                 const float* __restrict__ g, const float* __restrict__ bta,
                 float* __restrict__ Yout)
{
  const int tid = threadIdx.x;
  const int w = (blockIdx.x << 2) + (tid >> 6);
  const int lane = tid & 63;
  const int m = w >> 4;
  const int h = w & 15;
  const size_t idx = (size_t)m * Ee + h * Dd + lane;
  float x = O[idx];
  float s = x, s2 = x * x;
#pragma unroll
  for (int off = 1; off < 64; off <<= 1) {
    s  += __shfl_xor(s, off);
    s2 += __shfl_xor(s2, off);
  }
  float mean = s * (1.f / 64.f);
  float var  = s2 * (1.f / 64.f) - mean * mean;
  float inv  = rsqrtf(var + EPS);
  Yout[idx] = Yin[idx] + (x - mean) * inv * g[h * Dd + lane] + bta[h * Dd + lane];
}

// ---------------------------------------------------------------------------
// Row LayerNorm over E=1024 + residual (PROVEN r1/r4).
// ---------------------------------------------------------------------------
__global__ __launch_bounds__(256)
void ff_ln_res(const float* __restrict__ Tm, const float* __restrict__ Yin,
               const float* __restrict__ g, const float* __restrict__ bb,
               float* __restrict__ Yout)
{
  __shared__ float red[8];
  const int m = blockIdx.x;
  const int tid = threadIdx.x;
  const size_t basep = (size_t)m * Ee;
  float4 x = *(const float4*)&Tm[basep + (tid << 2)];
  float s  = x.x + x.y + x.z + x.w;
  float s2 = x.x * x.x + x.y * x.y + x.z * x.z + x.w * x.w;
#pragma unroll
  for (int off = 1; off < 64; off <<= 1) {
    s  += __shfl_xor(s, off);
    s2 += __shfl_xor(s2, off);
  }
  const int wid = tid >> 6;
  if ((tid & 63) == 0) { red[wid] = s; red[4 + wid] = s2; }
  __syncthreads();
  s  = red[0] + red[1] + red[2] + red[3];
  s2 = red[4] + red[5] + red[6] + red[7];
  float mean = s * (1.f / Ee);
  float var  = s2 * (1.f / Ee) - mean * mean;
  float inv  = rsqrtf(var + EPS);
  float4 y  = *(const float4*)&Yin[basep + (tid << 2)];
  float4 gg = *(const float4*)&g[tid << 2];
  float4 bv = *(const float4*)&bb[tid << 2];
  float4 o;
  o.x = y.x + (x.x - mean) * inv * gg.x + bv.x;
  o.y = y.y + (x.y - mean) * inv * gg.y + bv.y;
  o.z = y.z + (x.z - mean) * inv * gg.z + bv.z;
  o.w = y.w + (x.w - mean) * inv * gg.w + bv.w;
  *(float4*)&Yout[basep + (tid << 2)] = o;
}

// ---------------------------------------------------------------------------
// fp32 [R][C] -> bf16 hi/lo [C][R] transpose-split (PROVEN r4).
// ---------------------------------------------------------------------------
__global__ __launch_bounds__(256)
void cvtT_split(const float* __restrict__ in, u16* __restrict__ out_h,
                u16* __restrict__ out_l, int R, int C)
{
  __shared__ float tile[32][33];
  const size_t zo = (size_t)blockIdx.z * R * C;
  const int c0 = blockIdx.x * 32, r0 = blockIdx.y * 32;
  const int tid = threadIdx.x;
  const int ir = tid >> 3, ic = (tid & 7) * 4;
  float4 v = *(const float4*)&in[zo + (size_t)(r0 + ir) * C + c0 + ic];
  tile[ir][ic] = v.x; tile[ir][ic + 1] = v.y;
  tile[ir][ic + 2] = v.z; tile[ir][ic + 3] = v.w;
  __syncthreads();
  const int oc = tid >> 3, orr = (tid & 7) * 4;
  const size_t ob = zo + (size_t)(c0 + oc) * R + r0 + orr;
#pragma unroll
  for (int j = 0; j < 4; ++j) {
    float f = tile[orr + j][oc];
    u16 h = f2bf(f);
    out_h[ob + j] = h;
    out_l[ob + j] = f2bf(f - bf2f(h));
  }
}

// ---------------------------------------------------------------------------
extern "C" void kernel_launch(void* const* d_in, const int* in_sizes, int n_in,
                              void* d_out, int out_size, void* d_ws, size_t ws_size,
                              hipStream_t stream)
{
  const float* x     = (const float*)d_in[0];
  const float* mh_wq = (const float*)d_in[1];
  const float* mh_wk = (const float*)d_in[2];
  const float* mh_wv = (const float*)d_in[3];
  const float* mh_g  = (const float*)d_in[4];
  const float* mh_b  = (const float*)d_in[5];
  const float* ff_w1 = (const float*)d_in[6];
  const float* ff_b1 = (const float*)d_in[7];
  const float* ff_w2 = (const float*)d_in[8];
  const float* ff_b2 = (const float*)d_in[9];
  const float* ff_g  = (const float*)d_in[10];
  const float* ff_bb = (const float*)d_in[11];
  const float* lt_w  = (const float*)d_in[12];
  const float* lt_b  = (const float*)d_in[13];
  float* out = (float*)d_out;

  const size_t ME = (size_t)Mm * Ee;   // 2M elements
  char* p = (char*)d_ws;
  auto alloc = [&](size_t bytes) { void* r = (void*)p; p += (bytes + 255) & ~(size_t)255; return r; };
  float* bufA = (float*)alloc(ME * 4);                 // 8 MB
  float* bufB = (float*)alloc(ME * 4);                 // 8 MB
  u16* wt_h   = (u16*)alloc((size_t)Ff * Ee * 2);      // 8 MB
  u16* wt_l   = (u16*)alloc((size_t)Ff * Ee * 2);      // 8 MB
  float* reg  = (float*)alloc((size_t)10 * 1024 * 1024 * 4);  // 40 MB union
  float* qb   = reg;                // mh phase
  float* kb   = reg + 2 * 1024 * 1024;
  float* vb   = reg + 4 * 1024 * 1024;
  float* ob   = reg + 6 * 1024 * 1024;
  float* hid  = reg;                // ff phase (aliases qb..ob)
  float* tmp  = reg + 8 * 1024 * 1024;

  auto mh = [&](int i, const float* src, float* dst) {
    const size_t wo = (size_t)i * Hh * Ee * Dd;
    cvtT_split<<<dim3(Dd / 32, Ee / 32, Hh), 256, 0, stream>>>(mh_wq + wo, wt_h, wt_l, Ee, Dd);
    gemm_split<64, false, false><<<dim3(Ee / 128, Mm / 64), 256, 0, stream>>>(
        src, nullptr, wt_h, wt_l, nullptr, qb, Ee, Ee);
    cvtT_split<<<dim3(Dd / 32, Ee / 32, Hh), 256, 0, stream>>>(mh_wk + wo, wt_h, wt_l, Ee, Dd);
    gemm_split<64, false, false><<<dim3(Ee / 128, Mm / 64), 256, 0, stream>>>(
        src, nullptr, wt_h, wt_l, nullptr, kb, Ee, Ee);
    cvtT_split<<<dim3(Dd / 32, Ee / 32, Hh), 256, 0, stream>>>(mh_wv + wo, wt_h, wt_l, Ee, Dd);
    gemm_split<64, false, false><<<dim3(Ee / 128, Mm / 64), 256, 0, stream>>>(
        src, nullptr, wt_h, wt_l, nullptr, vb, Ee, Ee);
    attn_ms<<<dim3(Tt / 64, Bb * Hh), 256, 0, stream>>>(qb, kb, vb, ob);
    attn_ln_res<<<dim3(Mm * Hh / 4), 256, 0, stream>>>(
        ob, src, mh_g + (size_t)i * Hh * Dd, mh_b + (size_t)i * Hh * Dd, dst);
  };
  auto ff = [&](int i, const float* src, float* dst) {
    cvtT_split<<<dim3(Ff / 32, Ee / 32, 1), 256, 0, stream>>>(ff_w1 + (size_t)i * Ee * Ff, wt_h, wt_l, Ee, Ff);
    gemm_split<128, false, true><<<dim3(Ff / 128, Mm / 128), 256, 0, stream>>>(
        src, nullptr, wt_h, wt_l, ff_b1 + (size_t)i * Ff, hid, Ff, Ee);
    cvtT_split<<<dim3(Ee / 32, Ff / 32, 1), 256, 0, stream>>>(ff_w2 + (size_t)i * Ff * Ee, wt_h, wt_l, Ff, Ee);
    gemm_split<64, false, false><<<dim3(Ee / 128, Mm / 64), 256, 0, stream>>>(
        hid, nullptr, wt_h, wt_l, ff_b2 + (size_t)i * Ee, tmp, Ee, Ff);
    ff_ln_res<<<dim3(Mm), 256, 0, stream>>>(
        tmp, src, ff_g + (size_t)i * Ee, ff_bb + (size_t)i * Ee, dst);
  };

  // out_one branch: ff(3, mh(4, mh(0, x)))
  mh(0, x, bufA);
  mh(4, bufA, bufA);
  ff(3, bufA, bufA);

  // out_two branch: 3 encoder blocks then decoder
  mh(1, x, bufB);
  ff(0, bufB, bufB);
  mh(2, bufB, bufB);
  ff(1, bufB, bufB);
  mh(3, bufB, bufB);
  ff(2, bufB, bufB);
  mh(4, bufB, bufB);
  ff(3, bufB, bufB);

  // final: out = concat(bufA, bufB) @ lt_w + lt_b  (fp32 out)
  cvtT_split<<<dim3(Ee / 32, 2 * Ee / 32, 1), 256, 0, stream>>>(lt_w, wt_h, wt_l, 2 * Ee, Ee);
  gemm_split<64, true, false><<<dim3(Ee / 128, Mm / 64), 256, 0, stream>>>(
      bufA, bufB, wt_h, wt_l, lt_b, out, Ee, 2 * Ee);
}

// Round 6
// 2002.953 us; speedup vs baseline: 2.3358x; 1.0529x over previous
//
#include <hip/hip_runtime.h>
#include <math.h>

#define Bb 4
#define Tt 512
#define Ee 1024
#define Hh 16
#define Dd 64
#define Ff 4096
#define Mm (Bb*Tt)   // 2048
static constexpr float EPS = 1e-5f;

typedef __attribute__((ext_vector_type(8))) short short8;   // 8 bf16 (4 VGPR)
typedef __attribute__((ext_vector_type(4))) float f32x4;
typedef unsigned short u16;
typedef __attribute__((ext_vector_type(4))) u16 u16x4;

__device__ __forceinline__ u16 f2bf(float f) {
  unsigned u = __builtin_bit_cast(unsigned, f);
  return (u16)((u + 0x7fffu + ((u >> 16) & 1u)) >> 16);   // RNE
}
__device__ __forceinline__ float bf2f(u16 h) {
  unsigned u = (unsigned)h << 16;
  return __builtin_bit_cast(float, u);
}

// ---------------------------------------------------------------------------
// Pre-split bf16 MFMA GEMM: C = A * W^T (+bias)(+relu), A pre-split (hi,lo),
// W pre-split (hi,lo). acc += Ah*Bh + Ah*Bl + Al*Bh (3-pass, fp32-grade).
// BM x 128 tile, BK=32, 256 thr = 4 waves (2x2), wave tile (BM/2)x64.
// Inner loop is pure copies + MFMA (split hoisted to producers).
// OUT_SPLIT: write C as (hi,lo) bf16 pair instead of fp32.
// ---------------------------------------------------------------------------
template<int BM, bool CONCAT, bool RELU, bool OUT_SPLIT>
__global__ __launch_bounds__(256)
void gemm_ps(const u16* __restrict__ Ah_g, const u16* __restrict__ Al_g,
             const u16* __restrict__ A2h, const u16* __restrict__ A2l,
             const u16* __restrict__ Wh, const u16* __restrict__ Wl,
             const float* __restrict__ bias,
             float* __restrict__ Cf, u16* __restrict__ Ch, u16* __restrict__ Cl,
             int ldc, int K)
{
  constexpr int MF = BM / 32;   // m-frags per wave
  __shared__ u16 Ah[BM][40], Al[BM][40];
  __shared__ u16 Bh[128][40], Bl[128][40];
  const int tid = threadIdx.x;
  const int lane = tid & 63;
  const int w = tid >> 6;
  const int wr = w >> 1, wc = w & 1;
  const int lhi = lane >> 4, llo = lane & 15;
  const int n0 = blockIdx.x * 128;
  const int m0 = blockIdx.y * BM;

  f32x4 acc[MF][4] = {};

  for (int k0 = 0; k0 < K; k0 += 32) {
#pragma unroll
    for (int i = 0; i < (BM * 4) / 256; ++i) {
      int c = tid + 256 * i;
      int row = c >> 2, ko = (c & 3) * 8;
      int gk = k0 + ko;
      size_t g;
      const u16 *sh, *sl;
      if (CONCAT) {
        if (gk < Ee) {
          g = (size_t)(m0 + row) * Ee + gk; sh = Ah_g; sl = Al_g;
        } else {
          g = (size_t)(m0 + row) * Ee + (gk - Ee); sh = A2h; sl = A2l;
        }
      } else {
        g = (size_t)(m0 + row) * K + gk; sh = Ah_g; sl = Al_g;
      }
      *(short8*)&Ah[row][ko] = *(const short8*)&sh[g];
      *(short8*)&Al[row][ko] = *(const short8*)&sl[g];
    }
#pragma unroll
    for (int i = 0; i < 2; ++i) {
      int c = tid + 256 * i;
      int row = c >> 2, ko = (c & 3) * 8;
      size_t g = (size_t)(n0 + row) * K + k0 + ko;
      *(short8*)&Bh[row][ko] = *(const short8*)&Wh[g];
      *(short8*)&Bl[row][ko] = *(const short8*)&Wl[g];
    }
    __syncthreads();
    short8 ah[MF], al[MF], bh[4], bl[4];
#pragma unroll
    for (int m = 0; m < MF; ++m) {
      ah[m] = *(const short8*)&Ah[wr * (BM / 2) + m * 16 + llo][lhi * 8];
      al[m] = *(const short8*)&Al[wr * (BM / 2) + m * 16 + llo][lhi * 8];
    }
#pragma unroll
    for (int n = 0; n < 4; ++n) {
      bh[n] = *(const short8*)&Bh[wc * 64 + n * 16 + llo][lhi * 8];
      bl[n] = *(const short8*)&Bl[wc * 64 + n * 16 + llo][lhi * 8];
    }
#pragma unroll
    for (int m = 0; m < MF; ++m)
#pragma unroll
      for (int n = 0; n < 4; ++n) {
        acc[m][n] = __builtin_amdgcn_mfma_f32_16x16x32_bf16(ah[m], bh[n], acc[m][n], 0, 0, 0);
        acc[m][n] = __builtin_amdgcn_mfma_f32_16x16x32_bf16(ah[m], bl[n], acc[m][n], 0, 0, 0);
        acc[m][n] = __builtin_amdgcn_mfma_f32_16x16x32_bf16(al[m], bh[n], acc[m][n], 0, 0, 0);
      }
    __syncthreads();
  }

#pragma unroll
  for (int n = 0; n < 4; ++n) {
    const int col = n0 + wc * 64 + n * 16 + llo;
    const float bv = bias ? bias[col] : 0.f;
#pragma unroll
    for (int m = 0; m < MF; ++m) {
      const int rbase = m0 + wr * (BM / 2) + m * 16 + lhi * 4;
#pragma unroll
      for (int j = 0; j < 4; ++j) {
        float v = acc[m][n][j] + bv;
        if (RELU) v = fmaxf(v, 0.f);
        const size_t idx = (size_t)(rbase + j) * ldc + col;
        if (OUT_SPLIT) {
          u16 h = f2bf(v);
          Ch[idx] = h;
          Cl[idx] = f2bf(v - bf2f(h));
        } else {
          Cf[idx] = v;
        }
      }
    }
  }
}

// ---------------------------------------------------------------------------
// Split-bf16 MFMA flash attention (PROVEN r5), causal, no 1/sqrt(d) scaling.
// ---------------------------------------------------------------------------
__global__ __launch_bounds__(256)
void attn_ms(const float* __restrict__ Q, const float* __restrict__ Kp,
             const float* __restrict__ V, float* __restrict__ O)
{
  __shared__ u16 Ksh[64][72], Ksl[64][72];   // [s][d]
  __shared__ u16 Vsh[64][72], Vsl[64][72];   // [d][s] (transposed)
  __shared__ u16 Pwh[4][16][72], Pwl[4][16][72];  // per-wave P [q_local][s]
  const int tid = threadIdx.x;
  const int lane = tid & 63, w = tid >> 6;
  const int lhi = lane >> 4, llo = lane & 15;
  const int q0 = blockIdx.x * 64;
  const int bh = blockIdx.y;
  const size_t base = (size_t)(bh >> 4) * Tt * Ee + (size_t)(bh & 15) * Dd;

  short8 qh[2], ql[2];
#pragma unroll
  for (int ks = 0; ks < 2; ++ks) {
    const float* qsrc = &Q[base + (size_t)(q0 + w * 16 + llo) * Ee + ks * 32 + lhi * 8];
    float4 a = *(const float4*)qsrc, b2 = *(const float4*)(qsrc + 4);
    float f[8] = {a.x, a.y, a.z, a.w, b2.x, b2.y, b2.z, b2.w};
#pragma unroll
    for (int j = 0; j < 8; ++j) {
      u16 h = f2bf(f[j]);
      qh[ks][j] = (short)h;
      ql[ks][j] = (short)f2bf(f[j] - bf2f(h));
    }
  }

  f32x4 oacc[4] = {};
  float m_run[4], l_run[4];
#pragma unroll
  for (int j = 0; j < 4; ++j) { m_run[j] = -INFINITY; l_run[j] = 0.f; }

  for (int s0 = 0; s0 <= q0; s0 += 64) {
#pragma unroll
    for (int pass = 0; pass < 2; ++pass) {
      int c = tid + 256 * pass;
      int row = c >> 3, d0 = (c & 7) * 8;
      const float* ksrc = &Kp[base + (size_t)(s0 + row) * Ee + d0];
      const float* vsrc = &V[base + (size_t)(s0 + row) * Ee + d0];
      float4 ka = *(const float4*)ksrc, kb2 = *(const float4*)(ksrc + 4);
      float4 va = *(const float4*)vsrc, vb2 = *(const float4*)(vsrc + 4);
      float kf[8] = {ka.x, ka.y, ka.z, ka.w, kb2.x, kb2.y, kb2.z, kb2.w};
      float vf[8] = {va.x, va.y, va.z, va.w, vb2.x, vb2.y, vb2.z, vb2.w};
      short8 khv, klv;
#pragma unroll
      for (int j = 0; j < 8; ++j) {
        u16 h = f2bf(kf[j]);
        khv[j] = (short)h;
        klv[j] = (short)f2bf(kf[j] - bf2f(h));
      }
      *(short8*)&Ksh[row][d0] = khv;
      *(short8*)&Ksl[row][d0] = klv;
#pragma unroll
      for (int j = 0; j < 8; ++j) {
        u16 h = f2bf(vf[j]);
        Vsh[d0 + j][row] = h;
        Vsl[d0 + j][row] = f2bf(vf[j] - bf2f(h));
      }
    }
    __syncthreads();

    f32x4 sacc[4] = {};
#pragma unroll
    for (int ks = 0; ks < 2; ++ks)
#pragma unroll
      for (int n = 0; n < 4; ++n) {
        short8 kh = *(const short8*)&Ksh[n * 16 + llo][ks * 32 + lhi * 8];
        short8 kl = *(const short8*)&Ksl[n * 16 + llo][ks * 32 + lhi * 8];
        sacc[n] = __builtin_amdgcn_mfma_f32_16x16x32_bf16(qh[ks], kh, sacc[n], 0, 0, 0);
        sacc[n] = __builtin_amdgcn_mfma_f32_16x16x32_bf16(qh[ks], kl, sacc[n], 0, 0, 0);
        sacc[n] = __builtin_amdgcn_mfma_f32_16x16x32_bf16(ql[ks], kh, sacc[n], 0, 0, 0);
      }

    if (s0 == q0) {
#pragma unroll
      for (int n = 0; n < 4; ++n)
#pragma unroll
        for (int j = 0; j < 4; ++j)
          if (n * 16 + llo > w * 16 + lhi * 4 + j) sacc[n][j] = -INFINITY;
    }

    float scj[4];
#pragma unroll
    for (int j = 0; j < 4; ++j) {
      float mt = fmaxf(fmaxf(sacc[0][j], sacc[1][j]), fmaxf(sacc[2][j], sacc[3][j]));
#pragma unroll
      for (int off = 1; off < 16; off <<= 1) mt = fmaxf(mt, __shfl_xor(mt, off));
      float mn = fmaxf(m_run[j], mt);
      scj[j] = __expf(m_run[j] - mn);
      m_run[j] = mn;
      float rs = 0.f;
#pragma unroll
      for (int n = 0; n < 4; ++n) {
        float pp = __expf(sacc[n][j] - mn);
        sacc[n][j] = pp;
        rs += pp;
      }
#pragma unroll
      for (int off = 1; off < 16; off <<= 1) rs += __shfl_xor(rs, off);
      l_run[j] = l_run[j] * scj[j] + rs;
    }

#pragma unroll
    for (int n = 0; n < 4; ++n)
#pragma unroll
      for (int j = 0; j < 4; ++j) {
        float pp = sacc[n][j];
        u16 h = f2bf(pp);
        Pwh[w][lhi * 4 + j][n * 16 + llo] = h;
        Pwl[w][lhi * 4 + j][n * 16 + llo] = f2bf(pp - bf2f(h));
      }
#pragma unroll
    for (int df = 0; df < 4; ++df)
#pragma unroll
      for (int j = 0; j < 4; ++j)
        oacc[df][j] *= scj[j];

#pragma unroll
    for (int ks = 0; ks < 2; ++ks) {
      short8 ph = *(const short8*)&Pwh[w][llo][ks * 32 + lhi * 8];
      short8 pl = *(const short8*)&Pwl[w][llo][ks * 32 + lhi * 8];
#pragma unroll
      for (int df = 0; df < 4; ++df) {
        short8 vh = *(const short8*)&Vsh[df * 16 + llo][ks * 32 + lhi * 8];
        short8 vl = *(const short8*)&Vsl[df * 16 + llo][ks * 32 + lhi * 8];
        oacc[df] = __builtin_amdgcn_mfma_f32_16x16x32_bf16(ph, vh, oacc[df], 0, 0, 0);
        oacc[df] = __builtin_amdgcn_mfma_f32_16x16x32_bf16(ph, vl, oacc[df], 0, 0, 0);
        oacc[df] = __builtin_amdgcn_mfma_f32_16x16x32_bf16(pl, vh, oacc[df], 0, 0, 0);
      }
    }
    __syncthreads();
  }

#pragma unroll
  for (int j = 0; j < 4; ++j) {
    float inv = 1.f / l_run[j];
#pragma unroll
    for (int df = 0; df < 4; ++df)
      O[base + (size_t)(q0 + w * 16 + lhi * 4 + j) * Ee + df * 16 + llo] =
          oacc[df][j] * inv;
  }
}

// ---------------------------------------------------------------------------
// Per-head LN over D=64 + residual; writes fp32 + (hi,lo) bf16 streams.
// ---------------------------------------------------------------------------
__global__ __launch_bounds__(256)
void attn_ln_res(const float* __restrict__ O, const float* __restrict__ Yin,
                 const float* __restrict__ g, const float* __restrict__ bta,
                 float* __restrict__ Yout, u16* __restrict__ Yh, u16* __restrict__ Yl)
{
  const int tid = threadIdx.x;
  const int w = (blockIdx.x << 2) + (tid >> 6);
  const int lane = tid & 63;
  const int m = w >> 4;
  const int h = w & 15;
  const size_t idx = (size_t)m * Ee + h * Dd + lane;
  float x = O[idx];
  float s = x, s2 = x * x;
#pragma unroll
  for (int off = 1; off < 64; off <<= 1) {
    s  += __shfl_xor(s, off);
    s2 += __shfl_xor(s2, off);
  }
  float mean = s * (1.f / 64.f);
  float var  = s2 * (1.f / 64.f) - mean * mean;
  float inv  = rsqrtf(var + EPS);
  float r = Yin[idx] + (x - mean) * inv * g[h * Dd + lane] + bta[h * Dd + lane];
  Yout[idx] = r;
  u16 hh = f2bf(r);
  Yh[idx] = hh;
  Yl[idx] = f2bf(r - bf2f(hh));
}

// ---------------------------------------------------------------------------
// Row LN over E=1024 + residual; writes fp32 + (hi,lo) bf16 streams.
// ---------------------------------------------------------------------------
__global__ __launch_bounds__(256)
void ff_ln_res(const float* __restrict__ Tm, const float* __restrict__ Yin,
               const float* __restrict__ g, const float* __restrict__ bb,
               float* __restrict__ Yout, u16* __restrict__ Yh, u16* __restrict__ Yl)
{
  __shared__ float red[8];
  const int m = blockIdx.x;
  const int tid = threadIdx.x;
  const size_t basep = (size_t)m * Ee;
  float4 x = *(const float4*)&Tm[basep + (tid << 2)];
  float s  = x.x + x.y + x.z + x.w;
  float s2 = x.x * x.x + x.y * x.y + x.z * x.z + x.w * x.w;
#pragma unroll
  for (int off = 1; off < 64; off <<= 1) {
    s  += __shfl_xor(s, off);
    s2 += __shfl_xor(s2, off);
  }
  const int wid = tid >> 6;
  if ((tid & 63) == 0) { red[wid] = s; red[4 + wid] = s2; }
  __syncthreads();
  s  = red[0] + red[1] + red[2] + red[3];
  s2 = red[4] + red[5] + red[6] + red[7];
  float mean = s * (1.f / Ee);
  float var  = s2 * (1.f / Ee) - mean * mean;
  float inv  = rsqrtf(var + EPS);
  float4 y  = *(const float4*)&Yin[basep + (tid << 2)];
  float4 gg = *(const float4*)&g[tid << 2];
  float4 bv = *(const float4*)&bb[tid << 2];
  float o[4];
  o[0] = y.x + (x.x - mean) * inv * gg.x + bv.x;
  o[1] = y.y + (x.y - mean) * inv * gg.y + bv.y;
  o[2] = y.z + (x.z - mean) * inv * gg.z + bv.z;
  o[3] = y.w + (x.w - mean) * inv * gg.w + bv.w;
  *(float4*)&Yout[basep + (tid << 2)] = *(float4*)o;
  u16x4 oh, ol;
#pragma unroll
  for (int j = 0; j < 4; ++j) {
    u16 hh = f2bf(o[j]);
    oh[j] = hh;
    ol[j] = f2bf(o[j] - bf2f(hh));
  }
  *(u16x4*)&Yh[basep + (tid << 2)] = oh;
  *(u16x4*)&Yl[basep + (tid << 2)] = ol;
}

// ---------------------------------------------------------------------------
// fp32 -> (hi,lo) bf16 split, no transpose (activations).
// ---------------------------------------------------------------------------
__global__ __launch_bounds__(256)
void split_act(const float* __restrict__ in, u16* __restrict__ oh, u16* __restrict__ ol)
{
  const size_t i = ((size_t)blockIdx.x * 256 + threadIdx.x) * 4;
  float4 v = *(const float4*)&in[i];
  float f[4] = {v.x, v.y, v.z, v.w};
  u16x4 h4, l4;
#pragma unroll
  for (int j = 0; j < 4; ++j) {
    u16 h = f2bf(f[j]);
    h4[j] = h;
    l4[j] = f2bf(f[j] - bf2f(h));
  }
  *(u16x4*)&oh[i] = h4;
  *(u16x4*)&ol[i] = l4;
}

// ---------------------------------------------------------------------------
// fp32 [R][C] -> bf16 hi/lo [C][R] transpose-split (PROVEN r4/r5).
// ---------------------------------------------------------------------------
__global__ __launch_bounds__(256)
void cvtT_split(const float* __restrict__ in, u16* __restrict__ out_h,
                u16* __restrict__ out_l, int R, int C)
{
  __shared__ float tile[32][33];
  const size_t zo = (size_t)blockIdx.z * R * C;
  const int c0 = blockIdx.x * 32, r0 = blockIdx.y * 32;
  const int tid = threadIdx.x;
  const int ir = tid >> 3, ic = (tid & 7) * 4;
  float4 v = *(const float4*)&in[zo + (size_t)(r0 + ir) * C + c0 + ic];
  tile[ir][ic] = v.x; tile[ir][ic + 1] = v.y;
  tile[ir][ic + 2] = v.z; tile[ir][ic + 3] = v.w;
  __syncthreads();
  const int oc = tid >> 3, orr = (tid & 7) * 4;
  const size_t ob = zo + (size_t)(c0 + oc) * R + r0 + orr;
#pragma unroll
  for (int j = 0; j < 4; ++j) {
    float f = tile[orr + j][oc];
    u16 h = f2bf(f);
    out_h[ob + j] = h;
    out_l[ob + j] = f2bf(f - bf2f(h));
  }
}

// ---------------------------------------------------------------------------
extern "C" void kernel_launch(void* const* d_in, const int* in_sizes, int n_in,
                              void* d_out, int out_size, void* d_ws, size_t ws_size,
                              hipStream_t stream)
{
  const float* x     = (const float*)d_in[0];
  const float* mh_wq = (const float*)d_in[1];
  const float* mh_wk = (const float*)d_in[2];
  const float* mh_wv = (const float*)d_in[3];
  const float* mh_g  = (const float*)d_in[4];
  const float* mh_b  = (const float*)d_in[5];
  const float* ff_w1 = (const float*)d_in[6];
  const float* ff_b1 = (const float*)d_in[7];
  const float* ff_w2 = (const float*)d_in[8];
  const float* ff_b2 = (const float*)d_in[9];
  const float* ff_g  = (const float*)d_in[10];
  const float* ff_bb = (const float*)d_in[11];
  const float* lt_w  = (const float*)d_in[12];
  const float* lt_b  = (const float*)d_in[13];
  float* out = (float*)d_out;

  const size_t ME = (size_t)Mm * Ee;   // 2M elements
  char* p = (char*)d_ws;
  auto alloc = [&](size_t bytes) { void* r = (void*)p; p += (bytes + 255) & ~(size_t)255; return r; };
  float* bufA  = (float*)alloc(ME * 4);                // 8 MB
  u16*   bufAh = (u16*)alloc(ME * 2);                  // 4 MB
  u16*   bufAl = (u16*)alloc(ME * 2);                  // 4 MB
  float* bufB  = (float*)alloc(ME * 4);                // 8 MB
  u16*   bufBh = (u16*)alloc(ME * 2);                  // 4 MB
  u16*   bufBl = (u16*)alloc(ME * 2);                  // 4 MB
  u16*   wt_h  = (u16*)alloc((size_t)Ff * Ee * 2);     // 8 MB
  u16*   wt_l  = (u16*)alloc((size_t)Ff * Ee * 2);     // 8 MB
  float* reg   = (float*)alloc((size_t)10 * 1024 * 1024 * 4);  // 40 MB union
  float* qb    = reg;                          // mh phase
  float* kb    = reg + 2 * 1024 * 1024;
  float* vb    = reg + 4 * 1024 * 1024;
  float* ob    = reg + 6 * 1024 * 1024;
  u16*   hidh  = (u16*)reg;                    // ff phase (aliases qb..ob)
  u16*   hidl  = (u16*)(reg + 4 * 1024 * 1024);
  float* tmp   = reg + 8 * 1024 * 1024;

  auto mh = [&](int i, const float* srcF, const u16* srcH, const u16* srcL,
                float* dstF, u16* dstH, u16* dstL) {
    const size_t wo = (size_t)i * Hh * Ee * Dd;
    cvtT_split<<<dim3(Dd / 32, Ee / 32, Hh), 256, 0, stream>>>(mh_wq + wo, wt_h, wt_l, Ee, Dd);
    gemm_ps<64, false, false, false><<<dim3(Ee / 128, Mm / 64), 256, 0, stream>>>(
        srcH, srcL, nullptr, nullptr, wt_h, wt_l, nullptr, qb, nullptr, nullptr, Ee, Ee);
    cvtT_split<<<dim3(Dd / 32, Ee / 32, Hh), 256, 0, stream>>>(mh_wk + wo, wt_h, wt_l, Ee, Dd);
    gemm_ps<64, false, false, false><<<dim3(Ee / 128, Mm / 64), 256, 0, stream>>>(
        srcH, srcL, nullptr, nullptr, wt_h, wt_l, nullptr, kb, nullptr, nullptr, Ee, Ee);
    cvtT_split<<<dim3(Dd / 32, Ee / 32, Hh), 256, 0, stream>>>(mh_wv + wo, wt_h, wt_l, Ee, Dd);
    gemm_ps<64, false, false, false><<<dim3(Ee / 128, Mm / 64), 256, 0, stream>>>(
        srcH, srcL, nullptr, nullptr, wt_h, wt_l, nullptr, vb, nullptr, nullptr, Ee, Ee);
    attn_ms<<<dim3(Tt / 64, Bb * Hh), 256, 0, stream>>>(qb, kb, vb, ob);
    attn_ln_res<<<dim3(Mm * Hh / 4), 256, 0, stream>>>(
        ob, srcF, mh_g + (size_t)i * Hh * Dd, mh_b + (size_t)i * Hh * Dd, dstF, dstH, dstL);
  };
  auto ff = [&](int i, const float* srcF, const u16* srcH, const u16* srcL,
                float* dstF, u16* dstH, u16* dstL) {
    cvtT_split<<<dim3(Ff / 32, Ee / 32, 1), 256, 0, stream>>>(ff_w1 + (size_t)i * Ee * Ff, wt_h, wt_l, Ee, Ff);
    gemm_ps<128, false, true, true><<<dim3(Ff / 128, Mm / 128), 256, 0, stream>>>(
        srcH, srcL, nullptr, nullptr, wt_h, wt_l, ff_b1 + (size_t)i * Ff,
        nullptr, hidh, hidl, Ff, Ee);
    cvtT_split<<<dim3(Ee / 32, Ff / 32, 1), 256, 0, stream>>>(ff_w2 + (size_t)i * Ff * Ee, wt_h, wt_l, Ff, Ee);
    gemm_ps<64, false, false, false><<<dim3(Ee / 128, Mm / 64), 256, 0, stream>>>(
        hidh, hidl, nullptr, nullptr, wt_h, wt_l, ff_b2 + (size_t)i * Ee,
        tmp, nullptr, nullptr, Ee, Ff);
    ff_ln_res<<<dim3(Mm), 256, 0, stream>>>(
        tmp, srcF, ff_g + (size_t)i * Ee, ff_bb + (size_t)i * Ee, dstF, dstH, dstL);
  };

  // out_one branch: ff(3, mh(4, mh(0, x)))
  split_act<<<dim3(ME / 1024), 256, 0, stream>>>(x, bufAh, bufAl);  // x-split in bufA h/l
  mh(0, x, bufAh, bufAl, bufA, bufAh, bufAl);
  mh(4, bufA, bufAh, bufAl, bufA, bufAh, bufAl);
  ff(3, bufA, bufAh, bufAl, bufA, bufAh, bufAl);

  // out_two branch: 3 encoder blocks then decoder
  split_act<<<dim3(ME / 1024), 256, 0, stream>>>(x, bufBh, bufBl);
  mh(1, x, bufBh, bufBl, bufB, bufBh, bufBl);
  ff(0, bufB, bufBh, bufBl, bufB, bufBh, bufBl);
  mh(2, bufB, bufBh, bufBl, bufB, bufBh, bufBl);
  ff(1, bufB, bufBh, bufBl, bufB, bufBh, bufBl);
  mh(3, bufB, bufBh, bufBl, bufB, bufBh, bufBl);
  ff(2, bufB, bufBh, bufBl, bufB, bufBh, bufBl);
  mh(4, bufB, bufBh, bufBl, bufB, bufBh, bufBl);
  ff(3, bufB, bufBh, bufBl, bufB, bufBh, bufBl);

  // final: out = concat(bufA, bufB) @ lt_w + lt_b  (fp32 out)
  cvtT_split<<<dim3(Ee / 32, 2 * Ee / 32, 1), 256, 0, stream>>>(lt_w, wt_h, wt_l, 2 * Ee, Ee);
  gemm_ps<64, true, false, false><<<dim3(Ee / 128, Mm / 64), 256, 0, stream>>>(
      bufAh, bufAl, bufBh, bufBl, wt_h, wt_l, lt_b, out, nullptr, nullptr, Ee, 2 * Ee);
}

// Round 7
// 1624.199 us; speedup vs baseline: 2.8805x; 1.2332x over previous
//
#include <hip/hip_runtime.h>
#include <math.h>

#define Bb 4
#define Tt 512
#define Ee 1024
#define Hh 16
#define Dd 64
#define Ff 4096
#define Mm (Bb*Tt)   // 2048
static constexpr float EPS = 1e-5f;

typedef __attribute__((ext_vector_type(8))) short short8;   // 8 bf16 (4 VGPR)
typedef __attribute__((ext_vector_type(4))) float f32x4;
typedef unsigned short u16;
typedef __attribute__((ext_vector_type(4))) u16 u16x4;

__device__ __forceinline__ u16 f2bf(float f) {
  unsigned u = __builtin_bit_cast(unsigned, f);
  return (u16)((u + 0x7fffu + ((u >> 16) & 1u)) >> 16);   // RNE
}
__device__ __forceinline__ float bf2f(u16 h) {
  unsigned u = (unsigned)h << 16;
  return __builtin_bit_cast(float, u);
}

// ---------------------------------------------------------------------------
// Pre-split bf16 MFMA GEMM, double-buffered + reg-prefetch (2-phase).
// C = A * W^T (+bias)(+relu). A,W pre-split (hi,lo) bf16.
// acc += Ah*Bh + Ah*Bl + Al*Bh (3-pass). 64x128 tile, BK=32, 4 waves (2x2),
// wave tile 32x64. LDS: 2 buffers x (A 64x40 h/l + B 128x40 h/l) = 60 KB.
// Loop: issue loads(t+1) -> compute(t from LDS[cur]) -> commit regs->LDS[cur^1]
// -> one barrier. Global latency hides under MFMA of tile t.
// QKV: grid.x = 24, section = bx>>3 selects weight slab + output buffer.
// ---------------------------------------------------------------------------
template<bool CONCAT, bool RELU, bool OUT_SPLIT, bool QKV>
__global__ __launch_bounds__(256)
void gemm_ps(const u16* __restrict__ Ah_g, const u16* __restrict__ Al_g,
             const u16* __restrict__ A2h, const u16* __restrict__ A2l,
             const u16* __restrict__ Wh, const u16* __restrict__ Wl,
             const float* __restrict__ bias,
             float* __restrict__ Cf, float* __restrict__ Cf1, float* __restrict__ Cf2,
             u16* __restrict__ Ch, u16* __restrict__ Cl,
             int ldc, int K)
{
  __shared__ u16 AhS[2][64][40], AlS[2][64][40];
  __shared__ u16 BhS[2][128][40], BlS[2][128][40];
  const int tid = threadIdx.x;
  const int lane = tid & 63;
  const int w = tid >> 6;
  const int wr = w >> 1, wc = w & 1;
  const int lhi = lane >> 4, llo = lane & 15;
  int n0;
  if (QKV) {
    const int sec = blockIdx.x >> 3;
    n0 = (blockIdx.x & 7) * 128;
    Wh += (size_t)sec << 20;   // sections of [1024][1024]
    Wl += (size_t)sec << 20;
    if (sec == 1) Cf = Cf1; else if (sec == 2) Cf = Cf2;
  } else {
    n0 = blockIdx.x * 128;
  }
  const int m0 = blockIdx.y * 64;

  const int s_row = tid >> 2, s_ko = (tid & 3) * 8;   // staging coords

  short8 rAh, rAl, rBh[2], rBl[2];

  auto issue = [&](int k0) {
    int gk = k0 + s_ko;
    size_t g; const u16 *sh, *sl;
    if (CONCAT) {
      if (gk < Ee) { g = (size_t)(m0 + s_row) * Ee + gk; sh = Ah_g; sl = Al_g; }
      else { g = (size_t)(m0 + s_row) * Ee + (gk - Ee); sh = A2h; sl = A2l; }
    } else { g = (size_t)(m0 + s_row) * K + gk; sh = Ah_g; sl = Al_g; }
    rAh = *(const short8*)&sh[g];
    rAl = *(const short8*)&sl[g];
#pragma unroll
    for (int i = 0; i < 2; ++i) {
      size_t gb = (size_t)(n0 + s_row + i * 64) * K + k0 + s_ko;
      rBh[i] = *(const short8*)&Wh[gb];
      rBl[i] = *(const short8*)&Wl[gb];
    }
  };
  auto commit = [&](int buf) {
    *(short8*)&AhS[buf][s_row][s_ko] = rAh;
    *(short8*)&AlS[buf][s_row][s_ko] = rAl;
#pragma unroll
    for (int i = 0; i < 2; ++i) {
      *(short8*)&BhS[buf][s_row + i * 64][s_ko] = rBh[i];
      *(short8*)&BlS[buf][s_row + i * 64][s_ko] = rBl[i];
    }
  };

  f32x4 acc[2][4] = {};
  const int nt = K / 32;
  issue(0);
  commit(0);
  __syncthreads();
  int cur = 0;
  for (int t = 0; t < nt; ++t) {
    if (t + 1 < nt) issue((t + 1) * 32);
    short8 ah[2], al[2], bh[4], bl[4];
#pragma unroll
    for (int m = 0; m < 2; ++m) {
      ah[m] = *(const short8*)&AhS[cur][wr * 32 + m * 16 + llo][lhi * 8];
      al[m] = *(const short8*)&AlS[cur][wr * 32 + m * 16 + llo][lhi * 8];
    }
#pragma unroll
    for (int n = 0; n < 4; ++n) {
      bh[n] = *(const short8*)&BhS[cur][wc * 64 + n * 16 + llo][lhi * 8];
      bl[n] = *(const short8*)&BlS[cur][wc * 64 + n * 16 + llo][lhi * 8];
    }
#pragma unroll
    for (int m = 0; m < 2; ++m)
#pragma unroll
      for (int n = 0; n < 4; ++n) {
        acc[m][n] = __builtin_amdgcn_mfma_f32_16x16x32_bf16(ah[m], bh[n], acc[m][n], 0, 0, 0);
        acc[m][n] = __builtin_amdgcn_mfma_f32_16x16x32_bf16(ah[m], bl[n], acc[m][n], 0, 0, 0);
        acc[m][n] = __builtin_amdgcn_mfma_f32_16x16x32_bf16(al[m], bh[n], acc[m][n], 0, 0, 0);
      }
    if (t + 1 < nt) {
      commit(cur ^ 1);
      __syncthreads();
      cur ^= 1;
    }
  }

#pragma unroll
  for (int n = 0; n < 4; ++n) {
    const int col = n0 + wc * 64 + n * 16 + llo;
    const float bv = bias ? bias[col] : 0.f;
#pragma unroll
    for (int m = 0; m < 2; ++m) {
      const int rbase = m0 + wr * 32 + m * 16 + lhi * 4;
#pragma unroll
      for (int j = 0; j < 4; ++j) {
        float v = acc[m][n][j] + bv;
        if (RELU) v = fmaxf(v, 0.f);
        const size_t idx = (size_t)(rbase + j) * ldc + col;
        if (OUT_SPLIT) {
          u16 h = f2bf(v);
          Ch[idx] = h;
          Cl[idx] = f2bf(v - bf2f(h));
        } else {
          Cf[idx] = v;
        }
      }
    }
  }
}

// ---------------------------------------------------------------------------
// Split-bf16 MFMA flash attention (PROVEN r5/r6), causal, no 1/sqrt(d).
// ---------------------------------------------------------------------------
__global__ __launch_bounds__(256)
void attn_ms(const float* __restrict__ Q, const float* __restrict__ Kp,
             const float* __restrict__ V, float* __restrict__ O)
{
  __shared__ u16 Ksh[64][72], Ksl[64][72];   // [s][d]
  __shared__ u16 Vsh[64][72], Vsl[64][72];   // [d][s] (transposed)
  __shared__ u16 Pwh[4][16][72], Pwl[4][16][72];  // per-wave P [q_local][s]
  const int tid = threadIdx.x;
  const int lane = tid & 63, w = tid >> 6;
  const int lhi = lane >> 4, llo = lane & 15;
  const int q0 = blockIdx.x * 64;
  const int bh = blockIdx.y;
  const size_t base = (size_t)(bh >> 4) * Tt * Ee + (size_t)(bh & 15) * Dd;

  short8 qh[2], ql[2];
#pragma unroll
  for (int ks = 0; ks < 2; ++ks) {
    const float* qsrc = &Q[base + (size_t)(q0 + w * 16 + llo) * Ee + ks * 32 + lhi * 8];
    float4 a = *(const float4*)qsrc, b2 = *(const float4*)(qsrc + 4);
    float f[8] = {a.x, a.y, a.z, a.w, b2.x, b2.y, b2.z, b2.w};
#pragma unroll
    for (int j = 0; j < 8; ++j) {
      u16 h = f2bf(f[j]);
      qh[ks][j] = (short)h;
      ql[ks][j] = (short)f2bf(f[j] - bf2f(h));
    }
  }

  f32x4 oacc[4] = {};
  float m_run[4], l_run[4];
#pragma unroll
  for (int j = 0; j < 4; ++j) { m_run[j] = -INFINITY; l_run[j] = 0.f; }

  for (int s0 = 0; s0 <= q0; s0 += 64) {
#pragma unroll
    for (int pass = 0; pass < 2; ++pass) {
      int c = tid + 256 * pass;
      int row = c >> 3, d0 = (c & 7) * 8;
      const float* ksrc = &Kp[base + (size_t)(s0 + row) * Ee + d0];
      const float* vsrc = &V[base + (size_t)(s0 + row) * Ee + d0];
      float4 ka = *(const float4*)ksrc, kb2 = *(const float4*)(ksrc + 4);
      float4 va = *(const float4*)vsrc, vb2 = *(const float4*)(vsrc + 4);
      float kf[8] = {ka.x, ka.y, ka.z, ka.w, kb2.x, kb2.y, kb2.z, kb2.w};
      float vf[8] = {va.x, va.y, va.z, va.w, vb2.x, vb2.y, vb2.z, vb2.w};
      short8 khv, klv;
#pragma unroll
      for (int j = 0; j < 8; ++j) {
        u16 h = f2bf(kf[j]);
        khv[j] = (short)h;
        klv[j] = (short)f2bf(kf[j] - bf2f(h));
      }
      *(short8*)&Ksh[row][d0] = khv;
      *(short8*)&Ksl[row][d0] = klv;
#pragma unroll
      for (int j = 0; j < 8; ++j) {
        u16 h = f2bf(vf[j]);
        Vsh[d0 + j][row] = h;
        Vsl[d0 + j][row] = f2bf(vf[j] - bf2f(h));
      }
    }
    __syncthreads();

    f32x4 sacc[4] = {};
#pragma unroll
    for (int ks = 0; ks < 2; ++ks)
#pragma unroll
      for (int n = 0; n < 4; ++n) {
        short8 kh = *(const short8*)&Ksh[n * 16 + llo][ks * 32 + lhi * 8];
        short8 kl = *(const short8*)&Ksl[n * 16 + llo][ks * 32 + lhi * 8];
        sacc[n] = __builtin_amdgcn_mfma_f32_16x16x32_bf16(qh[ks], kh, sacc[n], 0, 0, 0);
        sacc[n] = __builtin_amdgcn_mfma_f32_16x16x32_bf16(qh[ks], kl, sacc[n], 0, 0, 0);
        sacc[n] = __builtin_amdgcn_mfma_f32_16x16x32_bf16(ql[ks], kh, sacc[n], 0, 0, 0);
      }

    if (s0 == q0) {
#pragma unroll
      for (int n = 0; n < 4; ++n)
#pragma unroll
        for (int j = 0; j < 4; ++j)
          if (n * 16 + llo > w * 16 + lhi * 4 + j) sacc[n][j] = -INFINITY;
    }

    float scj[4];
#pragma unroll
    for (int j = 0; j < 4; ++j) {
      float mt = fmaxf(fmaxf(sacc[0][j], sacc[1][j]), fmaxf(sacc[2][j], sacc[3][j]));
#pragma unroll
      for (int off = 1; off < 16; off <<= 1) mt = fmaxf(mt, __shfl_xor(mt, off));
      float mn = fmaxf(m_run[j], mt);
      scj[j] = __expf(m_run[j] - mn);
      m_run[j] = mn;
      float rs = 0.f;
#pragma unroll
      for (int n = 0; n < 4; ++n) {
        float pp = __expf(sacc[n][j] - mn);
        sacc[n][j] = pp;
        rs += pp;
      }
#pragma unroll
      for (int off = 1; off < 16; off <<= 1) rs += __shfl_xor(rs, off);
      l_run[j] = l_run[j] * scj[j] + rs;
    }

#pragma unroll
    for (int n = 0; n < 4; ++n)
#pragma unroll
      for (int j = 0; j < 4; ++j) {
        float pp = sacc[n][j];
        u16 h = f2bf(pp);
        Pwh[w][lhi * 4 + j][n * 16 + llo] = h;
        Pwl[w][lhi * 4 + j][n * 16 + llo] = f2bf(pp - bf2f(h));
      }
#pragma unroll
    for (int df = 0; df < 4; ++df)
#pragma unroll
      for (int j = 0; j < 4; ++j)
        oacc[df][j] *= scj[j];

#pragma unroll
    for (int ks = 0; ks < 2; ++ks) {
      short8 ph = *(const short8*)&Pwh[w][llo][ks * 32 + lhi * 8];
      short8 pl = *(const short8*)&Pwl[w][llo][ks * 32 + lhi * 8];
#pragma unroll
      for (int df = 0; df < 4; ++df) {
        short8 vh = *(const short8*)&Vsh[df * 16 + llo][ks * 32 + lhi * 8];
        short8 vl = *(const short8*)&Vsl[df * 16 + llo][ks * 32 + lhi * 8];
        oacc[df] = __builtin_amdgcn_mfma_f32_16x16x32_bf16(ph, vh, oacc[df], 0, 0, 0);
        oacc[df] = __builtin_amdgcn_mfma_f32_16x16x32_bf16(ph, vl, oacc[df], 0, 0, 0);
        oacc[df] = __builtin_amdgcn_mfma_f32_16x16x32_bf16(pl, vh, oacc[df], 0, 0, 0);
      }
    }
    __syncthreads();
  }

#pragma unroll
  for (int j = 0; j < 4; ++j) {
    float inv = 1.f / l_run[j];
#pragma unroll
    for (int df = 0; df < 4; ++df)
      O[base + (size_t)(q0 + w * 16 + lhi * 4 + j) * Ee + df * 16 + llo] =
          oacc[df][j] * inv;
  }
}

// ---------------------------------------------------------------------------
// Per-head LN over D=64 + residual; writes fp32 + (hi,lo) bf16 streams.
// ---------------------------------------------------------------------------
__global__ __launch_bounds__(256)
void attn_ln_res(const float* __restrict__ O, const float* __restrict__ Yin,
                 const float* __restrict__ g, const float* __restrict__ bta,
                 float* __restrict__ Yout, u16* __restrict__ Yh, u16* __restrict__ Yl)
{
  const int tid = threadIdx.x;
  const int w = (blockIdx.x << 2) + (tid >> 6);
  const int lane = tid & 63;
  const int m = w >> 4;
  const int h = w & 15;
  const size_t idx = (size_t)m * Ee + h * Dd + lane;
  float x = O[idx];
  float s = x, s2 = x * x;
#pragma unroll
  for (int off = 1; off < 64; off <<= 1) {
    s  += __shfl_xor(s, off);
    s2 += __shfl_xor(s2, off);
  }
  float mean = s * (1.f / 64.f);
  float var  = s2 * (1.f / 64.f) - mean * mean;
  float inv  = rsqrtf(var + EPS);
  float r = Yin[idx] + (x - mean) * inv * g[h * Dd + lane] + bta[h * Dd + lane];
  Yout[idx] = r;
  u16 hh = f2bf(r);
  Yh[idx] = hh;
  Yl[idx] = f2bf(r - bf2f(hh));
}

// ---------------------------------------------------------------------------
// Row LN over E=1024 + residual; writes fp32 + (hi,lo) bf16 streams.
// ---------------------------------------------------------------------------
__global__ __launch_bounds__(256)
void ff_ln_res(const float* __restrict__ Tm, const float* __restrict__ Yin,
               const float* __restrict__ g, const float* __restrict__ bb,
               float* __restrict__ Yout, u16* __restrict__ Yh, u16* __restrict__ Yl)
{
  __shared__ float red[8];
  const int m = blockIdx.x;
  const int tid = threadIdx.x;
  const size_t basep = (size_t)m * Ee;
  float4 x = *(const float4*)&Tm[basep + (tid << 2)];
  float s  = x.x + x.y + x.z + x.w;
  float s2 = x.x * x.x + x.y * x.y + x.z * x.z + x.w * x.w;
#pragma unroll
  for (int off = 1; off < 64; off <<= 1) {
    s  += __shfl_xor(s, off);
    s2 += __shfl_xor(s2, off);
  }
  const int wid = tid >> 6;
  if ((tid & 63) == 0) { red[wid] = s; red[4 + wid] = s2; }
  __syncthreads();
  s  = red[0] + red[1] + red[2] + red[3];
  s2 = red[4] + red[5] + red[6] + red[7];
  float mean = s * (1.f / Ee);
  float var  = s2 * (1.f / Ee) - mean * mean;
  float inv  = rsqrtf(var + EPS);
  float4 y  = *(const float4*)&Yin[basep + (tid << 2)];
  float4 gg = *(const float4*)&g[tid << 2];
  float4 bv = *(const float4*)&bb[tid << 2];
  float o[4];
  o[0] = y.x + (x.x - mean) * inv * gg.x + bv.x;
  o[1] = y.y + (x.y - mean) * inv * gg.y + bv.y;
  o[2] = y.z + (x.z - mean) * inv * gg.z + bv.z;
  o[3] = y.w + (x.w - mean) * inv * gg.w + bv.w;
  *(float4*)&Yout[basep + (tid << 2)] = *(float4*)o;
  u16x4 oh, ol;
#pragma unroll
  for (int j = 0; j < 4; ++j) {
    u16 hh = f2bf(o[j]);
    oh[j] = hh;
    ol[j] = f2bf(o[j] - bf2f(hh));
  }
  *(u16x4*)&Yh[basep + (tid << 2)] = oh;
  *(u16x4*)&Yl[basep + (tid << 2)] = ol;
}

// ---------------------------------------------------------------------------
// fp32 -> (hi,lo) bf16 split, no transpose (activations).
// ---------------------------------------------------------------------------
__global__ __launch_bounds__(256)
void split_act(const float* __restrict__ in, u16* __restrict__ oh, u16* __restrict__ ol)
{
  const size_t i = ((size_t)blockIdx.x * 256 + threadIdx.x) * 4;
  float4 v = *(const float4*)&in[i];
  float f[4] = {v.x, v.y, v.z, v.w};
  u16x4 h4, l4;
#pragma unroll
  for (int j = 0; j < 4; ++j) {
    u16 h = f2bf(f[j]);
    h4[j] = h;
    l4[j] = f2bf(f[j] - bf2f(h));
  }
  *(u16x4*)&oh[i] = h4;
  *(u16x4*)&ol[i] = l4;
}

// ---------------------------------------------------------------------------
// fp32 [R][C] -> bf16 hi/lo [C][R] transpose-split (PROVEN r4-r6).
// ---------------------------------------------------------------------------
__global__ __launch_bounds__(256)
void cvtT_split(const float* __restrict__ in, u16* __restrict__ out_h,
                u16* __restrict__ out_l, int R, int C)
{
  __shared__ float tile[32][33];
  const size_t zo = (size_t)blockIdx.z * R * C;
  const int c0 = blockIdx.x * 32, r0 = blockIdx.y * 32;
  const int tid = threadIdx.x;
  const int ir = tid >> 3, ic = (tid & 7) * 4;
  float4 v = *(const float4*)&in[zo + (size_t)(r0 + ir) * C + c0 + ic];
  tile[ir][ic] = v.x; tile[ir][ic + 1] = v.y;
  tile[ir][ic + 2] = v.z; tile[ir][ic + 3] = v.w;
  __syncthreads();
  const int oc = tid >> 3, orr = (tid & 7) * 4;
  const size_t ob = zo + (size_t)(c0 + oc) * R + r0 + orr;
#pragma unroll
  for (int j = 0; j < 4; ++j) {
    float f = tile[orr + j][oc];
    u16 h = f2bf(f);
    out_h[ob + j] = h;
    out_l[ob + j] = f2bf(f - bf2f(h));
  }
}

// ---------------------------------------------------------------------------
extern "C" void kernel_launch(void* const* d_in, const int* in_sizes, int n_in,
                              void* d_out, int out_size, void* d_ws, size_t ws_size,
                              hipStream_t stream)
{
  const float* x     = (const float*)d_in[0];
  const float* mh_wq = (const float*)d_in[1];
  const float* mh_wk = (const float*)d_in[2];
  const float* mh_wv = (const float*)d_in[3];
  const float* mh_g  = (const float*)d_in[4];
  const float* mh_b  = (const float*)d_in[5];
  const float* ff_w1 = (const float*)d_in[6];
  const float* ff_b1 = (const float*)d_in[7];
  const float* ff_w2 = (const float*)d_in[8];
  const float* ff_b2 = (const float*)d_in[9];
  const float* ff_g  = (const float*)d_in[10];
  const float* ff_bb = (const float*)d_in[11];
  const float* lt_w  = (const float*)d_in[12];
  const float* lt_b  = (const float*)d_in[13];
  float* out = (float*)d_out;

  const size_t ME = (size_t)Mm * Ee;   // 2M elements
  char* p = (char*)d_ws;
  auto alloc = [&](size_t bytes) { void* r = (void*)p; p += (bytes + 255) & ~(size_t)255; return r; };
  float* bufA  = (float*)alloc(ME * 4);                // 8 MB
  u16*   bufAh = (u16*)alloc(ME * 2);                  // 4 MB
  u16*   bufAl = (u16*)alloc(ME * 2);                  // 4 MB
  float* bufB  = (float*)alloc(ME * 4);                // 8 MB
  u16*   bufBh = (u16*)alloc(ME * 2);                  // 4 MB
  u16*   bufBl = (u16*)alloc(ME * 2);                  // 4 MB
  u16*   wt_h  = (u16*)alloc((size_t)Ff * Ee * 2);     // 8 MB (also holds QKV 3x1M slabs)
  u16*   wt_l  = (u16*)alloc((size_t)Ff * Ee * 2);     // 8 MB
  float* reg   = (float*)alloc((size_t)10 * 1024 * 1024 * 4);  // 40 MB union
  float* qb    = reg;                          // mh phase
  float* kb    = reg + 2 * 1024 * 1024;
  float* vb    = reg + 4 * 1024 * 1024;
  float* ob    = reg + 6 * 1024 * 1024;
  u16*   hidh  = (u16*)reg;                    // ff phase (aliases qb..ob)
  u16*   hidl  = (u16*)(reg + 4 * 1024 * 1024);
  float* tmp   = reg + 8 * 1024 * 1024;

  auto mh = [&](int i, const float* srcF, const u16* srcH, const u16* srcL,
                float* dstF, u16* dstH, u16* dstL) {
    const size_t wo = (size_t)i * Hh * Ee * Dd;
    cvtT_split<<<dim3(Dd / 32, Ee / 32, Hh), 256, 0, stream>>>(mh_wq + wo, wt_h, wt_l, Ee, Dd);
    cvtT_split<<<dim3(Dd / 32, Ee / 32, Hh), 256, 0, stream>>>(mh_wk + wo, wt_h + (1u << 20), wt_l + (1u << 20), Ee, Dd);
    cvtT_split<<<dim3(Dd / 32, Ee / 32, Hh), 256, 0, stream>>>(mh_wv + wo, wt_h + (2u << 20), wt_l + (2u << 20), Ee, Dd);
    gemm_ps<false, false, false, true><<<dim3(24, Mm / 64), 256, 0, stream>>>(
        srcH, srcL, nullptr, nullptr, wt_h, wt_l, nullptr,
        qb, kb, vb, nullptr, nullptr, Ee, Ee);
    attn_ms<<<dim3(Tt / 64, Bb * Hh), 256, 0, stream>>>(qb, kb, vb, ob);
    attn_ln_res<<<dim3(Mm * Hh / 4), 256, 0, stream>>>(
        ob, srcF, mh_g + (size_t)i * Hh * Dd, mh_b + (size_t)i * Hh * Dd, dstF, dstH, dstL);
  };
  auto ff = [&](int i, const float* srcF, const u16* srcH, const u16* srcL,
                float* dstF, u16* dstH, u16* dstL) {
    cvtT_split<<<dim3(Ff / 32, Ee / 32, 1), 256, 0, stream>>>(ff_w1 + (size_t)i * Ee * Ff, wt_h, wt_l, Ee, Ff);
    gemm_ps<false, true, true, false><<<dim3(Ff / 128, Mm / 64), 256, 0, stream>>>(
        srcH, srcL, nullptr, nullptr, wt_h, wt_l, ff_b1 + (size_t)i * Ff,
        nullptr, nullptr, nullptr, hidh, hidl, Ff, Ee);
    cvtT_split<<<dim3(Ee / 32, Ff / 32, 1), 256, 0, stream>>>(ff_w2 + (size_t)i * Ff * Ee, wt_h, wt_l, Ff, Ee);
    gemm_ps<false, false, false, false><<<dim3(Ee / 128, Mm / 64), 256, 0, stream>>>(
        hidh, hidl, nullptr, nullptr, wt_h, wt_l, ff_b2 + (size_t)i * Ee,
        tmp, nullptr, nullptr, nullptr, nullptr, Ee, Ff);
    ff_ln_res<<<dim3(Mm), 256, 0, stream>>>(
        tmp, srcF, ff_g + (size_t)i * Ee, ff_bb + (size_t)i * Ee, dstF, dstH, dstL);
  };

  // out_one branch: ff(3, mh(4, mh(0, x)))
  split_act<<<dim3(ME / 1024), 256, 0, stream>>>(x, bufAh, bufAl);
  mh(0, x, bufAh, bufAl, bufA, bufAh, bufAl);
  mh(4, bufA, bufAh, bufAl, bufA, bufAh, bufAl);
  ff(3, bufA, bufAh, bufAl, bufA, bufAh, bufAl);

  // out_two branch: 3 encoder blocks then decoder
  split_act<<<dim3(ME / 1024), 256, 0, stream>>>(x, bufBh, bufBl);
  mh(1, x, bufBh, bufBl, bufB, bufBh, bufBl);
  ff(0, bufB, bufBh, bufBl, bufB, bufBh, bufBl);
  mh(2, bufB, bufBh, bufBl, bufB, bufBh, bufBl);
  ff(1, bufB, bufBh, bufBl, bufB, bufBh, bufBl);
  mh(3, bufB, bufBh, bufBl, bufB, bufBh, bufBl);
  ff(2, bufB, bufBh, bufBl, bufB, bufBh, bufBl);
  mh(4, bufB, bufBh, bufBl, bufB, bufBh, bufBl);
  ff(3, bufB, bufBh, bufBl, bufB, bufBh, bufBl);

  // final: out = concat(bufA, bufB) @ lt_w + lt_b  (fp32 out)
  cvtT_split<<<dim3(Ee / 32, 2 * Ee / 32, 1), 256, 0, stream>>>(lt_w, wt_h, wt_l, 2 * Ee, Ee);
  gemm_ps<true, false, false, false><<<dim3(Ee / 128, Mm / 64), 256, 0, stream>>>(
      bufAh, bufAl, bufBh, bufBl, wt_h, wt_l, lt_b,
      out, nullptr, nullptr, nullptr, nullptr, Ee, 2 * Ee);
}

// Round 8
// 1502.876 us; speedup vs baseline: 3.1130x; 1.0807x over previous
//
#include <hip/hip_runtime.h>
#include <math.h>

#define Bb 4
#define Tt 512
#define Ee 1024
#define Hh 16
#define Dd 64
#define Ff 4096
#define Mm (Bb*Tt)   // 2048
static constexpr float EPS = 1e-5f;

typedef __attribute__((ext_vector_type(8))) short short8;   // 8 bf16 (4 VGPR)
typedef __attribute__((ext_vector_type(4))) float f32x4;
typedef unsigned short u16;
typedef __attribute__((ext_vector_type(4))) u16 u16x4;

__device__ __forceinline__ u16 f2bf(float f) {
  unsigned u = __builtin_bit_cast(unsigned, f);
  return (u16)((u + 0x7fffu + ((u >> 16) & 1u)) >> 16);   // RNE
}
__device__ __forceinline__ float bf2f(u16 h) {
  unsigned u = (unsigned)h << 16;
  return __builtin_bit_cast(float, u);
}
// async global->LDS, 16B per lane. LDS dest must be lane-linear (ours: tid*16).
__device__ __forceinline__ void gload16(const void* g, void* l) {
  __builtin_amdgcn_global_load_lds(
      (const __attribute__((address_space(1))) unsigned int*)g,
      (__attribute__((address_space(3))) unsigned int*)l, 16, 0, 0);
}

// ---------------------------------------------------------------------------
// Pre-split bf16 MFMA GEMM, global_load_lds staging + dbuf (m97 structure).
// C = A * W^T (+bias)(+relu). A,W pre-split (hi,lo) bf16.
// acc += Ah*Bh + Ah*Bl + Al*Bh (3-pass). 64x128 tile, BK=32, 4 waves (2x2),
// wave tile 32x64. LDS: 2 x (A 64x32 h/l + B 128x32 h/l) = 48 KB -> 3 blk/CU.
// Staging LDS byte offset == tid*16 (lane-linear, required by global_load_lds).
// QKV: grid.x = 24, sec = bx>>3 selects weight slab + output buffer.
// SPLITK: blockIdx.z halves K; z=1 writes Cf1; no bias (moved to consumer).
// ---------------------------------------------------------------------------
template<bool CONCAT, bool RELU, bool OUT_SPLIT, bool QKV, bool SPLITK>
__global__ __launch_bounds__(256)
void gemm_ps(const u16* __restrict__ Ah_g, const u16* __restrict__ Al_g,
             const u16* __restrict__ A2h, const u16* __restrict__ A2l,
             const u16* __restrict__ Wh, const u16* __restrict__ Wl,
             const float* __restrict__ bias,
             float* __restrict__ Cf, float* __restrict__ Cf1, float* __restrict__ Cf2,
             u16* __restrict__ Ch, u16* __restrict__ Cl,
             int ldc, int K)
{
  __shared__ u16 AhS[2][64][32], AlS[2][64][32];
  __shared__ u16 BhS[2][128][32], BlS[2][128][32];
  const int tid = threadIdx.x;
  const int lane = tid & 63;
  const int w = tid >> 6;
  const int wr = w >> 1, wc = w & 1;
  const int lhi = lane >> 4, llo = lane & 15;
  int n0;
  if (QKV) {
    const int sec = blockIdx.x >> 3;
    n0 = (blockIdx.x & 7) * 128;
    Wh += (size_t)sec << 20;   // sections of [1024][1024]
    Wl += (size_t)sec << 20;
    if (sec == 1) Cf = Cf1; else if (sec == 2) Cf = Cf2;
  } else {
    n0 = blockIdx.x * 128;
  }
  const int m0 = blockIdx.y * 64;
  int kbeg = 0, nt = K / 32;
  if (SPLITK) {
    const int half = K >> 1;
    kbeg = blockIdx.z * half;
    nt = half / 32;
    if (blockIdx.z == 1) Cf = Cf1;
  }

  const int s_row = tid >> 2, s_ko = (tid & 3) * 8;   // LDS byte off = tid*16

  auto stage = [&](int k0, int buf) {
    const int gk = k0 + s_ko;
    const u16 *sh = Ah_g, *sl = Al_g;
    size_t g;
    if (CONCAT) {
      if (gk < Ee) { g = (size_t)(m0 + s_row) * Ee + gk; }
      else { g = (size_t)(m0 + s_row) * Ee + (gk - Ee); sh = A2h; sl = A2l; }
    } else {
      g = (size_t)(m0 + s_row) * K + gk;
    }
    gload16(&sh[g], &AhS[buf][s_row][s_ko]);
    gload16(&sl[g], &AlS[buf][s_row][s_ko]);
#pragma unroll
    for (int i = 0; i < 2; ++i) {
      size_t gb = (size_t)(n0 + s_row + i * 64) * K + gk;
      gload16(&Wh[gb], &BhS[buf][s_row + i * 64][s_ko]);
      gload16(&Wl[gb], &BlS[buf][s_row + i * 64][s_ko]);
    }
  };

  f32x4 acc[2][4] = {};
  stage(kbeg, 0);
  __syncthreads();
  int cur = 0;
  for (int t = 0; t < nt; ++t) {
    if (t + 1 < nt) stage(kbeg + (t + 1) * 32, cur ^ 1);
    short8 ah[2], al[2], bh[4], bl[4];
#pragma unroll
    for (int m = 0; m < 2; ++m) {
      ah[m] = *(const short8*)&AhS[cur][wr * 32 + m * 16 + llo][lhi * 8];
      al[m] = *(const short8*)&AlS[cur][wr * 32 + m * 16 + llo][lhi * 8];
    }
#pragma unroll
    for (int n = 0; n < 4; ++n) {
      bh[n] = *(const short8*)&BhS[cur][wc * 64 + n * 16 + llo][lhi * 8];
      bl[n] = *(const short8*)&BlS[cur][wc * 64 + n * 16 + llo][lhi * 8];
    }
#pragma unroll
    for (int m = 0; m < 2; ++m)
#pragma unroll
      for (int n = 0; n < 4; ++n) {
        acc[m][n] = __builtin_amdgcn_mfma_f32_16x16x32_bf16(ah[m], bh[n], acc[m][n], 0, 0, 0);
        acc[m][n] = __builtin_amdgcn_mfma_f32_16x16x32_bf16(ah[m], bl[n], acc[m][n], 0, 0, 0);
        acc[m][n] = __builtin_amdgcn_mfma_f32_16x16x32_bf16(al[m], bh[n], acc[m][n], 0, 0, 0);
      }
    __syncthreads();
    cur ^= 1;
  }

#pragma unroll
  for (int n = 0; n < 4; ++n) {
    const int col = n0 + wc * 64 + n * 16 + llo;
    const float bv = bias ? bias[col] : 0.f;
#pragma unroll
    for (int m = 0; m < 2; ++m) {
      const int rbase = m0 + wr * 32 + m * 16 + lhi * 4;
#pragma unroll
      for (int j = 0; j < 4; ++j) {
        float v = acc[m][n][j] + bv;
        if (RELU) v = fmaxf(v, 0.f);
        const size_t idx = (size_t)(rbase + j) * ldc + col;
        if (OUT_SPLIT) {
          u16 h = f2bf(v);
          Ch[idx] = h;
          Cl[idx] = f2bf(v - bf2f(h));
        } else {
          Cf[idx] = v;
        }
      }
    }
  }
}

// ---------------------------------------------------------------------------
// Split-bf16 MFMA flash attention (PROVEN r5-r7), causal, no 1/sqrt(d).
// ---------------------------------------------------------------------------
__global__ __launch_bounds__(256)
void attn_ms(const float* __restrict__ Q, const float* __restrict__ Kp,
             const float* __restrict__ V, float* __restrict__ O)
{
  __shared__ u16 Ksh[64][72], Ksl[64][72];   // [s][d]
  __shared__ u16 Vsh[64][72], Vsl[64][72];   // [d][s] (transposed)
  __shared__ u16 Pwh[4][16][72], Pwl[4][16][72];  // per-wave P [q_local][s]
  const int tid = threadIdx.x;
  const int lane = tid & 63, w = tid >> 6;
  const int lhi = lane >> 4, llo = lane & 15;
  const int q0 = blockIdx.x * 64;
  const int bh = blockIdx.y;
  const size_t base = (size_t)(bh >> 4) * Tt * Ee + (size_t)(bh & 15) * Dd;

  short8 qh[2], ql[2];
#pragma unroll
  for (int ks = 0; ks < 2; ++ks) {
    const float* qsrc = &Q[base + (size_t)(q0 + w * 16 + llo) * Ee + ks * 32 + lhi * 8];
    float4 a = *(const float4*)qsrc, b2 = *(const float4*)(qsrc + 4);
    float f[8] = {a.x, a.y, a.z, a.w, b2.x, b2.y, b2.z, b2.w};
#pragma unroll
    for (int j = 0; j < 8; ++j) {
      u16 h = f2bf(f[j]);
      qh[ks][j] = (short)h;
      ql[ks][j] = (short)f2bf(f[j] - bf2f(h));
    }
  }

  f32x4 oacc[4] = {};
  float m_run[4], l_run[4];
#pragma unroll
  for (int j = 0; j < 4; ++j) { m_run[j] = -INFINITY; l_run[j] = 0.f; }

  for (int s0 = 0; s0 <= q0; s0 += 64) {
#pragma unroll
    for (int pass = 0; pass < 2; ++pass) {
      int c = tid + 256 * pass;
      int row = c >> 3, d0 = (c & 7) * 8;
      const float* ksrc = &Kp[base + (size_t)(s0 + row) * Ee + d0];
      const float* vsrc = &V[base + (size_t)(s0 + row) * Ee + d0];
      float4 ka = *(const float4*)ksrc, kb2 = *(const float4*)(ksrc + 4);
      float4 va = *(const float4*)vsrc, vb2 = *(const float4*)(vsrc + 4);
      float kf[8] = {ka.x, ka.y, ka.z, ka.w, kb2.x, kb2.y, kb2.z, kb2.w};
      float vf[8] = {va.x, va.y, va.z, va.w, vb2.x, vb2.y, vb2.z, vb2.w};
      short8 khv, klv;
#pragma unroll
      for (int j = 0; j < 8; ++j) {
        u16 h = f2bf(kf[j]);
        khv[j] = (short)h;
        klv[j] = (short)f2bf(kf[j] - bf2f(h));
      }
      *(short8*)&Ksh[row][d0] = khv;
      *(short8*)&Ksl[row][d0] = klv;
#pragma unroll
      for (int j = 0; j < 8; ++j) {
        u16 h = f2bf(vf[j]);
        Vsh[d0 + j][row] = h;
        Vsl[d0 + j][row] = f2bf(vf[j] - bf2f(h));
      }
    }
    __syncthreads();

    f32x4 sacc[4] = {};
#pragma unroll
    for (int ks = 0; ks < 2; ++ks)
#pragma unroll
      for (int n = 0; n < 4; ++n) {
        short8 kh = *(const short8*)&Ksh[n * 16 + llo][ks * 32 + lhi * 8];
        short8 kl = *(const short8*)&Ksl[n * 16 + llo][ks * 32 + lhi * 8];
        sacc[n] = __builtin_amdgcn_mfma_f32_16x16x32_bf16(qh[ks], kh, sacc[n], 0, 0, 0);
        sacc[n] = __builtin_amdgcn_mfma_f32_16x16x32_bf16(qh[ks], kl, sacc[n], 0, 0, 0);
        sacc[n] = __builtin_amdgcn_mfma_f32_16x16x32_bf16(ql[ks], kh, sacc[n], 0, 0, 0);
      }

    if (s0 == q0) {
#pragma unroll
      for (int n = 0; n < 4; ++n)
#pragma unroll
        for (int j = 0; j < 4; ++j)
          if (n * 16 + llo > w * 16 + lhi * 4 + j) sacc[n][j] = -INFINITY;
    }

    float scj[4];
#pragma unroll
    for (int j = 0; j < 4; ++j) {
      float mt = fmaxf(fmaxf(sacc[0][j], sacc[1][j]), fmaxf(sacc[2][j], sacc[3][j]));
#pragma unroll
      for (int off = 1; off < 16; off <<= 1) mt = fmaxf(mt, __shfl_xor(mt, off));
      float mn = fmaxf(m_run[j], mt);
      scj[j] = __expf(m_run[j] - mn);
      m_run[j] = mn;
      float rs = 0.f;
#pragma unroll
      for (int n = 0; n < 4; ++n) {
        float pp = __expf(sacc[n][j] - mn);
        sacc[n][j] = pp;
        rs += pp;
      }
#pragma unroll
      for (int off = 1; off < 16; off <<= 1) rs += __shfl_xor(rs, off);
      l_run[j] = l_run[j] * scj[j] + rs;
    }

#pragma unroll
    for (int n = 0; n < 4; ++n)
#pragma unroll
      for (int j = 0; j < 4; ++j) {
        float pp = sacc[n][j];
        u16 h = f2bf(pp);
        Pwh[w][lhi * 4 + j][n * 16 + llo] = h;
        Pwl[w][lhi * 4 + j][n * 16 + llo] = f2bf(pp - bf2f(h));
      }
#pragma unroll
    for (int df = 0; df < 4; ++df)
#pragma unroll
      for (int j = 0; j < 4; ++j)
        oacc[df][j] *= scj[j];

#pragma unroll
    for (int ks = 0; ks < 2; ++ks) {
      short8 ph = *(const short8*)&Pwh[w][llo][ks * 32 + lhi * 8];
      short8 pl = *(const short8*)&Pwl[w][llo][ks * 32 + lhi * 8];
#pragma unroll
      for (int df = 0; df < 4; ++df) {
        short8 vh = *(const short8*)&Vsh[df * 16 + llo][ks * 32 + lhi * 8];
        short8 vl = *(const short8*)&Vsl[df * 16 + llo][ks * 32 + lhi * 8];
        oacc[df] = __builtin_amdgcn_mfma_f32_16x16x32_bf16(ph, vh, oacc[df], 0, 0, 0);
        oacc[df] = __builtin_amdgcn_mfma_f32_16x16x32_bf16(ph, vl, oacc[df], 0, 0, 0);
        oacc[df] = __builtin_amdgcn_mfma_f32_16x16x32_bf16(pl, vh, oacc[df], 0, 0, 0);
      }
    }
    __syncthreads();
  }

#pragma unroll
  for (int j = 0; j < 4; ++j) {
    float inv = 1.f / l_run[j];
#pragma unroll
    for (int df = 0; df < 4; ++df)
      O[base + (size_t)(q0 + w * 16 + lhi * 4 + j) * Ee + df * 16 + llo] =
          oacc[df][j] * inv;
  }
}

// ---------------------------------------------------------------------------
// Per-head LN over D=64 + residual; writes fp32 + (hi,lo) bf16 streams.
// ---------------------------------------------------------------------------
__global__ __launch_bounds__(256)
void attn_ln_res(const float* __restrict__ O, const float* __restrict__ Yin,
                 const float* __restrict__ g, const float* __restrict__ bta,
                 float* __restrict__ Yout, u16* __restrict__ Yh, u16* __restrict__ Yl)
{
  const int tid = threadIdx.x;
  const int w = (blockIdx.x << 2) + (tid >> 6);
  const int lane = tid & 63;
  const int m = w >> 4;
  const int h = w & 15;
  const size_t idx = (size_t)m * Ee + h * Dd + lane;
  float x = O[idx];
  float s = x, s2 = x * x;
#pragma unroll
  for (int off = 1; off < 64; off <<= 1) {
    s  += __shfl_xor(s, off);
    s2 += __shfl_xor(s2, off);
  }
  float mean = s * (1.f / 64.f);
  float var  = s2 * (1.f / 64.f) - mean * mean;
  float inv  = rsqrtf(var + EPS);
  float r = Yin[idx] + (x - mean) * inv * g[h * Dd + lane] + bta[h * Dd + lane];
  Yout[idx] = r;
  u16 hh = f2bf(r);
  Yh[idx] = hh;
  Yl[idx] = f2bf(r - bf2f(hh));
}

// ---------------------------------------------------------------------------
// Row LN over E=1024 + residual. Input = T0 + T1 + bias (split-K partials).
// Writes fp32 + (hi,lo) bf16 streams.
// ---------------------------------------------------------------------------
__global__ __launch_bounds__(256)
void ff_ln_res(const float* __restrict__ T0, const float* __restrict__ T1,
               const float* __restrict__ b2,
               const float* __restrict__ Yin, const float* __restrict__ g,
               const float* __restrict__ bb,
               float* __restrict__ Yout, u16* __restrict__ Yh, u16* __restrict__ Yl)
{
  __shared__ float red[8];
  const int m = blockIdx.x;
  const int tid = threadIdx.x;
  const size_t basep = (size_t)m * Ee;
  float4 xa = *(const float4*)&T0[basep + (tid << 2)];
  float4 xb = *(const float4*)&T1[basep + (tid << 2)];
  float4 bv2 = *(const float4*)&b2[tid << 2];
  float xv[4] = {xa.x + xb.x + bv2.x, xa.y + xb.y + bv2.y,
                 xa.z + xb.z + bv2.z, xa.w + xb.w + bv2.w};
  float s  = xv[0] + xv[1] + xv[2] + xv[3];
  float s2 = xv[0]*xv[0] + xv[1]*xv[1] + xv[2]*xv[2] + xv[3]*xv[3];
#pragma unroll
  for (int off = 1; off < 64; off <<= 1) {
    s  += __shfl_xor(s, off);
    s2 += __shfl_xor(s2, off);
  }
  const int wid = tid >> 6;
  if ((tid & 63) == 0) { red[wid] = s; red[4 + wid] = s2; }
  __syncthreads();
  s  = red[0] + red[1] + red[2] + red[3];
  s2 = red[4] + red[5] + red[6] + red[7];
  float mean = s * (1.f / Ee);
  float var  = s2 * (1.f / Ee) - mean * mean;
  float inv  = rsqrtf(var + EPS);
  float4 y  = *(const float4*)&Yin[basep + (tid << 2)];
  float4 gg = *(const float4*)&g[tid << 2];
  float4 bv = *(const float4*)&bb[tid << 2];
  float gga[4] = {gg.x, gg.y, gg.z, gg.w};
  float bva[4] = {bv.x, bv.y, bv.z, bv.w};
  float ya[4] = {y.x, y.y, y.z, y.w};
  float o[4];
  u16x4 oh, ol;
#pragma unroll
  for (int j = 0; j < 4; ++j) {
    o[j] = ya[j] + (xv[j] - mean) * inv * gga[j] + bva[j];
    u16 hh = f2bf(o[j]);
    oh[j] = hh;
    ol[j] = f2bf(o[j] - bf2f(hh));
  }
  *(float4*)&Yout[basep + (tid << 2)] = *(float4*)o;
  *(u16x4*)&Yh[basep + (tid << 2)] = oh;
  *(u16x4*)&Yl[basep + (tid << 2)] = ol;
}

// out = p0 + p1 + bias (final linear reduce)
__global__ __launch_bounds__(256)
void add2_bias(const float* __restrict__ p0, const float* __restrict__ p1,
               const float* __restrict__ b, float* __restrict__ out)
{
  const size_t i = ((size_t)blockIdx.x * 256 + threadIdx.x) * 4;
  const int col = (int)(i & (Ee - 1));
  float4 a = *(const float4*)&p0[i];
  float4 c = *(const float4*)&p1[i];
  float4 bb = *(const float4*)&b[col];
  float4 o;
  o.x = a.x + c.x + bb.x; o.y = a.y + c.y + bb.y;
  o.z = a.z + c.z + bb.z; o.w = a.w + c.w + bb.w;
  *(float4*)&out[i] = o;
}

// ---------------------------------------------------------------------------
// fp32 -> (hi,lo) bf16 split, no transpose (activations).
// ---------------------------------------------------------------------------
__global__ __launch_bounds__(256)
void split_act(const float* __restrict__ in, u16* __restrict__ oh, u16* __restrict__ ol)
{
  const size_t i = ((size_t)blockIdx.x * 256 + threadIdx.x) * 4;
  float4 v = *(const float4*)&in[i];
  float f[4] = {v.x, v.y, v.z, v.w};
  u16x4 h4, l4;
#pragma unroll
  for (int j = 0; j < 4; ++j) {
    u16 h = f2bf(f[j]);
    h4[j] = h;
    l4[j] = f2bf(f[j] - bf2f(h));
  }
  *(u16x4*)&oh[i] = h4;
  *(u16x4*)&ol[i] = l4;
}

// ---------------------------------------------------------------------------
// fp32 [R][C] -> bf16 hi/lo [C][R] transpose-split (PROVEN r4-r7).
// ---------------------------------------------------------------------------
__global__ __launch_bounds__(256)
void cvtT_split(const float* __restrict__ in, u16* __restrict__ out_h,
                u16* __restrict__ out_l, int R, int C)
{
  __shared__ float tile[32][33];
  const size_t zo = (size_t)blockIdx.z * R * C;
  const int c0 = blockIdx.x * 32, r0 = blockIdx.y * 32;
  const int tid = threadIdx.x;
  const int ir = tid >> 3, ic = (tid & 7) * 4;
  float4 v = *(const float4*)&in[zo + (size_t)(r0 + ir) * C + c0 + ic];
  tile[ir][ic] = v.x; tile[ir][ic + 1] = v.y;
  tile[ir][ic + 2] = v.z; tile[ir][ic + 3] = v.w;
  __syncthreads();
  const int oc = tid >> 3, orr = (tid & 7) * 4;
  const size_t ob = zo + (size_t)(c0 + oc) * R + r0 + orr;
#pragma unroll
  for (int j = 0; j < 4; ++j) {
    float f = tile[orr + j][oc];
    u16 h = f2bf(f);
    out_h[ob + j] = h;
    out_l[ob + j] = f2bf(f - bf2f(h));
  }
}

// ---------------------------------------------------------------------------
extern "C" void kernel_launch(void* const* d_in, const int* in_sizes, int n_in,
                              void* d_out, int out_size, void* d_ws, size_t ws_size,
                              hipStream_t stream)
{
  const float* x     = (const float*)d_in[0];
  const float* mh_wq = (const float*)d_in[1];
  const float* mh_wk = (const float*)d_in[2];
  const float* mh_wv = (const float*)d_in[3];
  const float* mh_g  = (const float*)d_in[4];
  const float* mh_b  = (const float*)d_in[5];
  const float* ff_w1 = (const float*)d_in[6];
  const float* ff_b1 = (const float*)d_in[7];
  const float* ff_w2 = (const float*)d_in[8];
  const float* ff_b2 = (const float*)d_in[9];
  const float* ff_g  = (const float*)d_in[10];
  const float* ff_bb = (const float*)d_in[11];
  const float* lt_w  = (const float*)d_in[12];
  const float* lt_b  = (const float*)d_in[13];
  float* out = (float*)d_out;

  const size_t ME = (size_t)Mm * Ee;   // 2M elements
  char* p = (char*)d_ws;
  auto alloc = [&](size_t bytes) { void* r = (void*)p; p += (bytes + 255) & ~(size_t)255; return r; };
  float* bufA  = (float*)alloc(ME * 4);                // 8 MB
  u16*   bufAh = (u16*)alloc(ME * 2);                  // 4 MB
  u16*   bufAl = (u16*)alloc(ME * 2);                  // 4 MB
  float* bufB  = (float*)alloc(ME * 4);                // 8 MB
  u16*   bufBh = (u16*)alloc(ME * 2);                  // 4 MB
  u16*   bufBl = (u16*)alloc(ME * 2);                  // 4 MB
  u16*   wt_h  = (u16*)alloc((size_t)Ff * Ee * 2);     // 8 MB (also QKV 3x1M slabs)
  u16*   wt_l  = (u16*)alloc((size_t)Ff * Ee * 2);     // 8 MB
  float* reg   = (float*)alloc((size_t)10 * 1024 * 1024 * 4);  // 40 MB union
  float* qb    = reg;                          // mh phase
  float* kb    = reg + 2 * 1024 * 1024;
  float* vb    = reg + 4 * 1024 * 1024;
  float* ob    = reg + 6 * 1024 * 1024;
  u16*   hidh  = (u16*)reg;                    // ff phase (aliases qb..ob)
  u16*   hidl  = (u16*)(reg + 4 * 1024 * 1024);
  float* tmp   = reg + 8 * 1024 * 1024;

  auto mh = [&](int i, const float* srcF, const u16* srcH, const u16* srcL,
                float* dstF, u16* dstH, u16* dstL) {
    const size_t wo = (size_t)i * Hh * Ee * Dd;
    cvtT_split<<<dim3(Dd / 32, Ee / 32, Hh), 256, 0, stream>>>(mh_wq + wo, wt_h, wt_l, Ee, Dd);
    cvtT_split<<<dim3(Dd / 32, Ee / 32, Hh), 256, 0, stream>>>(mh_wk + wo, wt_h + (1u << 20), wt_l + (1u << 20), Ee, Dd);
    cvtT_split<<<dim3(Dd / 32, Ee / 32, Hh), 256, 0, stream>>>(mh_wv + wo, wt_h + (2u << 20), wt_l + (2u << 20), Ee, Dd);
    gemm_ps<false, false, false, true, false><<<dim3(24, Mm / 64), 256, 0, stream>>>(
        srcH, srcL, nullptr, nullptr, wt_h, wt_l, nullptr,
        qb, kb, vb, nullptr, nullptr, Ee, Ee);
    attn_ms<<<dim3(Tt / 64, Bb * Hh), 256, 0, stream>>>(qb, kb, vb, ob);
    attn_ln_res<<<dim3(Mm * Hh / 4), 256, 0, stream>>>(
        ob, srcF, mh_g + (size_t)i * Hh * Dd, mh_b + (size_t)i * Hh * Dd, dstF, dstH, dstL);
  };
  // tmp1: fp32 scratch [M,E] for the z=1 split-K partial (a dead buffer).
  auto ff = [&](int i, const float* srcF, const u16* srcH, const u16* srcL,
                float* dstF, u16* dstH, u16* dstL, float* tmp1) {
    cvtT_split<<<dim3(Ff / 32, Ee / 32, 1), 256, 0, stream>>>(ff_w1 + (size_t)i * Ee * Ff, wt_h, wt_l, Ee, Ff);
    gemm_ps<false, true, true, false, false><<<dim3(Ff / 128, Mm / 64), 256, 0, stream>>>(
        srcH, srcL, nullptr, nullptr, wt_h, wt_l, ff_b1 + (size_t)i * Ff,
        nullptr, nullptr, nullptr, hidh, hidl, Ff, Ee);
    cvtT_split<<<dim3(Ee / 32, Ff / 32, 1), 256, 0, stream>>>(ff_w2 + (size_t)i * Ff * Ee, wt_h, wt_l, Ff, Ee);
    gemm_ps<false, false, false, false, true><<<dim3(Ee / 128, Mm / 64, 2), 256, 0, stream>>>(
        hidh, hidl, nullptr, nullptr, wt_h, wt_l, nullptr,
        tmp, tmp1, nullptr, nullptr, nullptr, Ee, Ff);
    ff_ln_res<<<dim3(Mm), 256, 0, stream>>>(
        tmp, tmp1, ff_b2 + (size_t)i * Ee,
        srcF, ff_g + (size_t)i * Ee, ff_bb + (size_t)i * Ee, dstF, dstH, dstL);
  };

  // out_one branch: ff(3, mh(4, mh(0, x)))   [bufB fp32 dead -> tmp1]
  split_act<<<dim3(ME / 1024), 256, 0, stream>>>(x, bufAh, bufAl);
  mh(0, x, bufAh, bufAl, bufA, bufAh, bufAl);
  mh(4, bufA, bufAh, bufAl, bufA, bufAh, bufAl);
  ff(3, bufA, bufAh, bufAl, bufA, bufAh, bufAl, bufB);

  // out_two branch: 3 encoder blocks then decoder  [bufA fp32 dead -> tmp1]
  split_act<<<dim3(ME / 1024), 256, 0, stream>>>(x, bufBh, bufBl);
  mh(1, x, bufBh, bufBl, bufB, bufBh, bufBl);
  ff(0, bufB, bufBh, bufBl, bufB, bufBh, bufBl, bufA);
  mh(2, bufB, bufBh, bufBl, bufB, bufBh, bufBl);
  ff(1, bufB, bufBh, bufBl, bufB, bufBh, bufBl, bufA);
  mh(3, bufB, bufBh, bufBl, bufB, bufBh, bufBl);
  ff(2, bufB, bufBh, bufBl, bufB, bufBh, bufBl, bufA);
  mh(4, bufB, bufBh, bufBl, bufB, bufBh, bufBl);
  ff(3, bufB, bufBh, bufBl, bufB, bufBh, bufBl, bufA);

  // final: out = concat(A,B) @ lt_w + lt_b, split-K=2 into dead bufA/bufB
  cvtT_split<<<dim3(Ee / 32, 2 * Ee / 32, 1), 256, 0, stream>>>(lt_w, wt_h, wt_l, 2 * Ee, Ee);
  gemm_ps<true, false, false, false, true><<<dim3(Ee / 128, Mm / 64, 2), 256, 0, stream>>>(
      bufAh, bufAl, bufBh, bufBl, wt_h, wt_l, nullptr,
      bufA, bufB, nullptr, nullptr, nullptr, Ee, 2 * Ee);
  add2_bias<<<dim3(ME / 1024), 256, 0, stream>>>(bufA, bufB, lt_b, out);
}

// Round 9
// 1434.379 us; speedup vs baseline: 3.2617x; 1.0478x over previous
//
#include <hip/hip_runtime.h>
#include <math.h>

#define Bb 4
#define Tt 512
#define Ee 1024
#define Hh 16
#define Dd 64
#define Ff 4096
#define Mm (Bb*Tt)   // 2048
static constexpr float EPS = 1e-5f;

typedef __attribute__((ext_vector_type(8))) short short8;   // 8 bf16 (4 VGPR)
typedef __attribute__((ext_vector_type(4))) float f32x4;
typedef unsigned short u16;
typedef __attribute__((ext_vector_type(4))) u16 u16x4;

__device__ __forceinline__ u16 f2bf(float f) {
  unsigned u = __builtin_bit_cast(unsigned, f);
  return (u16)((u + 0x7fffu + ((u >> 16) & 1u)) >> 16);   // RNE
}
__device__ __forceinline__ float bf2f(u16 h) {
  unsigned u = (unsigned)h << 16;
  return __builtin_bit_cast(float, u);
}
// async global->LDS, 16B per lane. LDS dest must be lane-linear.
__device__ __forceinline__ void gload16(const void* g, void* l) {
  __builtin_amdgcn_global_load_lds(
      (const __attribute__((address_space(1))) unsigned int*)g,
      (__attribute__((address_space(3))) unsigned int*)l, 16, 0, 0);
}

// ---------------------------------------------------------------------------
// m97-structure split GEMM for FF1: 128x128 tile, 4 waves (2x2), wave 64x64,
// BK=32, SINGLE-buffer 32KB LDS, global_load_lds staging.
// Per K-step/wave: 16 ds_read_b128, 48 MFMA (3:1). A,W pre-split h/l.
// Epilogue: bias + relu + split (hi,lo) output.
// ---------------------------------------------------------------------------
__global__ __launch_bounds__(256)
void gemm_128(const u16* __restrict__ Ah_g, const u16* __restrict__ Al_g,
              const u16* __restrict__ Wh, const u16* __restrict__ Wl,
              const float* __restrict__ bias,
              u16* __restrict__ Ch, u16* __restrict__ Cl, int ldc, int K)
{
  __shared__ u16 AhS[128][32], AlS[128][32], BhS[128][32], BlS[128][32];
  const int tid = threadIdx.x;
  const int lane = tid & 63, w = tid >> 6;
  const int wr = w >> 1, wc = w & 1;
  const int lhi = lane >> 4, llo = lane & 15;
  const int n0 = blockIdx.x * 128, m0 = blockIdx.y * 128;
  const int s_row = tid >> 2, s_ko = (tid & 3) * 8;   // LDS byte = tid*16 (+pass*4096)

  f32x4 acc[4][4] = {};

  for (int k0 = 0; k0 < K; k0 += 32) {
#pragma unroll
    for (int i = 0; i < 2; ++i) {
      const int row = s_row + i * 64;
      const size_t ga = (size_t)(m0 + row) * K + k0 + s_ko;
      gload16(&Ah_g[ga], &AhS[row][s_ko]);
      gload16(&Al_g[ga], &AlS[row][s_ko]);
      const size_t gb = (size_t)(n0 + row) * K + k0 + s_ko;
      gload16(&Wh[gb], &BhS[row][s_ko]);
      gload16(&Wl[gb], &BlS[row][s_ko]);
    }
    __syncthreads();
    short8 ah[4], al[4], bh[4], bl[4];
#pragma unroll
    for (int f = 0; f < 4; ++f) {
      ah[f] = *(const short8*)&AhS[wr * 64 + f * 16 + llo][lhi * 8];
      al[f] = *(const short8*)&AlS[wr * 64 + f * 16 + llo][lhi * 8];
      bh[f] = *(const short8*)&BhS[wc * 64 + f * 16 + llo][lhi * 8];
      bl[f] = *(const short8*)&BlS[wc * 64 + f * 16 + llo][lhi * 8];
    }
#pragma unroll
    for (int m = 0; m < 4; ++m)
#pragma unroll
      for (int n = 0; n < 4; ++n) {
        acc[m][n] = __builtin_amdgcn_mfma_f32_16x16x32_bf16(ah[m], bh[n], acc[m][n], 0, 0, 0);
        acc[m][n] = __builtin_amdgcn_mfma_f32_16x16x32_bf16(ah[m], bl[n], acc[m][n], 0, 0, 0);
        acc[m][n] = __builtin_amdgcn_mfma_f32_16x16x32_bf16(al[m], bh[n], acc[m][n], 0, 0, 0);
      }
    __syncthreads();
  }

#pragma unroll
  for (int n = 0; n < 4; ++n) {
    const int col = n0 + wc * 64 + n * 16 + llo;
    const float bv = bias[col];
#pragma unroll
    for (int m = 0; m < 4; ++m) {
      const int rbase = m0 + wr * 64 + m * 16 + lhi * 4;
#pragma unroll
      for (int j = 0; j < 4; ++j) {
        float v = fmaxf(acc[m][n][j] + bv, 0.f);   // ReLU
        const size_t idx = (size_t)(rbase + j) * ldc + col;
        u16 h = f2bf(v);
        Ch[idx] = h;
        Cl[idx] = f2bf(v - bf2f(h));
      }
    }
  }
}

// ---------------------------------------------------------------------------
// Pre-split bf16 MFMA GEMM (PROVEN r8): 64x128 tile, dbuf, gload_lds.
// ---------------------------------------------------------------------------
template<bool CONCAT, bool RELU, bool OUT_SPLIT, bool QKV, bool SPLITK>
__global__ __launch_bounds__(256)
void gemm_ps(const u16* __restrict__ Ah_g, const u16* __restrict__ Al_g,
             const u16* __restrict__ A2h, const u16* __restrict__ A2l,
             const u16* __restrict__ Wh, const u16* __restrict__ Wl,
             const float* __restrict__ bias,
             float* __restrict__ Cf, float* __restrict__ Cf1, float* __restrict__ Cf2,
             u16* __restrict__ Ch, u16* __restrict__ Cl,
             int ldc, int K)
{
  __shared__ u16 AhS[2][64][32], AlS[2][64][32];
  __shared__ u16 BhS[2][128][32], BlS[2][128][32];
  const int tid = threadIdx.x;
  const int lane = tid & 63;
  const int w = tid >> 6;
  const int wr = w >> 1, wc = w & 1;
  const int lhi = lane >> 4, llo = lane & 15;
  int n0;
  if (QKV) {
    const int sec = blockIdx.x >> 3;
    n0 = (blockIdx.x & 7) * 128;
    Wh += (size_t)sec << 20;
    Wl += (size_t)sec << 20;
    if (sec == 1) Cf = Cf1; else if (sec == 2) Cf = Cf2;
  } else {
    n0 = blockIdx.x * 128;
  }
  const int m0 = blockIdx.y * 64;
  int kbeg = 0, nt = K / 32;
  if (SPLITK) {
    const int half = K >> 1;
    kbeg = blockIdx.z * half;
    nt = half / 32;
    if (blockIdx.z == 1) Cf = Cf1;
  }

  const int s_row = tid >> 2, s_ko = (tid & 3) * 8;

  auto stage = [&](int k0, int buf) {
    const int gk = k0 + s_ko;
    const u16 *sh = Ah_g, *sl = Al_g;
    size_t g;
    if (CONCAT) {
      if (gk < Ee) { g = (size_t)(m0 + s_row) * Ee + gk; }
      else { g = (size_t)(m0 + s_row) * Ee + (gk - Ee); sh = A2h; sl = A2l; }
    } else {
      g = (size_t)(m0 + s_row) * K + gk;
    }
    gload16(&sh[g], &AhS[buf][s_row][s_ko]);
    gload16(&sl[g], &AlS[buf][s_row][s_ko]);
#pragma unroll
    for (int i = 0; i < 2; ++i) {
      size_t gb = (size_t)(n0 + s_row + i * 64) * K + gk;
      gload16(&Wh[gb], &BhS[buf][s_row + i * 64][s_ko]);
      gload16(&Wl[gb], &BlS[buf][s_row + i * 64][s_ko]);
    }
  };

  f32x4 acc[2][4] = {};
  stage(kbeg, 0);
  __syncthreads();
  int cur = 0;
  for (int t = 0; t < nt; ++t) {
    if (t + 1 < nt) stage(kbeg + (t + 1) * 32, cur ^ 1);
    short8 ah[2], al[2], bh[4], bl[4];
#pragma unroll
    for (int m = 0; m < 2; ++m) {
      ah[m] = *(const short8*)&AhS[cur][wr * 32 + m * 16 + llo][lhi * 8];
      al[m] = *(const short8*)&AlS[cur][wr * 32 + m * 16 + llo][lhi * 8];
    }
#pragma unroll
    for (int n = 0; n < 4; ++n) {
      bh[n] = *(const short8*)&BhS[cur][wc * 64 + n * 16 + llo][lhi * 8];
      bl[n] = *(const short8*)&BlS[cur][wc * 64 + n * 16 + llo][lhi * 8];
    }
#pragma unroll
    for (int m = 0; m < 2; ++m)
#pragma unroll
      for (int n = 0; n < 4; ++n) {
        acc[m][n] = __builtin_amdgcn_mfma_f32_16x16x32_bf16(ah[m], bh[n], acc[m][n], 0, 0, 0);
        acc[m][n] = __builtin_amdgcn_mfma_f32_16x16x32_bf16(ah[m], bl[n], acc[m][n], 0, 0, 0);
        acc[m][n] = __builtin_amdgcn_mfma_f32_16x16x32_bf16(al[m], bh[n], acc[m][n], 0, 0, 0);
      }
    __syncthreads();
    cur ^= 1;
  }

#pragma unroll
  for (int n = 0; n < 4; ++n) {
    const int col = n0 + wc * 64 + n * 16 + llo;
    const float bv = bias ? bias[col] : 0.f;
#pragma unroll
    for (int m = 0; m < 2; ++m) {
      const int rbase = m0 + wr * 32 + m * 16 + lhi * 4;
#pragma unroll
      for (int j = 0; j < 4; ++j) {
        float v = acc[m][n][j] + bv;
        if (RELU) v = fmaxf(v, 0.f);
        const size_t idx = (size_t)(rbase + j) * ldc + col;
        if (OUT_SPLIT) {
          u16 h = f2bf(v);
          Ch[idx] = h;
          Cl[idx] = f2bf(v - bf2f(h));
        } else {
          Cf[idx] = v;
        }
      }
    }
  }
}

// ---------------------------------------------------------------------------
// Split-bf16 MFMA flash attention (PROVEN r5-r8), causal, no 1/sqrt(d).
// ---------------------------------------------------------------------------
__global__ __launch_bounds__(256)
void attn_ms(const float* __restrict__ Q, const float* __restrict__ Kp,
             const float* __restrict__ V, float* __restrict__ O)
{
  __shared__ u16 Ksh[64][72], Ksl[64][72];   // [s][d]
  __shared__ u16 Vsh[64][72], Vsl[64][72];   // [d][s] (transposed)
  __shared__ u16 Pwh[4][16][72], Pwl[4][16][72];  // per-wave P [q_local][s]
  const int tid = threadIdx.x;
  const int lane = tid & 63, w = tid >> 6;
  const int lhi = lane >> 4, llo = lane & 15;
  const int q0 = blockIdx.x * 64;
  const int bh = blockIdx.y;
  const size_t base = (size_t)(bh >> 4) * Tt * Ee + (size_t)(bh & 15) * Dd;

  short8 qh[2], ql[2];
#pragma unroll
  for (int ks = 0; ks < 2; ++ks) {
    const float* qsrc = &Q[base + (size_t)(q0 + w * 16 + llo) * Ee + ks * 32 + lhi * 8];
    float4 a = *(const float4*)qsrc, b2 = *(const float4*)(qsrc + 4);
    float f[8] = {a.x, a.y, a.z, a.w, b2.x, b2.y, b2.z, b2.w};
#pragma unroll
    for (int j = 0; j < 8; ++j) {
      u16 h = f2bf(f[j]);
      qh[ks][j] = (short)h;
      ql[ks][j] = (short)f2bf(f[j] - bf2f(h));
    }
  }

  f32x4 oacc[4] = {};
  float m_run[4], l_run[4];
#pragma unroll
  for (int j = 0; j < 4; ++j) { m_run[j] = -INFINITY; l_run[j] = 0.f; }

  for (int s0 = 0; s0 <= q0; s0 += 64) {
#pragma unroll
    for (int pass = 0; pass < 2; ++pass) {
      int c = tid + 256 * pass;
      int row = c >> 3, d0 = (c & 7) * 8;
      const float* ksrc = &Kp[base + (size_t)(s0 + row) * Ee + d0];
      const float* vsrc = &V[base + (size_t)(s0 + row) * Ee + d0];
      float4 ka = *(const float4*)ksrc, kb2 = *(const float4*)(ksrc + 4);
      float4 va = *(const float4*)vsrc, vb2 = *(const float4*)(vsrc + 4);
      float kf[8] = {ka.x, ka.y, ka.z, ka.w, kb2.x, kb2.y, kb2.z, kb2.w};
      float vf[8] = {va.x, va.y, va.z, va.w, vb2.x, vb2.y, vb2.z, vb2.w};
      short8 khv, klv;
#pragma unroll
      for (int j = 0; j < 8; ++j) {
        u16 h = f2bf(kf[j]);
        khv[j] = (short)h;
        klv[j] = (short)f2bf(kf[j] - bf2f(h));
      }
      *(short8*)&Ksh[row][d0] = khv;
      *(short8*)&Ksl[row][d0] = klv;
#pragma unroll
      for (int j = 0; j < 8; ++j) {
        u16 h = f2bf(vf[j]);
        Vsh[d0 + j][row] = h;
        Vsl[d0 + j][row] = f2bf(vf[j] - bf2f(h));
      }
    }
    __syncthreads();

    f32x4 sacc[4] = {};
#pragma unroll
    for (int ks = 0; ks < 2; ++ks)
#pragma unroll
      for (int n = 0; n < 4; ++n) {
        short8 kh = *(const short8*)&Ksh[n * 16 + llo][ks * 32 + lhi * 8];
        short8 kl = *(const short8*)&Ksl[n * 16 + llo][ks * 32 + lhi * 8];
        sacc[n] = __builtin_amdgcn_mfma_f32_16x16x32_bf16(qh[ks], kh, sacc[n], 0, 0, 0);
        sacc[n] = __builtin_amdgcn_mfma_f32_16x16x32_bf16(qh[ks], kl, sacc[n], 0, 0, 0);
        sacc[n] = __builtin_amdgcn_mfma_f32_16x16x32_bf16(ql[ks], kh, sacc[n], 0, 0, 0);
      }

    if (s0 == q0) {
#pragma unroll
      for (int n = 0; n < 4; ++n)
#pragma unroll
        for (int j = 0; j < 4; ++j)
          if (n * 16 + llo > w * 16 + lhi * 4 + j) sacc[n][j] = -INFINITY;
    }

    float scj[4];
#pragma unroll
    for (int j = 0; j < 4; ++j) {
      float mt = fmaxf(fmaxf(sacc[0][j], sacc[1][j]), fmaxf(sacc[2][j], sacc[3][j]));
#pragma unroll
      for (int off = 1; off < 16; off <<= 1) mt = fmaxf(mt, __shfl_xor(mt, off));
      float mn = fmaxf(m_run[j], mt);
      scj[j] = __expf(m_run[j] - mn);
      m_run[j] = mn;
      float rs = 0.f;
#pragma unroll
      for (int n = 0; n < 4; ++n) {
        float pp = __expf(sacc[n][j] - mn);
        sacc[n][j] = pp;
        rs += pp;
      }
#pragma unroll
      for (int off = 1; off < 16; off <<= 1) rs += __shfl_xor(rs, off);
      l_run[j] = l_run[j] * scj[j] + rs;
    }

#pragma unroll
    for (int n = 0; n < 4; ++n)
#pragma unroll
      for (int j = 0; j < 4; ++j) {
        float pp = sacc[n][j];
        u16 h = f2bf(pp);
        Pwh[w][lhi * 4 + j][n * 16 + llo] = h;
        Pwl[w][lhi * 4 + j][n * 16 + llo] = f2bf(pp - bf2f(h));
      }
#pragma unroll
    for (int df = 0; df < 4; ++df)
#pragma unroll
      for (int j = 0; j < 4; ++j)
        oacc[df][j] *= scj[j];

#pragma unroll
    for (int ks = 0; ks < 2; ++ks) {
      short8 ph = *(const short8*)&Pwh[w][llo][ks * 32 + lhi * 8];
      short8 pl = *(const short8*)&Pwl[w][llo][ks * 32 + lhi * 8];
#pragma unroll
      for (int df = 0; df < 4; ++df) {
        short8 vh = *(const short8*)&Vsh[df * 16 + llo][ks * 32 + lhi * 8];
        short8 vl = *(const short8*)&Vsl[df * 16 + llo][ks * 32 + lhi * 8];
        oacc[df] = __builtin_amdgcn_mfma_f32_16x16x32_bf16(ph, vh, oacc[df], 0, 0, 0);
        oacc[df] = __builtin_amdgcn_mfma_f32_16x16x32_bf16(ph, vl, oacc[df], 0, 0, 0);
        oacc[df] = __builtin_amdgcn_mfma_f32_16x16x32_bf16(pl, vh, oacc[df], 0, 0, 0);
      }
    }
    __syncthreads();
  }

#pragma unroll
  for (int j = 0; j < 4; ++j) {
    float inv = 1.f / l_run[j];
#pragma unroll
    for (int df = 0; df < 4; ++df)
      O[base + (size_t)(q0 + w * 16 + lhi * 4 + j) * Ee + df * 16 + llo] =
          oacc[df][j] * inv;
  }
}

// ---------------------------------------------------------------------------
// Per-head LN over D=64 + residual; writes fp32 + (hi,lo) bf16 streams.
// ---------------------------------------------------------------------------
__global__ __launch_bounds__(256)
void attn_ln_res(const float* __restrict__ O, const float* __restrict__ Yin,
                 const float* __restrict__ g, const float* __restrict__ bta,
                 float* __restrict__ Yout, u16* __restrict__ Yh, u16* __restrict__ Yl)
{
  const int tid = threadIdx.x;
  const int w = (blockIdx.x << 2) + (tid >> 6);
  const int lane = tid & 63;
  const int m = w >> 4;
  const int h = w & 15;
  const size_t idx = (size_t)m * Ee + h * Dd + lane;
  float x = O[idx];
  float s = x, s2 = x * x;
#pragma unroll
  for (int off = 1; off < 64; off <<= 1) {
    s  += __shfl_xor(s, off);
    s2 += __shfl_xor(s2, off);
  }
  float mean = s * (1.f / 64.f);
  float var  = s2 * (1.f / 64.f) - mean * mean;
  float inv  = rsqrtf(var + EPS);
  float r = Yin[idx] + (x - mean) * inv * g[h * Dd + lane] + bta[h * Dd + lane];
  Yout[idx] = r;
  u16 hh = f2bf(r);
  Yh[idx] = hh;
  Yl[idx] = f2bf(r - bf2f(hh));
}

// ---------------------------------------------------------------------------
// Row LN over E=1024 + residual. Input = T0 + T1 + bias (split-K partials).
// ---------------------------------------------------------------------------
__global__ __launch_bounds__(256)
void ff_ln_res(const float* __restrict__ T0, const float* __restrict__ T1,
               const float* __restrict__ b2,
               const float* __restrict__ Yin, const float* __restrict__ g,
               const float* __restrict__ bb,
               float* __restrict__ Yout, u16* __restrict__ Yh, u16* __restrict__ Yl)
{
  __shared__ float red[8];
  const int m = blockIdx.x;
  const int tid = threadIdx.x;
  const size_t basep = (size_t)m * Ee;
  float4 xa = *(const float4*)&T0[basep + (tid << 2)];
  float4 xb = *(const float4*)&T1[basep + (tid << 2)];
  float4 bv2 = *(const float4*)&b2[tid << 2];
  float xv[4] = {xa.x + xb.x + bv2.x, xa.y + xb.y + bv2.y,
                 xa.z + xb.z + bv2.z, xa.w + xb.w + bv2.w};
  float s  = xv[0] + xv[1] + xv[2] + xv[3];
  float s2 = xv[0]*xv[0] + xv[1]*xv[1] + xv[2]*xv[2] + xv[3]*xv[3];
#pragma unroll
  for (int off = 1; off < 64; off <<= 1) {
    s  += __shfl_xor(s, off);
    s2 += __shfl_xor(s2, off);
  }
  const int wid = tid >> 6;
  if ((tid & 63) == 0) { red[wid] = s; red[4 + wid] = s2; }
  __syncthreads();
  s  = red[0] + red[1] + red[2] + red[3];
  s2 = red[4] + red[5] + red[6] + red[7];
  float mean = s * (1.f / Ee);
  float var  = s2 * (1.f / Ee) - mean * mean;
  float inv  = rsqrtf(var + EPS);
  float4 y  = *(const float4*)&Yin[basep + (tid << 2)];
  float4 gg = *(const float4*)&g[tid << 2];
  float4 bv = *(const float4*)&bb[tid << 2];
  float gga[4] = {gg.x, gg.y, gg.z, gg.w};
  float bva[4] = {bv.x, bv.y, bv.z, bv.w};
  float ya[4] = {y.x, y.y, y.z, y.w};
  float o[4];
  u16x4 oh, ol;
#pragma unroll
  for (int j = 0; j < 4; ++j) {
    o[j] = ya[j] + (xv[j] - mean) * inv * gga[j] + bva[j];
    u16 hh = f2bf(o[j]);
    oh[j] = hh;
    ol[j] = f2bf(o[j] - bf2f(hh));
  }
  *(float4*)&Yout[basep + (tid << 2)] = *(float4*)o;
  *(u16x4*)&Yh[basep + (tid << 2)] = oh;
  *(u16x4*)&Yl[basep + (tid << 2)] = ol;
}

// out = p0 + p1 + bias (final linear reduce)
__global__ __launch_bounds__(256)
void add2_bias(const float* __restrict__ p0, const float* __restrict__ p1,
               const float* __restrict__ b, float* __restrict__ out)
{
  const size_t i = ((size_t)blockIdx.x * 256 + threadIdx.x) * 4;
  const int col = (int)(i & (Ee - 1));
  float4 a = *(const float4*)&p0[i];
  float4 c = *(const float4*)&p1[i];
  float4 bb = *(const float4*)&b[col];
  float4 o;
  o.x = a.x + c.x + bb.x; o.y = a.y + c.y + bb.y;
  o.z = a.z + c.z + bb.z; o.w = a.w + c.w + bb.w;
  *(float4*)&out[i] = o;
}

// ---------------------------------------------------------------------------
// fp32 -> (hi,lo) bf16 split, no transpose (activations).
// ---------------------------------------------------------------------------
__global__ __launch_bounds__(256)
void split_act(const float* __restrict__ in, u16* __restrict__ oh, u16* __restrict__ ol)
{
  const size_t i = ((size_t)blockIdx.x * 256 + threadIdx.x) * 4;
  float4 v = *(const float4*)&in[i];
  float f[4] = {v.x, v.y, v.z, v.w};
  u16x4 h4, l4;
#pragma unroll
  for (int j = 0; j < 4; ++j) {
    u16 h = f2bf(f[j]);
    h4[j] = h;
    l4[j] = f2bf(f[j] - bf2f(h));
  }
  *(u16x4*)&oh[i] = h4;
  *(u16x4*)&ol[i] = l4;
}

// ---------------------------------------------------------------------------
// fp32 [R][C] -> bf16 hi/lo [C][R] transpose-split (PROVEN r4-r8).
// ---------------------------------------------------------------------------
__global__ __launch_bounds__(256)
void cvtT_split(const float* __restrict__ in, u16* __restrict__ out_h,
                u16* __restrict__ out_l, int R, int C)
{
  __shared__ float tile[32][33];
  const size_t zo = (size_t)blockIdx.z * R * C;
  const int c0 = blockIdx.x * 32, r0 = blockIdx.y * 32;
  const int tid = threadIdx.x;
  const int ir = tid >> 3, ic = (tid & 7) * 4;
  float4 v = *(const float4*)&in[zo + (size_t)(r0 + ir) * C + c0 + ic];
  tile[ir][ic] = v.x; tile[ir][ic + 1] = v.y;
  tile[ir][ic + 2] = v.z; tile[ir][ic + 3] = v.w;
  __syncthreads();
  const int oc = tid >> 3, orr = (tid & 7) * 4;
  const size_t ob = zo + (size_t)(c0 + oc) * R + r0 + orr;
#pragma unroll
  for (int j = 0; j < 4; ++j) {
    float f = tile[orr + j][oc];
    u16 h = f2bf(f);
    out_h[ob + j] = h;
    out_l[ob + j] = f2bf(f - bf2f(h));
  }
}

// ---------------------------------------------------------------------------
// Fused QKV weight transpose-split: z = sec*16 + head; sec selects wq/wk/wv.
// Each head matrix is [Ee][Dd] -> out [Dd][Ee]-per-head at slab sec<<20.
// ---------------------------------------------------------------------------
__global__ __launch_bounds__(256)
void cvtT_qkv(const float* __restrict__ wq, const float* __restrict__ wk,
              const float* __restrict__ wv, u16* __restrict__ out_h,
              u16* __restrict__ out_l)
{
  __shared__ float tile[32][33];
  const int z = blockIdx.z, sec = z >> 4, hh = z & 15;
  const float* in = (sec == 0) ? wq : (sec == 1) ? wk : wv;
  const size_t zi = (size_t)hh * Ee * Dd;
  const size_t zo = ((size_t)sec << 20) + (size_t)hh * Ee * Dd;
  const int c0 = blockIdx.x * 32, r0 = blockIdx.y * 32;
  const int tid = threadIdx.x;
  const int ir = tid >> 3, ic = (tid & 7) * 4;
  float4 v = *(const float4*)&in[zi + (size_t)(r0 + ir) * Dd + c0 + ic];
  tile[ir][ic] = v.x; tile[ir][ic + 1] = v.y;
  tile[ir][ic + 2] = v.z; tile[ir][ic + 3] = v.w;
  __syncthreads();
  const int oc = tid >> 3, orr = (tid & 7) * 4;
  const size_t ob = zo + (size_t)(c0 + oc) * Ee + r0 + orr;
#pragma unroll
  for (int j = 0; j < 4; ++j) {
    float f = tile[orr + j][oc];
    u16 h = f2bf(f);
    out_h[ob + j] = h;
    out_l[ob + j] = f2bf(f - bf2f(h));
  }
}

// ---------------------------------------------------------------------------
extern "C" void kernel_launch(void* const* d_in, const int* in_sizes, int n_in,
                              void* d_out, int out_size, void* d_ws, size_t ws_size,
                              hipStream_t stream)
{
  const float* x     = (const float*)d_in[0];
  const float* mh_wq = (const float*)d_in[1];
  const float* mh_wk = (const float*)d_in[2];
  const float* mh_wv = (const float*)d_in[3];
  const float* mh_g  = (const float*)d_in[4];
  const float* mh_b  = (const float*)d_in[5];
  const float* ff_w1 = (const float*)d_in[6];
  const float* ff_b1 = (const float*)d_in[7];
  const float* ff_w2 = (const float*)d_in[8];
  const float* ff_b2 = (const float*)d_in[9];
  const float* ff_g  = (const float*)d_in[10];
  const float* ff_bb = (const float*)d_in[11];
  const float* lt_w  = (const float*)d_in[12];
  const float* lt_b  = (const float*)d_in[13];
  float* out = (float*)d_out;

  const size_t ME = (size_t)Mm * Ee;   // 2M elements
  char* p = (char*)d_ws;
  auto alloc = [&](size_t bytes) { void* r = (void*)p; p += (bytes + 255) & ~(size_t)255; return r; };
  float* bufA  = (float*)alloc(ME * 4);                // 8 MB
  u16*   bufAh = (u16*)alloc(ME * 2);                  // 4 MB
  u16*   bufAl = (u16*)alloc(ME * 2);                  // 4 MB
  float* bufB  = (float*)alloc(ME * 4);                // 8 MB
  u16*   bufBh = (u16*)alloc(ME * 2);                  // 4 MB
  u16*   bufBl = (u16*)alloc(ME * 2);                  // 4 MB
  u16*   wt_h  = (u16*)alloc((size_t)Ff * Ee * 2);     // 8 MB (also QKV 3x1M slabs)
  u16*   wt_l  = (u16*)alloc((size_t)Ff * Ee * 2);     // 8 MB
  float* reg   = (float*)alloc((size_t)10 * 1024 * 1024 * 4);  // 40 MB union
  float* qb    = reg;                          // mh phase
  float* kb    = reg + 2 * 1024 * 1024;
  float* vb    = reg + 4 * 1024 * 1024;
  float* ob    = reg + 6 * 1024 * 1024;
  u16*   hidh  = (u16*)reg;                    // ff phase (aliases qb..ob)
  u16*   hidl  = (u16*)(reg + 4 * 1024 * 1024);
  float* tmp   = reg + 8 * 1024 * 1024;

  auto mh = [&](int i, const float* srcF, const u16* srcH, const u16* srcL,
                float* dstF, u16* dstH, u16* dstL) {
    const size_t wo = (size_t)i * Hh * Ee * Dd;
    cvtT_qkv<<<dim3(Dd / 32, Ee / 32, 48), 256, 0, stream>>>(
        mh_wq + wo, mh_wk + wo, mh_wv + wo, wt_h, wt_l);
    gemm_ps<false, false, false, true, false><<<dim3(24, Mm / 64), 256, 0, stream>>>(
        srcH, srcL, nullptr, nullptr, wt_h, wt_l, nullptr,
        qb, kb, vb, nullptr, nullptr, Ee, Ee);
    attn_ms<<<dim3(Tt / 64, Bb * Hh), 256, 0, stream>>>(qb, kb, vb, ob);
    attn_ln_res<<<dim3(Mm * Hh / 4), 256, 0, stream>>>(
        ob, srcF, mh_g + (size_t)i * Hh * Dd, mh_b + (size_t)i * Hh * Dd, dstF, dstH, dstL);
  };
  // tmp1: fp32 scratch [M,E] for the z=1 split-K partial (a dead buffer).
  auto ff = [&](int i, const float* srcF, const u16* srcH, const u16* srcL,
                float* dstF, u16* dstH, u16* dstL, float* tmp1) {
    cvtT_split<<<dim3(Ff / 32, Ee / 32, 1), 256, 0, stream>>>(ff_w1 + (size_t)i * Ee * Ff, wt_h, wt_l, Ee, Ff);
    gemm_128<<<dim3(Ff / 128, Mm / 128), 256, 0, stream>>>(
        srcH, srcL, wt_h, wt_l, ff_b1 + (size_t)i * Ff, hidh, hidl, Ff, Ee);
    cvtT_split<<<dim3(Ee / 32, Ff / 32, 1), 256, 0, stream>>>(ff_w2 + (size_t)i * Ff * Ee, wt_h, wt_l, Ff, Ee);
    gemm_ps<false, false, false, false, true><<<dim3(Ee / 128, Mm / 64, 2), 256, 0, stream>>>(
        hidh, hidl, nullptr, nullptr, wt_h, wt_l, nullptr,
        tmp, tmp1, nullptr, nullptr, nullptr, Ee, Ff);
    ff_ln_res<<<dim3(Mm), 256, 0, stream>>>(
        tmp, tmp1, ff_b2 + (size_t)i * Ee,
        srcF, ff_g + (size_t)i * Ee, ff_bb + (size_t)i * Ee, dstF, dstH, dstL);
  };

  // out_one branch: ff(3, mh(4, mh(0, x)))   [bufB fp32 dead -> tmp1]
  split_act<<<dim3(ME / 1024), 256, 0, stream>>>(x, bufAh, bufAl);
  mh(0, x, bufAh, bufAl, bufA, bufAh, bufAl);
  mh(4, bufA, bufAh, bufAl, bufA, bufAh, bufAl);
  ff(3, bufA, bufAh, bufAl, bufA, bufAh, bufAl, bufB);

  // out_two branch: 3 encoder blocks then decoder  [bufA fp32 dead -> tmp1]
  split_act<<<dim3(ME / 1024), 256, 0, stream>>>(x, bufBh, bufBl);
  mh(1, x, bufBh, bufBl, bufB, bufBh, bufBl);
  ff(0, bufB, bufBh, bufBl, bufB, bufBh, bufBl, bufA);
  mh(2, bufB, bufBh, bufBl, bufB, bufBh, bufBl);
  ff(1, bufB, bufBh, bufBl, bufB, bufBh, bufBl, bufA);
  mh(3, bufB, bufBh, bufBl, bufB, bufBh, bufBl);
  ff(2, bufB, bufBh, bufBl, bufB, bufBh, bufBl, bufA);
  mh(4, bufB, bufBh, bufBl, bufB, bufBh, bufBl);
  ff(3, bufB, bufBh, bufBl, bufB, bufBh, bufBl, bufA);

  // final: out = concat(A,B) @ lt_w + lt_b, split-K=2 into dead bufA/bufB
  cvtT_split<<<dim3(Ee / 32, 2 * Ee / 32, 1), 256, 0, stream>>>(lt_w, wt_h, wt_l, 2 * Ee, Ee);
  gemm_ps<true, false, false, false, true><<<dim3(Ee / 128, Mm / 64, 2), 256, 0, stream>>>(
      bufAh, bufAl, bufBh, bufBl, wt_h, wt_l, nullptr,
      bufA, bufB, nullptr, nullptr, nullptr, Ee, 2 * Ee);
  add2_bias<<<dim3(ME / 1024), 256, 0, stream>>>(bufA, bufB, lt_b, out);
}

// Round 10
// 1149.430 us; speedup vs baseline: 4.0703x; 1.2479x over previous
//
#include <hip/hip_runtime.h>
#include <math.h>

#define Bb 4
#define Tt 512
#define Ee 1024
#define Hh 16
#define Dd 64
#define Ff 4096
#define Mm (Bb*Tt)   // 2048
static constexpr float EPS = 1e-5f;

typedef __attribute__((ext_vector_type(8))) short short8;
typedef __attribute__((ext_vector_type(4))) float f32x4;
typedef unsigned short u16;
typedef _Float16 f16;
typedef __attribute__((ext_vector_type(8))) _Float16 f16x8;

__device__ __forceinline__ u16 f2bf(float f) {
  unsigned u = __builtin_bit_cast(unsigned, f);
  return (u16)((u + 0x7fffu + ((u >> 16) & 1u)) >> 16);   // RNE
}
__device__ __forceinline__ float bf2f(u16 h) {
  unsigned u = (unsigned)h << 16;
  return __builtin_bit_cast(float, u);
}
// async global->LDS, 16B per lane. LDS dest must be lane-linear.
__device__ __forceinline__ void gload16(const void* g, void* l) {
  __builtin_amdgcn_global_load_lds(
      (const __attribute__((address_space(1))) unsigned int*)g,
      (__attribute__((address_space(3))) unsigned int*)l, 16, 0, 0);
}

// ---------------------------------------------------------------------------
// FF1: 1-pass fp16 GEMM, m97 structure. 128x128 tile, 4 waves (2x2),
// wave 64x64, BK=32, single-buffer 16KB LDS, gload_lds staging.
// Per K-step/wave: 8 ds_read_b128, 16 MFMA. Bias+ReLU, f16 out.
// ---------------------------------------------------------------------------
__global__ __launch_bounds__(256)
void gemm_f16_128(const f16* __restrict__ A, const f16* __restrict__ W,
                  const float* __restrict__ bias,
                  f16* __restrict__ C, int ldc, int K)
{
  __shared__ f16 AS[128][32], BS[128][32];
  const int tid = threadIdx.x;
  const int lane = tid & 63, w = tid >> 6;
  const int wr = w >> 1, wc = w & 1;
  const int lhi = lane >> 4, llo = lane & 15;
  const int n0 = blockIdx.x * 128, m0 = blockIdx.y * 128;
  const int s_row = tid >> 2, s_ko = (tid & 3) * 8;   // LDS byte = tid*16

  f32x4 acc[4][4] = {};

  for (int k0 = 0; k0 < K; k0 += 32) {
#pragma unroll
    for (int i = 0; i < 2; ++i) {
      const int row = s_row + i * 64;
      gload16(&A[(size_t)(m0 + row) * K + k0 + s_ko], &AS[row][s_ko]);
      gload16(&W[(size_t)(n0 + row) * K + k0 + s_ko], &BS[row][s_ko]);
    }
    __syncthreads();
    f16x8 af[4], bf[4];
#pragma unroll
    for (int f = 0; f < 4; ++f) {
      af[f] = *(const f16x8*)&AS[wr * 64 + f * 16 + llo][lhi * 8];
      bf[f] = *(const f16x8*)&BS[wc * 64 + f * 16 + llo][lhi * 8];
    }
#pragma unroll
    for (int m = 0; m < 4; ++m)
#pragma unroll
      for (int n = 0; n < 4; ++n)
        acc[m][n] = __builtin_amdgcn_mfma_f32_16x16x32_f16(af[m], bf[n], acc[m][n], 0, 0, 0);
    __syncthreads();
  }

#pragma unroll
  for (int n = 0; n < 4; ++n) {
    const int col = n0 + wc * 64 + n * 16 + llo;
    const float bv = bias[col];
#pragma unroll
    for (int m = 0; m < 4; ++m) {
      const int rbase = m0 + wr * 64 + m * 16 + lhi * 4;
#pragma unroll
      for (int j = 0; j < 4; ++j) {
        float v = fmaxf(acc[m][n][j] + bv, 0.f);
        C[(size_t)(rbase + j) * ldc + col] = (f16)v;
      }
    }
  }
}

// ---------------------------------------------------------------------------
// 1-pass fp16 GEMM, 64x128 dbuf (r8 structure minus lo): FF2 (SPLITK) and
// final (CONCAT+SPLITK). fp32 partial outputs (bias in consumer).
// ---------------------------------------------------------------------------
template<bool CONCAT>
__global__ __launch_bounds__(256)
void gemm_f16_1p(const f16* __restrict__ A, const f16* __restrict__ A2,
                 const f16* __restrict__ W,
                 float* __restrict__ Cf, float* __restrict__ Cf1,
                 int ldc, int K)
{
  __shared__ f16 AS[2][64][32], BS[2][128][32];
  const int tid = threadIdx.x;
  const int lane = tid & 63, w = tid >> 6;
  const int wr = w >> 1, wc = w & 1;
  const int lhi = lane >> 4, llo = lane & 15;
  const int n0 = blockIdx.x * 128;
  const int m0 = blockIdx.y * 64;
  const int half = K >> 1;
  const int kbeg = blockIdx.z * half;
  const int nt = half / 32;
  if (blockIdx.z == 1) Cf = Cf1;

  const int s_row = tid >> 2, s_ko = (tid & 3) * 8;

  auto stage = [&](int k0, int buf) {
    const int gk = k0 + s_ko;
    const f16* s = A;
    size_t g;
    if (CONCAT) {
      if (gk < Ee) { g = (size_t)(m0 + s_row) * Ee + gk; }
      else { g = (size_t)(m0 + s_row) * Ee + (gk - Ee); s = A2; }
    } else {
      g = (size_t)(m0 + s_row) * K + gk;
    }
    gload16(&s[g], &AS[buf][s_row][s_ko]);
#pragma unroll
    for (int i = 0; i < 2; ++i)
      gload16(&W[(size_t)(n0 + s_row + i * 64) * K + gk], &BS[buf][s_row + i * 64][s_ko]);
  };

  f32x4 acc[2][4] = {};
  stage(kbeg, 0);
  __syncthreads();
  int cur = 0;
  for (int t = 0; t < nt; ++t) {
    if (t + 1 < nt) stage(kbeg + (t + 1) * 32, cur ^ 1);
    f16x8 af[2], bf[4];
#pragma unroll
    for (int m = 0; m < 2; ++m)
      af[m] = *(const f16x8*)&AS[cur][wr * 32 + m * 16 + llo][lhi * 8];
#pragma unroll
    for (int n = 0; n < 4; ++n)
      bf[n] = *(const f16x8*)&BS[cur][wc * 64 + n * 16 + llo][lhi * 8];
#pragma unroll
    for (int m = 0; m < 2; ++m)
#pragma unroll
      for (int n = 0; n < 4; ++n)
        acc[m][n] = __builtin_amdgcn_mfma_f32_16x16x32_f16(af[m], bf[n], acc[m][n], 0, 0, 0);
    __syncthreads();
    cur ^= 1;
  }

#pragma unroll
  for (int n = 0; n < 4; ++n) {
    const int col = n0 + wc * 64 + n * 16 + llo;
#pragma unroll
    for (int m = 0; m < 2; ++m) {
      const int rbase = m0 + wr * 32 + m * 16 + lhi * 4;
#pragma unroll
      for (int j = 0; j < 4; ++j)
        Cf[(size_t)(rbase + j) * ldc + col] = acc[m][n][j];
    }
  }
}

// ---------------------------------------------------------------------------
// QKV projection: 3-pass fp16 (h,l) GEMM, 64x128 dbuf (r8/r9 structure).
// grid.x = 24: sec = bx>>3 selects weight slab + output buffer (q/k/v fp32).
// ---------------------------------------------------------------------------
__global__ __launch_bounds__(256)
void gemm_qkv(const f16* __restrict__ Ah_g, const f16* __restrict__ Al_g,
              const f16* __restrict__ Wh, const f16* __restrict__ Wl,
              float* __restrict__ Cq, float* __restrict__ Ck, float* __restrict__ Cv)
{
  __shared__ f16 AhS[2][64][32], AlS[2][64][32];
  __shared__ f16 BhS[2][128][32], BlS[2][128][32];
  const int tid = threadIdx.x;
  const int lane = tid & 63, w = tid >> 6;
  const int wr = w >> 1, wc = w & 1;
  const int lhi = lane >> 4, llo = lane & 15;
  const int sec = blockIdx.x >> 3;
  const int n0 = (blockIdx.x & 7) * 128;
  Wh += (size_t)sec << 20;
  Wl += (size_t)sec << 20;
  float* Cf = (sec == 0) ? Cq : (sec == 1) ? Ck : Cv;
  const int m0 = blockIdx.y * 64;
  const int s_row = tid >> 2, s_ko = (tid & 3) * 8;

  auto stage = [&](int k0, int buf) {
    const size_t g = (size_t)(m0 + s_row) * Ee + k0 + s_ko;
    gload16(&Ah_g[g], &AhS[buf][s_row][s_ko]);
    gload16(&Al_g[g], &AlS[buf][s_row][s_ko]);
#pragma unroll
    for (int i = 0; i < 2; ++i) {
      size_t gb = (size_t)(n0 + s_row + i * 64) * Ee + k0 + s_ko;
      gload16(&Wh[gb], &BhS[buf][s_row + i * 64][s_ko]);
      gload16(&Wl[gb], &BlS[buf][s_row + i * 64][s_ko]);
    }
  };

  f32x4 acc[2][4] = {};
  stage(0, 0);
  __syncthreads();
  int cur = 0;
  for (int t = 0; t < Ee / 32; ++t) {
    if (t + 1 < Ee / 32) stage((t + 1) * 32, cur ^ 1);
    f16x8 ah[2], al[2], bh[4], bl[4];
#pragma unroll
    for (int m = 0; m < 2; ++m) {
      ah[m] = *(const f16x8*)&AhS[cur][wr * 32 + m * 16 + llo][lhi * 8];
      al[m] = *(const f16x8*)&AlS[cur][wr * 32 + m * 16 + llo][lhi * 8];
    }
#pragma unroll
    for (int n = 0; n < 4; ++n) {
      bh[n] = *(const f16x8*)&BhS[cur][wc * 64 + n * 16 + llo][lhi * 8];
      bl[n] = *(const f16x8*)&BlS[cur][wc * 64 + n * 16 + llo][lhi * 8];
    }
#pragma unroll
    for (int m = 0; m < 2; ++m)
#pragma unroll
      for (int n = 0; n < 4; ++n) {
        acc[m][n] = __builtin_amdgcn_mfma_f32_16x16x32_f16(ah[m], bh[n], acc[m][n], 0, 0, 0);
        acc[m][n] = __builtin_amdgcn_mfma_f32_16x16x32_f16(ah[m], bl[n], acc[m][n], 0, 0, 0);
        acc[m][n] = __builtin_amdgcn_mfma_f32_16x16x32_f16(al[m], bh[n], acc[m][n], 0, 0, 0);
      }
    __syncthreads();
    cur ^= 1;
  }

#pragma unroll
  for (int n = 0; n < 4; ++n) {
    const int col = n0 + wc * 64 + n * 16 + llo;
#pragma unroll
    for (int m = 0; m < 2; ++m) {
      const int rbase = m0 + wr * 32 + m * 16 + lhi * 4;
#pragma unroll
      for (int j = 0; j < 4; ++j)
        Cf[(size_t)(rbase + j) * Ee + col] = acc[m][n][j];
    }
  }
}

// ---------------------------------------------------------------------------
// Split-bf16 MFMA flash attention (PROVEN r5-r9, byte-identical), causal.
// ---------------------------------------------------------------------------
__global__ __launch_bounds__(256)
void attn_ms(const float* __restrict__ Q, const float* __restrict__ Kp,
             const float* __restrict__ V, float* __restrict__ O)
{
  __shared__ u16 Ksh[64][72], Ksl[64][72];   // [s][d]
  __shared__ u16 Vsh[64][72], Vsl[64][72];   // [d][s] (transposed)
  __shared__ u16 Pwh[4][16][72], Pwl[4][16][72];  // per-wave P [q_local][s]
  const int tid = threadIdx.x;
  const int lane = tid & 63, w = tid >> 6;
  const int lhi = lane >> 4, llo = lane & 15;
  const int q0 = blockIdx.x * 64;
  const int bh = blockIdx.y;
  const size_t base = (size_t)(bh >> 4) * Tt * Ee + (size_t)(bh & 15) * Dd;

  short8 qh[2], ql[2];
#pragma unroll
  for (int ks = 0; ks < 2; ++ks) {
    const float* qsrc = &Q[base + (size_t)(q0 + w * 16 + llo) * Ee + ks * 32 + lhi * 8];
    float4 a = *(const float4*)qsrc, b2 = *(const float4*)(qsrc + 4);
    float f[8] = {a.x, a.y, a.z, a.w, b2.x, b2.y, b2.z, b2.w};
#pragma unroll
    for (int j = 0; j < 8; ++j) {
      u16 h = f2bf(f[j]);
      qh[ks][j] = (short)h;
      ql[ks][j] = (short)f2bf(f[j] - bf2f(h));
    }
  }

  f32x4 oacc[4] = {};
  float m_run[4], l_run[4];
#pragma unroll
  for (int j = 0; j < 4; ++j) { m_run[j] = -INFINITY; l_run[j] = 0.f; }

  for (int s0 = 0; s0 <= q0; s0 += 64) {
#pragma unroll
    for (int pass = 0; pass < 2; ++pass) {
      int c = tid + 256 * pass;
      int row = c >> 3, d0 = (c & 7) * 8;
      const float* ksrc = &Kp[base + (size_t)(s0 + row) * Ee + d0];
      const float* vsrc = &V[base + (size_t)(s0 + row) * Ee + d0];
      float4 ka = *(const float4*)ksrc, kb2 = *(const float4*)(ksrc + 4);
      float4 va = *(const float4*)vsrc, vb2 = *(const float4*)(vsrc + 4);
      float kf[8] = {ka.x, ka.y, ka.z, ka.w, kb2.x, kb2.y, kb2.z, kb2.w};
      float vf[8] = {va.x, va.y, va.z, va.w, vb2.x, vb2.y, vb2.z, vb2.w};
      short8 khv, klv;
#pragma unroll
      for (int j = 0; j < 8; ++j) {
        u16 h = f2bf(kf[j]);
        khv[j] = (short)h;
        klv[j] = (short)f2bf(kf[j] - bf2f(h));
      }
      *(short8*)&Ksh[row][d0] = khv;
      *(short8*)&Ksl[row][d0] = klv;
#pragma unroll
      for (int j = 0; j < 8; ++j) {
        u16 h = f2bf(vf[j]);
        Vsh[d0 + j][row] = h;
        Vsl[d0 + j][row] = f2bf(vf[j] - bf2f(h));
      }
    }
    __syncthreads();

    f32x4 sacc[4] = {};
#pragma unroll
    for (int ks = 0; ks < 2; ++ks)
#pragma unroll
      for (int n = 0; n < 4; ++n) {
        short8 kh = *(const short8*)&Ksh[n * 16 + llo][ks * 32 + lhi * 8];
        short8 kl = *(const short8*)&Ksl[n * 16 + llo][ks * 32 + lhi * 8];
        sacc[n] = __builtin_amdgcn_mfma_f32_16x16x32_bf16(qh[ks], kh, sacc[n], 0, 0, 0);
        sacc[n] = __builtin_amdgcn_mfma_f32_16x16x32_bf16(qh[ks], kl, sacc[n], 0, 0, 0);
        sacc[n] = __builtin_amdgcn_mfma_f32_16x16x32_bf16(ql[ks], kh, sacc[n], 0, 0, 0);
      }

    if (s0 == q0) {
#pragma unroll
      for (int n = 0; n < 4; ++n)
#pragma unroll
        for (int j = 0; j < 4; ++j)
          if (n * 16 + llo > w * 16 + lhi * 4 + j) sacc[n][j] = -INFINITY;
    }

    float scj[4];
#pragma unroll
    for (int j = 0; j < 4; ++j) {
      float mt = fmaxf(fmaxf(sacc[0][j], sacc[1][j]), fmaxf(sacc[2][j], sacc[3][j]));
#pragma unroll
      for (int off = 1; off < 16; off <<= 1) mt = fmaxf(mt, __shfl_xor(mt, off));
      float mn = fmaxf(m_run[j], mt);
      scj[j] = __expf(m_run[j] - mn);
      m_run[j] = mn;
      float rs = 0.f;
#pragma unroll
      for (int n = 0; n < 4; ++n) {
        float pp = __expf(sacc[n][j] - mn);
        sacc[n][j] = pp;
        rs += pp;
      }
#pragma unroll
      for (int off = 1; off < 16; off <<= 1) rs += __shfl_xor(rs, off);
      l_run[j] = l_run[j] * scj[j] + rs;
    }

#pragma unroll
    for (int n = 0; n < 4; ++n)
#pragma unroll
      for (int j = 0; j < 4; ++j) {
        float pp = sacc[n][j];
        u16 h = f2bf(pp);
        Pwh[w][lhi * 4 + j][n * 16 + llo] = h;
        Pwl[w][lhi * 4 + j][n * 16 + llo] = f2bf(pp - bf2f(h));
      }
#pragma unroll
    for (int df = 0; df < 4; ++df)
#pragma unroll
      for (int j = 0; j < 4; ++j)
        oacc[df][j] *= scj[j];

#pragma unroll
    for (int ks = 0; ks < 2; ++ks) {
      short8 ph = *(const short8*)&Pwh[w][llo][ks * 32 + lhi * 8];
      short8 pl = *(const short8*)&Pwl[w][llo][ks * 32 + lhi * 8];
#pragma unroll
      for (int df = 0; df < 4; ++df) {
        short8 vh = *(const short8*)&Vsh[df * 16 + llo][ks * 32 + lhi * 8];
        short8 vl = *(const short8*)&Vsl[df * 16 + llo][ks * 32 + lhi * 8];
        oacc[df] = __builtin_amdgcn_mfma_f32_16x16x32_bf16(ph, vh, oacc[df], 0, 0, 0);
        oacc[df] = __builtin_amdgcn_mfma_f32_16x16x32_bf16(ph, vl, oacc[df], 0, 0, 0);
        oacc[df] = __builtin_amdgcn_mfma_f32_16x16x32_bf16(pl, vh, oacc[df], 0, 0, 0);
      }
    }
    __syncthreads();
  }

#pragma unroll
  for (int j = 0; j < 4; ++j) {
    float inv = 1.f / l_run[j];
#pragma unroll
    for (int df = 0; df < 4; ++df)
      O[base + (size_t)(q0 + w * 16 + lhi * 4 + j) * Ee + df * 16 + llo] =
          oacc[df][j] * inv;
  }
}

// ---------------------------------------------------------------------------
// Per-head LN over D=64 + residual; writes fp32 + (hi,lo) f16 streams.
// ---------------------------------------------------------------------------
__global__ __launch_bounds__(256)
void attn_ln_res(const float* __restrict__ O, const float* __restrict__ Yin,
                 const float* __restrict__ g, const float* __restrict__ bta,
                 float* __restrict__ Yout, f16* __restrict__ Yh, f16* __restrict__ Yl)
{
  const int tid = threadIdx.x;
  const int w = (blockIdx.x << 2) + (tid >> 6);
  const int lane = tid & 63;
  const int m = w >> 4;
  const int h = w & 15;
  const size_t idx = (size_t)m * Ee + h * Dd + lane;
  float x = O[idx];
  float s = x, s2 = x * x;
#pragma unroll
  for (int off = 1; off < 64; off <<= 1) {
    s  += __shfl_xor(s, off);
    s2 += __shfl_xor(s2, off);
  }
  float mean = s * (1.f / 64.f);
  float var  = s2 * (1.f / 64.f) - mean * mean;
  float inv  = rsqrtf(var + EPS);
  float r = Yin[idx] + (x - mean) * inv * g[h * Dd + lane] + bta[h * Dd + lane];
  Yout[idx] = r;
  f16 hh = (f16)r;
  Yh[idx] = hh;
  Yl[idx] = (f16)(r - (float)hh);
}

// ---------------------------------------------------------------------------
// Row LN over E=1024 + residual. Input = T0 + T1 + bias (split-K partials).
// ---------------------------------------------------------------------------
__global__ __launch_bounds__(256)
void ff_ln_res(const float* __restrict__ T0, const float* __restrict__ T1,
               const float* __restrict__ b2,
               const float* __restrict__ Yin, const float* __restrict__ g,
               const float* __restrict__ bb,
               float* __restrict__ Yout, f16* __restrict__ Yh, f16* __restrict__ Yl)
{
  __shared__ float red[8];
  const int m = blockIdx.x;
  const int tid = threadIdx.x;
  const size_t basep = (size_t)m * Ee;
  float4 xa = *(const float4*)&T0[basep + (tid << 2)];
  float4 xb = *(const float4*)&T1[basep + (tid << 2)];
  float4 bv2 = *(const float4*)&b2[tid << 2];
  float xv[4] = {xa.x + xb.x + bv2.x, xa.y + xb.y + bv2.y,
                 xa.z + xb.z + bv2.z, xa.w + xb.w + bv2.w};
  float s  = xv[0] + xv[1] + xv[2] + xv[3];
  float s2 = xv[0]*xv[0] + xv[1]*xv[1] + xv[2]*xv[2] + xv[3]*xv[3];
#pragma unroll
  for (int off = 1; off < 64; off <<= 1) {
    s  += __shfl_xor(s, off);
    s2 += __shfl_xor(s2, off);
  }
  const int wid = tid >> 6;
  if ((tid & 63) == 0) { red[wid] = s; red[4 + wid] = s2; }
  __syncthreads();
  s  = red[0] + red[1] + red[2] + red[3];
  s2 = red[4] + red[5] + red[6] + red[7];
  float mean = s * (1.f / Ee);
  float var  = s2 * (1.f / Ee) - mean * mean;
  float inv  = rsqrtf(var + EPS);
  float4 y  = *(const float4*)&Yin[basep + (tid << 2)];
  float4 gg = *(const float4*)&g[tid << 2];
  float4 bv = *(const float4*)&bb[tid << 2];
  float gga[4] = {gg.x, gg.y, gg.z, gg.w};
  float bva[4] = {bv.x, bv.y, bv.z, bv.w};
  float ya[4] = {y.x, y.y, y.z, y.w};
  float o[4];
#pragma unroll
  for (int j = 0; j < 4; ++j) {
    o[j] = ya[j] + (xv[j] - mean) * inv * gga[j] + bva[j];
    f16 hh = (f16)o[j];
    Yh[basep + (tid << 2) + j] = hh;
    Yl[basep + (tid << 2) + j] = (f16)(o[j] - (float)hh);
  }
  *(float4*)&Yout[basep + (tid << 2)] = *(float4*)o;
}

// out = p0 + p1 + bias (final linear reduce)
__global__ __launch_bounds__(256)
void add2_bias(const float* __restrict__ p0, const float* __restrict__ p1,
               const float* __restrict__ b, float* __restrict__ out)
{
  const size_t i = ((size_t)blockIdx.x * 256 + threadIdx.x) * 4;
  const int col = (int)(i & (Ee - 1));
  float4 a = *(const float4*)&p0[i];
  float4 c = *(const float4*)&p1[i];
  float4 bb = *(const float4*)&b[col];
  float4 o;
  o.x = a.x + c.x + bb.x; o.y = a.y + c.y + bb.y;
  o.z = a.z + c.z + bb.z; o.w = a.w + c.w + bb.w;
  *(float4*)&out[i] = o;
}

// fp32 -> (hi,lo) f16 split, no transpose (x activations).
__global__ __launch_bounds__(256)
void split_act(const float* __restrict__ in, f16* __restrict__ oh, f16* __restrict__ ol)
{
  const size_t i = ((size_t)blockIdx.x * 256 + threadIdx.x) * 4;
  float4 v = *(const float4*)&in[i];
  float f[4] = {v.x, v.y, v.z, v.w};
#pragma unroll
  for (int j = 0; j < 4; ++j) {
    f16 h = (f16)f[j];
    oh[i + j] = h;
    ol[i + j] = (f16)(f[j] - (float)h);
  }
}

// fp32 [R][C] -> f16 [C][R] transpose (FF + final weights).
__global__ __launch_bounds__(256)
void cvtT_f16(const float* __restrict__ in, f16* __restrict__ outp, int R, int C)
{
  __shared__ float tile[32][33];
  const int c0 = blockIdx.x * 32, r0 = blockIdx.y * 32;
  const int tid = threadIdx.x;
  const int ir = tid >> 3, ic = (tid & 7) * 4;
  float4 v = *(const float4*)&in[(size_t)(r0 + ir) * C + c0 + ic];
  tile[ir][ic] = v.x; tile[ir][ic + 1] = v.y;
  tile[ir][ic + 2] = v.z; tile[ir][ic + 3] = v.w;
  __syncthreads();
  const int oc = tid >> 3, orr = (tid & 7) * 4;
  const size_t ob = (size_t)(c0 + oc) * R + r0 + orr;
#pragma unroll
  for (int j = 0; j < 4; ++j)
    outp[ob + j] = (f16)tile[orr + j][oc];
}

// Fused QKV weight transpose-split (f16 h/l): z = sec*16 + head.
__global__ __launch_bounds__(256)
void cvtT_qkv(const float* __restrict__ wq, const float* __restrict__ wk,
              const float* __restrict__ wv, f16* __restrict__ out_h,
              f16* __restrict__ out_l)
{
  __shared__ float tile[32][33];
  const int z = blockIdx.z, sec = z >> 4, hh = z & 15;
  const float* in = (sec == 0) ? wq : (sec == 1) ? wk : wv;
  const size_t zi = (size_t)hh * Ee * Dd;
  const size_t zo = ((size_t)sec << 20) + (size_t)hh * Ee * Dd;
  const int c0 = blockIdx.x * 32, r0 = blockIdx.y * 32;
  const int tid = threadIdx.x;
  const int ir = tid >> 3, ic = (tid & 7) * 4;
  float4 v = *(const float4*)&in[zi + (size_t)(r0 + ir) * Dd + c0 + ic];
  tile[ir][ic] = v.x; tile[ir][ic + 1] = v.y;
  tile[ir][ic + 2] = v.z; tile[ir][ic + 3] = v.w;
  __syncthreads();
  const int oc = tid >> 3, orr = (tid & 7) * 4;
  const size_t ob = zo + (size_t)(c0 + oc) * Ee + r0 + orr;
#pragma unroll
  for (int j = 0; j < 4; ++j) {
    float f = tile[orr + j][oc];
    f16 h = (f16)f;
    out_h[ob + j] = h;
    out_l[ob + j] = (f16)(f - (float)h);
  }
}

// ---------------------------------------------------------------------------
extern "C" void kernel_launch(void* const* d_in, const int* in_sizes, int n_in,
                              void* d_out, int out_size, void* d_ws, size_t ws_size,
                              hipStream_t stream)
{
  const float* x     = (const float*)d_in[0];
  const float* mh_wq = (const float*)d_in[1];
  const float* mh_wk = (const float*)d_in[2];
  const float* mh_wv = (const float*)d_in[3];
  const float* mh_g  = (const float*)d_in[4];
  const float* mh_b  = (const float*)d_in[5];
  const float* ff_w1 = (const float*)d_in[6];
  const float* ff_b1 = (const float*)d_in[7];
  const float* ff_w2 = (const float*)d_in[8];
  const float* ff_b2 = (const float*)d_in[9];
  const float* ff_g  = (const float*)d_in[10];
  const float* ff_bb = (const float*)d_in[11];
  const float* lt_w  = (const float*)d_in[12];
  const float* lt_b  = (const float*)d_in[13];
  float* out = (float*)d_out;

  const size_t ME = (size_t)Mm * Ee;   // 2M elements
  char* p = (char*)d_ws;
  auto alloc = [&](size_t bytes) { void* r = (void*)p; p += (bytes + 255) & ~(size_t)255; return r; };
  float* bufA  = (float*)alloc(ME * 4);                // 8 MB
  f16*   bufAh = (f16*)alloc(ME * 2);                  // 4 MB
  f16*   bufAl = (f16*)alloc(ME * 2);                  // 4 MB
  float* bufB  = (float*)alloc(ME * 4);                // 8 MB
  f16*   bufBh = (f16*)alloc(ME * 2);                  // 4 MB
  f16*   bufBl = (f16*)alloc(ME * 2);                  // 4 MB
  f16*   wt_h  = (f16*)alloc((size_t)Ff * Ee * 2);     // 8 MB (FF w f16 / QKV h slabs)
  f16*   wt_l  = (f16*)alloc((size_t)Ff * Ee * 2);     // 8 MB (QKV l slabs)
  float* reg   = (float*)alloc((size_t)10 * 1024 * 1024 * 4);  // 40 MB union
  float* qb    = reg;                          // mh phase
  float* kb    = reg + 2 * 1024 * 1024;
  float* vb    = reg + 4 * 1024 * 1024;
  float* ob    = reg + 6 * 1024 * 1024;
  f16*   hid   = (f16*)reg;                    // ff phase: [M,F] f16 = 16 MB
  float* tmp   = reg + 8 * 1024 * 1024;        // fp32 partial (32..40 MB)

  auto mh = [&](int i, const float* srcF, const f16* srcH, const f16* srcL,
                float* dstF, f16* dstH, f16* dstL) {
    const size_t wo = (size_t)i * Hh * Ee * Dd;
    cvtT_qkv<<<dim3(Dd / 32, Ee / 32, 48), 256, 0, stream>>>(
        mh_wq + wo, mh_wk + wo, mh_wv + wo, wt_h, wt_l);
    gemm_qkv<<<dim3(24, Mm / 64), 256, 0, stream>>>(
        srcH, srcL, wt_h, wt_l, qb, kb, vb);
    attn_ms<<<dim3(Tt / 64, Bb * Hh), 256, 0, stream>>>(qb, kb, vb, ob);
    attn_ln_res<<<dim3(Mm * Hh / 4), 256, 0, stream>>>(
        ob, srcF, mh_g + (size_t)i * Hh * Dd, mh_b + (size_t)i * Hh * Dd, dstF, dstH, dstL);
  };
  // tmp1: fp32 scratch [M,E] for the z=1 split-K partial (a dead buffer).
  auto ff = [&](int i, const float* srcF, const f16* srcH,
                float* dstF, f16* dstH, f16* dstL, float* tmp1) {
    cvtT_f16<<<dim3(Ff / 32, Ee / 32), 256, 0, stream>>>(ff_w1 + (size_t)i * Ee * Ff, wt_h, Ee, Ff);
    gemm_f16_128<<<dim3(Ff / 128, Mm / 128), 256, 0, stream>>>(
        srcH, wt_h, ff_b1 + (size_t)i * Ff, hid, Ff, Ee);
    cvtT_f16<<<dim3(Ee / 32, Ff / 32), 256, 0, stream>>>(ff_w2 + (size_t)i * Ff * Ee, wt_h, Ff, Ee);
    gemm_f16_1p<false><<<dim3(Ee / 128, Mm / 64, 2), 256, 0, stream>>>(
        hid, nullptr, wt_h, tmp, tmp1, Ee, Ff);
    ff_ln_res<<<dim3(Mm), 256, 0, stream>>>(
        tmp, tmp1, ff_b2 + (size_t)i * Ee,
        srcF, ff_g + (size_t)i * Ee, ff_bb + (size_t)i * Ee, dstF, dstH, dstL);
  };

  // out_one branch: ff(3, mh(4, mh(0, x)))   [bufB fp32 dead -> tmp1]
  split_act<<<dim3(ME / 1024), 256, 0, stream>>>(x, bufAh, bufAl);
  mh(0, x, bufAh, bufAl, bufA, bufAh, bufAl);
  mh(4, bufA, bufAh, bufAl, bufA, bufAh, bufAl);
  ff(3, bufA, bufAh, bufA, bufAh, bufAl, bufB);

  // out_two branch: 3 encoder blocks then decoder  [bufA fp32 dead -> tmp1]
  split_act<<<dim3(ME / 1024), 256, 0, stream>>>(x, bufBh, bufBl);
  mh(1, x, bufBh, bufBl, bufB, bufBh, bufBl);
  ff(0, bufB, bufBh, bufB, bufBh, bufBl, bufA);
  mh(2, bufB, bufBh, bufBl, bufB, bufBh, bufBl);
  ff(1, bufB, bufBh, bufB, bufBh, bufBl, bufA);
  mh(3, bufB, bufBh, bufBl, bufB, bufBh, bufBl);
  ff(2, bufB, bufBh, bufB, bufBh, bufBl, bufA);
  mh(4, bufB, bufBh, bufBl, bufB, bufBh, bufBl);
  ff(3, bufB, bufBh, bufB, bufBh, bufBl, bufA);

  // final: out = concat(A,B)@lt_w + lt_b, 1-pass f16, split-K=2 into dead bufs
  cvtT_f16<<<dim3(Ee / 32, 2 * Ee / 32), 256, 0, stream>>>(lt_w, wt_h, 2 * Ee, Ee);
  gemm_f16_1p<true><<<dim3(Ee / 128, Mm / 64, 2), 256, 0, stream>>>(
      bufAh, bufBh, wt_h, bufA, bufB, Ee, 2 * Ee);
  add2_bias<<<dim3(ME / 1024), 256, 0, stream>>>(bufA, bufB, lt_b, out);
}

// Round 11
// 1038.981 us; speedup vs baseline: 4.5029x; 1.1063x over previous
//
#include <hip/hip_runtime.h>
#include <math.h>

#define Bb 4
#define Tt 512
#define Ee 1024
#define Hh 16
#define Dd 64
#define Ff 4096
#define Mm (Bb*Tt)   // 2048
static constexpr float EPS = 1e-5f;

typedef __attribute__((ext_vector_type(4))) float f32x4;
typedef _Float16 f16;
typedef __attribute__((ext_vector_type(8))) _Float16 f16x8;

// async global->LDS, 16B per lane. LDS dest must be lane-linear.
__device__ __forceinline__ void gload16(const void* g, void* l) {
  __builtin_amdgcn_global_load_lds(
      (const __attribute__((address_space(1))) unsigned int*)g,
      (__attribute__((address_space(3))) unsigned int*)l, 16, 0, 0);
}

// ---------------------------------------------------------------------------
// FF1: 1-pass fp16 GEMM, m97 structure (PROVEN r10). 128x128, BK=32,
// single-buffer 16KB LDS, gload_lds staging. Bias+ReLU, f16 out.
// ---------------------------------------------------------------------------
__global__ __launch_bounds__(256)
void gemm_f16_128(const f16* __restrict__ A, const f16* __restrict__ W,
                  const float* __restrict__ bias,
                  f16* __restrict__ C, int ldc, int K)
{
  __shared__ f16 AS[128][32], BS[128][32];
  const int tid = threadIdx.x;
  const int lane = tid & 63, w = tid >> 6;
  const int wr = w >> 1, wc = w & 1;
  const int lhi = lane >> 4, llo = lane & 15;
  const int n0 = blockIdx.x * 128, m0 = blockIdx.y * 128;
  const int s_row = tid >> 2, s_ko = (tid & 3) * 8;

  f32x4 acc[4][4] = {};

  for (int k0 = 0; k0 < K; k0 += 32) {
#pragma unroll
    for (int i = 0; i < 2; ++i) {
      const int row = s_row + i * 64;
      gload16(&A[(size_t)(m0 + row) * K + k0 + s_ko], &AS[row][s_ko]);
      gload16(&W[(size_t)(n0 + row) * K + k0 + s_ko], &BS[row][s_ko]);
    }
    __syncthreads();
    f16x8 af[4], bf[4];
#pragma unroll
    for (int f = 0; f < 4; ++f) {
      af[f] = *(const f16x8*)&AS[wr * 64 + f * 16 + llo][lhi * 8];
      bf[f] = *(const f16x8*)&BS[wc * 64 + f * 16 + llo][lhi * 8];
    }
#pragma unroll
    for (int m = 0; m < 4; ++m)
#pragma unroll
      for (int n = 0; n < 4; ++n)
        acc[m][n] = __builtin_amdgcn_mfma_f32_16x16x32_f16(af[m], bf[n], acc[m][n], 0, 0, 0);
    __syncthreads();
  }

#pragma unroll
  for (int n = 0; n < 4; ++n) {
    const int col = n0 + wc * 64 + n * 16 + llo;
    const float bv = bias[col];
#pragma unroll
    for (int m = 0; m < 4; ++m) {
      const int rbase = m0 + wr * 64 + m * 16 + lhi * 4;
#pragma unroll
      for (int j = 0; j < 4; ++j) {
        float v = fmaxf(acc[m][n][j] + bv, 0.f);
        C[(size_t)(rbase + j) * ldc + col] = (f16)v;
      }
    }
  }
}

// ---------------------------------------------------------------------------
// 1-pass fp16 GEMM, 64x128 dbuf (PROVEN r10): FF2 (SPLITK) / final (CONCAT).
// ---------------------------------------------------------------------------
template<bool CONCAT>
__global__ __launch_bounds__(256)
void gemm_f16_1p(const f16* __restrict__ A, const f16* __restrict__ A2,
                 const f16* __restrict__ W,
                 float* __restrict__ Cf, float* __restrict__ Cf1,
                 int ldc, int K)
{
  __shared__ f16 AS[2][64][32], BS[2][128][32];
  const int tid = threadIdx.x;
  const int lane = tid & 63, w = tid >> 6;
  const int wr = w >> 1, wc = w & 1;
  const int lhi = lane >> 4, llo = lane & 15;
  const int n0 = blockIdx.x * 128;
  const int m0 = blockIdx.y * 64;
  const int half = K >> 1;
  const int kbeg = blockIdx.z * half;
  const int nt = half / 32;
  if (blockIdx.z == 1) Cf = Cf1;

  const int s_row = tid >> 2, s_ko = (tid & 3) * 8;

  auto stage = [&](int k0, int buf) {
    const int gk = k0 + s_ko;
    const f16* s = A;
    size_t g;
    if (CONCAT) {
      if (gk < Ee) { g = (size_t)(m0 + s_row) * Ee + gk; }
      else { g = (size_t)(m0 + s_row) * Ee + (gk - Ee); s = A2; }
    } else {
      g = (size_t)(m0 + s_row) * K + gk;
    }
    gload16(&s[g], &AS[buf][s_row][s_ko]);
#pragma unroll
    for (int i = 0; i < 2; ++i)
      gload16(&W[(size_t)(n0 + s_row + i * 64) * K + gk], &BS[buf][s_row + i * 64][s_ko]);
  };

  f32x4 acc[2][4] = {};
  stage(kbeg, 0);
  __syncthreads();
  int cur = 0;
  for (int t = 0; t < nt; ++t) {
    if (t + 1 < nt) stage(kbeg + (t + 1) * 32, cur ^ 1);
    f16x8 af[2], bf[4];
#pragma unroll
    for (int m = 0; m < 2; ++m)
      af[m] = *(const f16x8*)&AS[cur][wr * 32 + m * 16 + llo][lhi * 8];
#pragma unroll
    for (int n = 0; n < 4; ++n)
      bf[n] = *(const f16x8*)&BS[cur][wc * 64 + n * 16 + llo][lhi * 8];
#pragma unroll
    for (int m = 0; m < 2; ++m)
#pragma unroll
      for (int n = 0; n < 4; ++n)
        acc[m][n] = __builtin_amdgcn_mfma_f32_16x16x32_f16(af[m], bf[n], acc[m][n], 0, 0, 0);
    __syncthreads();
    cur ^= 1;
  }

#pragma unroll
  for (int n = 0; n < 4; ++n) {
    const int col = n0 + wc * 64 + n * 16 + llo;
#pragma unroll
    for (int m = 0; m < 2; ++m) {
      const int rbase = m0 + wr * 32 + m * 16 + lhi * 4;
#pragma unroll
      for (int j = 0; j < 4; ++j)
        Cf[(size_t)(rbase + j) * ldc + col] = acc[m][n][j];
    }
  }
}

// ---------------------------------------------------------------------------
// QKV projection (r10 structure): 64x128 dbuf, grid.x=24, sec = bx>>3.
// Q,K: 3-pass f16 (h,l), epilogue writes split (h,l) f16 pairs.
// V (sec==2): 1-pass (skips lo staging + lo MFMAs), plain f16 out.
// ---------------------------------------------------------------------------
__global__ __launch_bounds__(256)
void gemm_qkv(const f16* __restrict__ Ah_g, const f16* __restrict__ Al_g,
              const f16* __restrict__ Wh, const f16* __restrict__ Wl,
              f16* __restrict__ Qh, f16* __restrict__ Ql,
              f16* __restrict__ Kh, f16* __restrict__ Kl,
              f16* __restrict__ Vv)
{
  __shared__ f16 AhS[2][64][32], AlS[2][64][32];
  __shared__ f16 BhS[2][128][32], BlS[2][128][32];
  const int tid = threadIdx.x;
  const int lane = tid & 63, w = tid >> 6;
  const int wr = w >> 1, wc = w & 1;
  const int lhi = lane >> 4, llo = lane & 15;
  const int sec = blockIdx.x >> 3;
  const bool three = (sec < 2);
  const int n0 = (blockIdx.x & 7) * 128;
  Wh += (size_t)sec << 20;
  Wl += (size_t)sec << 20;
  const int m0 = blockIdx.y * 64;
  const int s_row = tid >> 2, s_ko = (tid & 3) * 8;

  auto stage = [&](int k0, int buf) {
    const size_t g = (size_t)(m0 + s_row) * Ee + k0 + s_ko;
    gload16(&Ah_g[g], &AhS[buf][s_row][s_ko]);
    if (three) gload16(&Al_g[g], &AlS[buf][s_row][s_ko]);
#pragma unroll
    for (int i = 0; i < 2; ++i) {
      size_t gb = (size_t)(n0 + s_row + i * 64) * Ee + k0 + s_ko;
      gload16(&Wh[gb], &BhS[buf][s_row + i * 64][s_ko]);
      if (three) gload16(&Wl[gb], &BlS[buf][s_row + i * 64][s_ko]);
    }
  };

  f32x4 acc[2][4] = {};
  stage(0, 0);
  __syncthreads();
  int cur = 0;
  for (int t = 0; t < Ee / 32; ++t) {
    if (t + 1 < Ee / 32) stage((t + 1) * 32, cur ^ 1);
    f16x8 ah[2], bh[4];
#pragma unroll
    for (int m = 0; m < 2; ++m)
      ah[m] = *(const f16x8*)&AhS[cur][wr * 32 + m * 16 + llo][lhi * 8];
#pragma unroll
    for (int n = 0; n < 4; ++n)
      bh[n] = *(const f16x8*)&BhS[cur][wc * 64 + n * 16 + llo][lhi * 8];
    if (three) {
      f16x8 al[2], bl[4];
#pragma unroll
      for (int m = 0; m < 2; ++m)
        al[m] = *(const f16x8*)&AlS[cur][wr * 32 + m * 16 + llo][lhi * 8];
#pragma unroll
      for (int n = 0; n < 4; ++n)
        bl[n] = *(const f16x8*)&BlS[cur][wc * 64 + n * 16 + llo][lhi * 8];
#pragma unroll
      for (int m = 0; m < 2; ++m)
#pragma unroll
        for (int n = 0; n < 4; ++n) {
          acc[m][n] = __builtin_amdgcn_mfma_f32_16x16x32_f16(ah[m], bh[n], acc[m][n], 0, 0, 0);
          acc[m][n] = __builtin_amdgcn_mfma_f32_16x16x32_f16(ah[m], bl[n], acc[m][n], 0, 0, 0);
          acc[m][n] = __builtin_amdgcn_mfma_f32_16x16x32_f16(al[m], bh[n], acc[m][n], 0, 0, 0);
        }
    } else {
#pragma unroll
      for (int m = 0; m < 2; ++m)
#pragma unroll
        for (int n = 0; n < 4; ++n)
          acc[m][n] = __builtin_amdgcn_mfma_f32_16x16x32_f16(ah[m], bh[n], acc[m][n], 0, 0, 0);
    }
    __syncthreads();
    cur ^= 1;
  }

#pragma unroll
  for (int n = 0; n < 4; ++n) {
    const int col = n0 + wc * 64 + n * 16 + llo;
#pragma unroll
    for (int m = 0; m < 2; ++m) {
      const int rbase = m0 + wr * 32 + m * 16 + lhi * 4;
#pragma unroll
      for (int j = 0; j < 4; ++j) {
        const float v = acc[m][n][j];
        const size_t idx = (size_t)(rbase + j) * Ee + col;
        if (sec == 0) {
          f16 h = (f16)v;
          Qh[idx] = h;
          Ql[idx] = (f16)(v - (float)h);
        } else if (sec == 1) {
          f16 h = (f16)v;
          Kh[idx] = h;
          Kl[idx] = (f16)(v - (float)h);
        } else {
          Vv[idx] = (f16)v;
        }
      }
    }
  }
}

// ---------------------------------------------------------------------------
// Split-f16 MFMA flash attention, causal, no 1/sqrt(d).
// Q,K pre-split f16 (h,l); V plain f16. QK^T 3-pass (logit-critical);
// PV 1-pass (linear path). LDS 37 KB -> 4 blocks/CU. Staging = pure copies.
// ---------------------------------------------------------------------------
__global__ __launch_bounds__(256)
void attn_ms(const f16* __restrict__ Qh_g, const f16* __restrict__ Ql_g,
             const f16* __restrict__ Kh_g, const f16* __restrict__ Kl_g,
             const f16* __restrict__ Vv_g, float* __restrict__ O)
{
  __shared__ f16 Ksh[64][72], Ksl[64][72];   // [s][d]
  __shared__ f16 Vs[64][72];                 // [d][s] (transposed)
  __shared__ f16 Pw[4][16][72];              // per-wave P [q_local][s]
  const int tid = threadIdx.x;
  const int lane = tid & 63, w = tid >> 6;
  const int lhi = lane >> 4, llo = lane & 15;
  const int q0 = blockIdx.x * 64;
  const int bh = blockIdx.y;
  const size_t base = (size_t)(bh >> 4) * Tt * Ee + (size_t)(bh & 15) * Dd;

  f16x8 qfh[2], qfl[2];
#pragma unroll
  for (int ks = 0; ks < 2; ++ks) {
    const size_t qoff = base + (size_t)(q0 + w * 16 + llo) * Ee + ks * 32 + lhi * 8;
    qfh[ks] = *(const f16x8*)&Qh_g[qoff];
    qfl[ks] = *(const f16x8*)&Ql_g[qoff];
  }

  f32x4 oacc[4] = {};
  float m_run[4], l_run[4];
#pragma unroll
  for (int j = 0; j < 4; ++j) { m_run[j] = -INFINITY; l_run[j] = 0.f; }

  for (int s0 = 0; s0 <= q0; s0 += 64) {
    // stage K (h,l) row-major and V transposed — pure f16 copies
#pragma unroll
    for (int pass = 0; pass < 2; ++pass) {
      int c = tid + 256 * pass;
      int row = c >> 3, d0 = (c & 7) * 8;
      const size_t g = base + (size_t)(s0 + row) * Ee + d0;
      f16x8 kh = *(const f16x8*)&Kh_g[g];
      f16x8 kl = *(const f16x8*)&Kl_g[g];
      f16x8 vf = *(const f16x8*)&Vv_g[g];
      *(f16x8*)&Ksh[row][d0] = kh;
      *(f16x8*)&Ksl[row][d0] = kl;
#pragma unroll
      for (int j = 0; j < 8; ++j) Vs[d0 + j][row] = vf[j];
    }
    __syncthreads();

    // S = Q K^T (3-pass split)
    f32x4 sacc[4] = {};
#pragma unroll
    for (int ks = 0; ks < 2; ++ks)
#pragma unroll
      for (int n = 0; n < 4; ++n) {
        f16x8 kfh = *(const f16x8*)&Ksh[n * 16 + llo][ks * 32 + lhi * 8];
        f16x8 kfl = *(const f16x8*)&Ksl[n * 16 + llo][ks * 32 + lhi * 8];
        sacc[n] = __builtin_amdgcn_mfma_f32_16x16x32_f16(qfh[ks], kfh, sacc[n], 0, 0, 0);
        sacc[n] = __builtin_amdgcn_mfma_f32_16x16x32_f16(qfh[ks], kfl, sacc[n], 0, 0, 0);
        sacc[n] = __builtin_amdgcn_mfma_f32_16x16x32_f16(qfl[ks], kfh, sacc[n], 0, 0, 0);
      }

    if (s0 == q0) {
#pragma unroll
      for (int n = 0; n < 4; ++n)
#pragma unroll
        for (int j = 0; j < 4; ++j)
          if (n * 16 + llo > w * 16 + lhi * 4 + j) sacc[n][j] = -INFINITY;
    }

    float scj[4];
#pragma unroll
    for (int j = 0; j < 4; ++j) {
      float mt = fmaxf(fmaxf(sacc[0][j], sacc[1][j]), fmaxf(sacc[2][j], sacc[3][j]));
#pragma unroll
      for (int off = 1; off < 16; off <<= 1) mt = fmaxf(mt, __shfl_xor(mt, off));
      float mn = fmaxf(m_run[j], mt);
      scj[j] = __expf(m_run[j] - mn);
      m_run[j] = mn;
      float rs = 0.f;
#pragma unroll
      for (int n = 0; n < 4; ++n) {
        float pp = __expf(sacc[n][j] - mn);
        sacc[n][j] = pp;
        rs += pp;
      }
#pragma unroll
      for (int off = 1; off < 16; off <<= 1) rs += __shfl_xor(rs, off);
      l_run[j] = l_run[j] * scj[j] + rs;
    }

    // P -> per-wave LDS (f16, 1-pass precision is sufficient: P in [0,1])
#pragma unroll
    for (int n = 0; n < 4; ++n)
#pragma unroll
      for (int j = 0; j < 4; ++j)
        Pw[w][lhi * 4 + j][n * 16 + llo] = (f16)sacc[n][j];
#pragma unroll
    for (int df = 0; df < 4; ++df)
#pragma unroll
      for (int j = 0; j < 4; ++j)
        oacc[df][j] *= scj[j];

    // O += P V (1-pass)
#pragma unroll
    for (int ks = 0; ks < 2; ++ks) {
      f16x8 pf = *(const f16x8*)&Pw[w][llo][ks * 32 + lhi * 8];
#pragma unroll
      for (int df = 0; df < 4; ++df) {
        f16x8 vfr = *(const f16x8*)&Vs[df * 16 + llo][ks * 32 + lhi * 8];
        oacc[df] = __builtin_amdgcn_mfma_f32_16x16x32_f16(pf, vfr, oacc[df], 0, 0, 0);
      }
    }
    __syncthreads();
  }

#pragma unroll
  for (int j = 0; j < 4; ++j) {
    float inv = 1.f / l_run[j];
#pragma unroll
    for (int df = 0; df < 4; ++df)
      O[base + (size_t)(q0 + w * 16 + lhi * 4 + j) * Ee + df * 16 + llo] =
          oacc[df][j] * inv;
  }
}

// ---------------------------------------------------------------------------
// Per-head LN over D=64 + residual; writes fp32 + (hi,lo) f16 streams.
// ---------------------------------------------------------------------------
__global__ __launch_bounds__(256)
void attn_ln_res(const float* __restrict__ O, const float* __restrict__ Yin,
                 const float* __restrict__ g, const float* __restrict__ bta,
                 float* __restrict__ Yout, f16* __restrict__ Yh, f16* __restrict__ Yl)
{
  const int tid = threadIdx.x;
  const int w = (blockIdx.x << 2) + (tid >> 6);
  const int lane = tid & 63;
  const int m = w >> 4;
  const int h = w & 15;
  const size_t idx = (size_t)m * Ee + h * Dd + lane;
  float x = O[idx];
  float s = x, s2 = x * x;
#pragma unroll
  for (int off = 1; off < 64; off <<= 1) {
    s  += __shfl_xor(s, off);
    s2 += __shfl_xor(s2, off);
  }
  float mean = s * (1.f / 64.f);
  float var  = s2 * (1.f / 64.f) - mean * mean;
  float inv  = rsqrtf(var + EPS);
  float r = Yin[idx] + (x - mean) * inv * g[h * Dd + lane] + bta[h * Dd + lane];
  Yout[idx] = r;
  f16 hh = (f16)r;
  Yh[idx] = hh;
  Yl[idx] = (f16)(r - (float)hh);
}

// ---------------------------------------------------------------------------
// Row LN over E=1024 + residual. Input = T0 + T1 + bias (split-K partials).
// ---------------------------------------------------------------------------
__global__ __launch_bounds__(256)
void ff_ln_res(const float* __restrict__ T0, const float* __restrict__ T1,
               const float* __restrict__ b2,
               const float* __restrict__ Yin, const float* __restrict__ g,
               const float* __restrict__ bb,
               float* __restrict__ Yout, f16* __restrict__ Yh, f16* __restrict__ Yl)
{
  __shared__ float red[8];
  const int m = blockIdx.x;
  const int tid = threadIdx.x;
  const size_t basep = (size_t)m * Ee;
  float4 xa = *(const float4*)&T0[basep + (tid << 2)];
  float4 xb = *(const float4*)&T1[basep + (tid << 2)];
  float4 bv2 = *(const float4*)&b2[tid << 2];
  float xv[4] = {xa.x + xb.x + bv2.x, xa.y + xb.y + bv2.y,
                 xa.z + xb.z + bv2.z, xa.w + xb.w + bv2.w};
  float s  = xv[0] + xv[1] + xv[2] + xv[3];
  float s2 = xv[0]*xv[0] + xv[1]*xv[1] + xv[2]*xv[2] + xv[3]*xv[3];
#pragma unroll
  for (int off = 1; off < 64; off <<= 1) {
    s  += __shfl_xor(s, off);
    s2 += __shfl_xor(s2, off);
  }
  const int wid = tid >> 6;
  if ((tid & 63) == 0) { red[wid] = s; red[4 + wid] = s2; }
  __syncthreads();
  s  = red[0] + red[1] + red[2] + red[3];
  s2 = red[4] + red[5] + red[6] + red[7];
  float mean = s * (1.f / Ee);
  float var  = s2 * (1.f / Ee) - mean * mean;
  float inv  = rsqrtf(var + EPS);
  float4 y  = *(const float4*)&Yin[basep + (tid << 2)];
  float4 gg = *(const float4*)&g[tid << 2];
  float4 bv = *(const float4*)&bb[tid << 2];
  float gga[4] = {gg.x, gg.y, gg.z, gg.w};
  float bva[4] = {bv.x, bv.y, bv.z, bv.w};
  float ya[4] = {y.x, y.y, y.z, y.w};
  float o[4];
#pragma unroll
  for (int j = 0; j < 4; ++j) {
    o[j] = ya[j] + (xv[j] - mean) * inv * gga[j] + bva[j];
    f16 hh = (f16)o[j];
    Yh[basep + (tid << 2) + j] = hh;
    Yl[basep + (tid << 2) + j] = (f16)(o[j] - (float)hh);
  }
  *(float4*)&Yout[basep + (tid << 2)] = *(float4*)o;
}

// out = p0 + p1 + bias (final linear reduce)
__global__ __launch_bounds__(256)
void add2_bias(const float* __restrict__ p0, const float* __restrict__ p1,
               const float* __restrict__ b, float* __restrict__ out)
{
  const size_t i = ((size_t)blockIdx.x * 256 + threadIdx.x) * 4;
  const int col = (int)(i & (Ee - 1));
  float4 a = *(const float4*)&p0[i];
  float4 c = *(const float4*)&p1[i];
  float4 bb = *(const float4*)&b[col];
  float4 o;
  o.x = a.x + c.x + bb.x; o.y = a.y + c.y + bb.y;
  o.z = a.z + c.z + bb.z; o.w = a.w + c.w + bb.w;
  *(float4*)&out[i] = o;
}

// fp32 -> (hi,lo) f16 split, no transpose (x activations).
__global__ __launch_bounds__(256)
void split_act(const float* __restrict__ in, f16* __restrict__ oh, f16* __restrict__ ol)
{
  const size_t i = ((size_t)blockIdx.x * 256 + threadIdx.x) * 4;
  float4 v = *(const float4*)&in[i];
  float f[4] = {v.x, v.y, v.z, v.w};
#pragma unroll
  for (int j = 0; j < 4; ++j) {
    f16 h = (f16)f[j];
    oh[i + j] = h;
    ol[i + j] = (f16)(f[j] - (float)h);
  }
}

// fp32 [R][C] -> f16 [C][R] transpose (FF + final weights).
__global__ __launch_bounds__(256)
void cvtT_f16(const float* __restrict__ in, f16* __restrict__ outp, int R, int C)
{
  __shared__ float tile[32][33];
  const int c0 = blockIdx.x * 32, r0 = blockIdx.y * 32;
  const int tid = threadIdx.x;
  const int ir = tid >> 3, ic = (tid & 7) * 4;
  float4 v = *(const float4*)&in[(size_t)(r0 + ir) * C + c0 + ic];
  tile[ir][ic] = v.x; tile[ir][ic + 1] = v.y;
  tile[ir][ic + 2] = v.z; tile[ir][ic + 3] = v.w;
  __syncthreads();
  const int oc = tid >> 3, orr = (tid & 7) * 4;
  const size_t ob = (size_t)(c0 + oc) * R + r0 + orr;
#pragma unroll
  for (int j = 0; j < 4; ++j)
    outp[ob + j] = (f16)tile[orr + j][oc];
}

// Fused QKV weight transpose-split (f16 h/l): z = sec*16 + head.
__global__ __launch_bounds__(256)
void cvtT_qkv(const float* __restrict__ wq, const float* __restrict__ wk,
              const float* __restrict__ wv, f16* __restrict__ out_h,
              f16* __restrict__ out_l)
{
  __shared__ float tile[32][33];
  const int z = blockIdx.z, sec = z >> 4, hh = z & 15;
  const float* in = (sec == 0) ? wq : (sec == 1) ? wk : wv;
  const size_t zi = (size_t)hh * Ee * Dd;
  const size_t zo = ((size_t)sec << 20) + (size_t)hh * Ee * Dd;
  const int c0 = blockIdx.x * 32, r0 = blockIdx.y * 32;
  const int tid = threadIdx.x;
  const int ir = tid >> 3, ic = (tid & 7) * 4;
  float4 v = *(const float4*)&in[zi + (size_t)(r0 + ir) * Dd + c0 + ic];
  tile[ir][ic] = v.x; tile[ir][ic + 1] = v.y;
  tile[ir][ic + 2] = v.z; tile[ir][ic + 3] = v.w;
  __syncthreads();
  const int oc = tid >> 3, orr = (tid & 7) * 4;
  const size_t ob = zo + (size_t)(c0 + oc) * Ee + r0 + orr;
#pragma unroll
  for (int j = 0; j < 4; ++j) {
    float f = tile[orr + j][oc];
    f16 h = (f16)f;
    out_h[ob + j] = h;
    out_l[ob + j] = (f16)(f - (float)h);
  }
}

// ---------------------------------------------------------------------------
extern "C" void kernel_launch(void* const* d_in, const int* in_sizes, int n_in,
                              void* d_out, int out_size, void* d_ws, size_t ws_size,
                              hipStream_t stream)
{
  const float* x     = (const float*)d_in[0];
  const float* mh_wq = (const float*)d_in[1];
  const float* mh_wk = (const float*)d_in[2];
  const float* mh_wv = (const float*)d_in[3];
  const float* mh_g  = (const float*)d_in[4];
  const float* mh_b  = (const float*)d_in[5];
  const float* ff_w1 = (const float*)d_in[6];
  const float* ff_b1 = (const float*)d_in[7];
  const float* ff_w2 = (const float*)d_in[8];
  const float* ff_b2 = (const float*)d_in[9];
  const float* ff_g  = (const float*)d_in[10];
  const float* ff_bb = (const float*)d_in[11];
  const float* lt_w  = (const float*)d_in[12];
  const float* lt_b  = (const float*)d_in[13];
  float* out = (float*)d_out;

  const size_t ME = (size_t)Mm * Ee;   // 2M elements
  char* p = (char*)d_ws;
  auto alloc = [&](size_t bytes) { void* r = (void*)p; p += (bytes + 255) & ~(size_t)255; return r; };
  float* bufA  = (float*)alloc(ME * 4);                // 8 MB
  f16*   bufAh = (f16*)alloc(ME * 2);                  // 4 MB
  f16*   bufAl = (f16*)alloc(ME * 2);                  // 4 MB
  float* bufB  = (float*)alloc(ME * 4);                // 8 MB
  f16*   bufBh = (f16*)alloc(ME * 2);                  // 4 MB
  f16*   bufBl = (f16*)alloc(ME * 2);                  // 4 MB
  f16*   wt_h  = (f16*)alloc((size_t)Ff * Ee * 2);     // 8 MB (FF w f16 / QKV h slabs)
  f16*   wt_l  = (f16*)alloc((size_t)Ff * Ee * 2);     // 8 MB (QKV l slabs)
  float* reg   = (float*)alloc((size_t)10 * 1024 * 1024 * 4);  // 40 MB union
  // mh phase: 5 f16 [M,E] buffers (20 MB) + ob fp32 (8 MB at 20..28 MB)
  f16*   qh_   = (f16*)reg;
  f16*   ql_   = qh_ + ME;
  f16*   kh_   = qh_ + 2 * ME;
  f16*   kl_   = qh_ + 3 * ME;
  f16*   vv_   = qh_ + 4 * ME;
  float* ob    = reg + 5 * 1024 * 1024;        // 20..28 MB
  f16*   hid   = (f16*)reg;                    // ff phase: [M,F] f16 = 16 MB
  float* tmp   = reg + 8 * 1024 * 1024;        // fp32 partial (32..40 MB)

  auto mh = [&](int i, const float* srcF, const f16* srcH, const f16* srcL,
                float* dstF, f16* dstH, f16* dstL) {
    const size_t wo = (size_t)i * Hh * Ee * Dd;
    cvtT_qkv<<<dim3(Dd / 32, Ee / 32, 48), 256, 0, stream>>>(
        mh_wq + wo, mh_wk + wo, mh_wv + wo, wt_h, wt_l);
    gemm_qkv<<<dim3(24, Mm / 64), 256, 0, stream>>>(
        srcH, srcL, wt_h, wt_l, qh_, ql_, kh_, kl_, vv_);
    attn_ms<<<dim3(Tt / 64, Bb * Hh), 256, 0, stream>>>(qh_, ql_, kh_, kl_, vv_, ob);
    attn_ln_res<<<dim3(Mm * Hh / 4), 256, 0, stream>>>(
        ob, srcF, mh_g + (size_t)i * Hh * Dd, mh_b + (size_t)i * Hh * Dd, dstF, dstH, dstL);
  };
  // tmp1: fp32 scratch [M,E] for the z=1 split-K partial (a dead buffer).
  auto ff = [&](int i, const float* srcF, const f16* srcH,
                float* dstF, f16* dstH, f16* dstL, float* tmp1) {
    cvtT_f16<<<dim3(Ff / 32, Ee / 32), 256, 0, stream>>>(ff_w1 + (size_t)i * Ee * Ff, wt_h, Ee, Ff);
    gemm_f16_128<<<dim3(Ff / 128, Mm / 128), 256, 0, stream>>>(
        srcH, wt_h, ff_b1 + (size_t)i * Ff, hid, Ff, Ee);
    cvtT_f16<<<dim3(Ee / 32, Ff / 32), 256, 0, stream>>>(ff_w2 + (size_t)i * Ff * Ee, wt_h, Ff, Ee);
    gemm_f16_1p<false><<<dim3(Ee / 128, Mm / 64, 2), 256, 0, stream>>>(
        hid, nullptr, wt_h, tmp, tmp1, Ee, Ff);
    ff_ln_res<<<dim3(Mm), 256, 0, stream>>>(
        tmp, tmp1, ff_b2 + (size_t)i * Ee,
        srcF, ff_g + (size_t)i * Ee, ff_bb + (size_t)i * Ee, dstF, dstH, dstL);
  };

  // out_one branch: ff(3, mh(4, mh(0, x)))   [bufB fp32 dead -> tmp1]
  split_act<<<dim3(ME / 1024), 256, 0, stream>>>(x, bufAh, bufAl);
  mh(0, x, bufAh, bufAl, bufA, bufAh, bufAl);
  mh(4, bufA, bufAh, bufAl, bufA, bufAh, bufAl);
  ff(3, bufA, bufAh, bufA, bufAh, bufAl, bufB);

  // out_two branch: 3 encoder blocks then decoder  [bufA fp32 dead -> tmp1]
  split_act<<<dim3(ME / 1024), 256, 0, stream>>>(x, bufBh, bufBl);
  mh(1, x, bufBh, bufBl, bufB, bufBh, bufBl);
  ff(0, bufB, bufBh, bufB, bufBh, bufBl, bufA);
  mh(2, bufB, bufBh, bufBl, bufB, bufBh, bufBl);
  ff(1, bufB, bufBh, bufB, bufBh, bufBl, bufA);
  mh(3, bufB, bufBh, bufBl, bufB, bufBh, bufBl);
  ff(2, bufB, bufBh, bufB, bufBh, bufBl, bufA);
  mh(4, bufB, bufBh, bufBl, bufB, bufBh, bufBl);
  ff(3, bufB, bufBh, bufB, bufBh, bufBl, bufA);

  // final: out = concat(A,B)@lt_w + lt_b, 1-pass f16, split-K=2 into dead bufs
  cvtT_f16<<<dim3(Ee / 32, 2 * Ee / 32), 256, 0, stream>>>(lt_w, wt_h, 2 * Ee, Ee);
  gemm_f16_1p<true><<<dim3(Ee / 128, Mm / 64, 2), 256, 0, stream>>>(
      bufAh, bufBh, wt_h, bufA, bufB, Ee, 2 * Ee);
  add2_bias<<<dim3(ME / 1024), 256, 0, stream>>>(bufA, bufB, lt_b, out);
}

// Round 15
// 1036.512 us; speedup vs baseline: 4.5137x; 1.0024x over previous
//
#include <hip/hip_runtime.h>
#include <math.h>

#define Bb 4
#define Tt 512
#define Ee 1024
#define Hh 16
#define Dd 64
#define Ff 4096
#define Mm (Bb*Tt)   // 2048
static constexpr float EPS = 1e-5f;

typedef __attribute__((ext_vector_type(4))) float f32x4;
typedef _Float16 f16;
typedef __attribute__((ext_vector_type(8))) _Float16 f16x8;

// async global->LDS, 16B per lane. LDS dest must be lane-linear.
__device__ __forceinline__ void gload16(const void* g, void* l) {
  __builtin_amdgcn_global_load_lds(
      (const __attribute__((address_space(1))) unsigned int*)g,
      (__attribute__((address_space(3))) unsigned int*)l, 16, 0, 0);
}

// ---------------------------------------------------------------------------
// FF1: 1-pass fp16 GEMM, m97 structure (PROVEN r10/r11). 128x128, BK=32,
// single-buffer 16KB LDS, gload_lds staging. Bias+ReLU, f16 out.
// ---------------------------------------------------------------------------
__global__ __launch_bounds__(256)
void gemm_f16_128(const f16* __restrict__ A, const f16* __restrict__ W,
                  const float* __restrict__ bias,
                  f16* __restrict__ C, int ldc, int K)
{
  __shared__ f16 AS[128][32], BS[128][32];
  const int tid = threadIdx.x;
  const int lane = tid & 63, w = tid >> 6;
  const int wr = w >> 1, wc = w & 1;
  const int lhi = lane >> 4, llo = lane & 15;
  const int n0 = blockIdx.x * 128, m0 = blockIdx.y * 128;
  const int s_row = tid >> 2, s_ko = (tid & 3) * 8;

  f32x4 acc[4][4] = {};

  for (int k0 = 0; k0 < K; k0 += 32) {
#pragma unroll
    for (int i = 0; i < 2; ++i) {
      const int row = s_row + i * 64;
      gload16(&A[(size_t)(m0 + row) * K + k0 + s_ko], &AS[row][s_ko]);
      gload16(&W[(size_t)(n0 + row) * K + k0 + s_ko], &BS[row][s_ko]);
    }
    __syncthreads();
    f16x8 af[4], bf[4];
#pragma unroll
    for (int f = 0; f < 4; ++f) {
      af[f] = *(const f16x8*)&AS[wr * 64 + f * 16 + llo][lhi * 8];
      bf[f] = *(const f16x8*)&BS[wc * 64 + f * 16 + llo][lhi * 8];
    }
#pragma unroll
    for (int m = 0; m < 4; ++m)
#pragma unroll
      for (int n = 0; n < 4; ++n)
        acc[m][n] = __builtin_amdgcn_mfma_f32_16x16x32_f16(af[m], bf[n], acc[m][n], 0, 0, 0);
    __syncthreads();
  }

#pragma unroll
  for (int n = 0; n < 4; ++n) {
    const int col = n0 + wc * 64 + n * 16 + llo;
    const float bv = bias[col];
#pragma unroll
    for (int m = 0; m < 4; ++m) {
      const int rbase = m0 + wr * 64 + m * 16 + lhi * 4;
#pragma unroll
      for (int j = 0; j < 4; ++j) {
        float v = fmaxf(acc[m][n][j] + bv, 0.f);
        C[(size_t)(rbase + j) * ldc + col] = (f16)v;
      }
    }
  }
}

// ---------------------------------------------------------------------------
// 1-pass fp16 GEMM, 64x128 dbuf (PROVEN r10/r11): FF2 (SPLITK) / final.
// ---------------------------------------------------------------------------
template<bool CONCAT>
__global__ __launch_bounds__(256)
void gemm_f16_1p(const f16* __restrict__ A, const f16* __restrict__ A2,
                 const f16* __restrict__ W,
                 float* __restrict__ Cf, float* __restrict__ Cf1,
                 int ldc, int K)
{
  __shared__ f16 AS[2][64][32], BS[2][128][32];
  const int tid = threadIdx.x;
  const int lane = tid & 63, w = tid >> 6;
  const int wr = w >> 1, wc = w & 1;
  const int lhi = lane >> 4, llo = lane & 15;
  const int n0 = blockIdx.x * 128;
  const int m0 = blockIdx.y * 64;
  const int half = K >> 1;
  const int kbeg = blockIdx.z * half;
  const int nt = half / 32;
  if (blockIdx.z == 1) Cf = Cf1;

  const int s_row = tid >> 2, s_ko = (tid & 3) * 8;

  auto stage = [&](int k0, int buf) {
    const int gk = k0 + s_ko;
    const f16* s = A;
    size_t g;
    if (CONCAT) {
      if (gk < Ee) { g = (size_t)(m0 + s_row) * Ee + gk; }
      else { g = (size_t)(m0 + s_row) * Ee + (gk - Ee); s = A2; }
    } else {
      g = (size_t)(m0 + s_row) * K + gk;
    }
    gload16(&s[g], &AS[buf][s_row][s_ko]);
#pragma unroll
    for (int i = 0; i < 2; ++i)
      gload16(&W[(size_t)(n0 + s_row + i * 64) * K + gk], &BS[buf][s_row + i * 64][s_ko]);
  };

  f32x4 acc[2][4] = {};
  stage(kbeg, 0);
  __syncthreads();
  int cur = 0;
  for (int t = 0; t < nt; ++t) {
    if (t + 1 < nt) stage(kbeg + (t + 1) * 32, cur ^ 1);
    f16x8 af[2], bf[4];
#pragma unroll
    for (int m = 0; m < 2; ++m)
      af[m] = *(const f16x8*)&AS[cur][wr * 32 + m * 16 + llo][lhi * 8];
#pragma unroll
    for (int n = 0; n < 4; ++n)
      bf[n] = *(const f16x8*)&BS[cur][wc * 64 + n * 16 + llo][lhi * 8];
#pragma unroll
    for (int m = 0; m < 2; ++m)
#pragma unroll
      for (int n = 0; n < 4; ++n)
        acc[m][n] = __builtin_amdgcn_mfma_f32_16x16x32_f16(af[m], bf[n], acc[m][n], 0, 0, 0);
    __syncthreads();
    cur ^= 1;
  }

#pragma unroll
  for (int n = 0; n < 4; ++n) {
    const int col = n0 + wc * 64 + n * 16 + llo;
#pragma unroll
    for (int m = 0; m < 2; ++m) {
      const int rbase = m0 + wr * 32 + m * 16 + lhi * 4;
#pragma unroll
      for (int j = 0; j < 4; ++j)
        Cf[(size_t)(rbase + j) * ldc + col] = acc[m][n][j];
    }
  }
}

// ---------------------------------------------------------------------------
// QKV projection (PROVEN r11): 64x128 dbuf, grid.x=24, sec = bx>>3.
// Q,K: 3-pass f16 (h,l) -> split (h,l) out. V: 1-pass -> plain f16 out.
// ---------------------------------------------------------------------------
__global__ __launch_bounds__(256)
void gemm_qkv(const f16* __restrict__ Ah_g, const f16* __restrict__ Al_g,
              const f16* __restrict__ Wh, const f16* __restrict__ Wl,
              f16* __restrict__ Qh, f16* __restrict__ Ql,
              f16* __restrict__ Kh, f16* __restrict__ Kl,
              f16* __restrict__ Vv)
{
  __shared__ f16 AhS[2][64][32], AlS[2][64][32];
  __shared__ f16 BhS[2][128][32], BlS[2][128][32];
  const int tid = threadIdx.x;
  const int lane = tid & 63, w = tid >> 6;
  const int wr = w >> 1, wc = w & 1;
  const int lhi = lane >> 4, llo = lane & 15;
  const int sec = blockIdx.x >> 3;
  const bool three = (sec < 2);
  const int n0 = (blockIdx.x & 7) * 128;
  Wh += (size_t)sec << 20;
  Wl += (size_t)sec << 20;
  const int m0 = blockIdx.y * 64;
  const int s_row = tid >> 2, s_ko = (tid & 3) * 8;

  auto stage = [&](int k0, int buf) {
    const size_t g = (size_t)(m0 + s_row) * Ee + k0 + s_ko;
    gload16(&Ah_g[g], &AhS[buf][s_row][s_ko]);
    if (three) gload16(&Al_g[g], &AlS[buf][s_row][s_ko]);
#pragma unroll
    for (int i = 0; i < 2; ++i) {
      size_t gb = (size_t)(n0 + s_row + i * 64) * Ee + k0 + s_ko;
      gload16(&Wh[gb], &BhS[buf][s_row + i * 64][s_ko]);
      if (three) gload16(&Wl[gb], &BlS[buf][s_row + i * 64][s_ko]);
    }
  };

  f32x4 acc[2][4] = {};
  stage(0, 0);
  __syncthreads();
  int cur = 0;
  for (int t = 0; t < Ee / 32; ++t) {
    if (t + 1 < Ee / 32) stage((t + 1) * 32, cur ^ 1);
    f16x8 ah[2], bh[4];
#pragma unroll
    for (int m = 0; m < 2; ++m)
      ah[m] = *(const f16x8*)&AhS[cur][wr * 32 + m * 16 + llo][lhi * 8];
#pragma unroll
    for (int n = 0; n < 4; ++n)
      bh[n] = *(const f16x8*)&BhS[cur][wc * 64 + n * 16 + llo][lhi * 8];
    if (three) {
      f16x8 al[2], bl[4];
#pragma unroll
      for (int m = 0; m < 2; ++m)
        al[m] = *(const f16x8*)&AlS[cur][wr * 32 + m * 16 + llo][lhi * 8];
#pragma unroll
      for (int n = 0; n < 4; ++n)
        bl[n] = *(const f16x8*)&BlS[cur][wc * 64 + n * 16 + llo][lhi * 8];
#pragma unroll
      for (int m = 0; m < 2; ++m)
#pragma unroll
        for (int n = 0; n < 4; ++n) {
          acc[m][n] = __builtin_amdgcn_mfma_f32_16x16x32_f16(ah[m], bh[n], acc[m][n], 0, 0, 0);
          acc[m][n] = __builtin_amdgcn_mfma_f32_16x16x32_f16(ah[m], bl[n], acc[m][n], 0, 0, 0);
          acc[m][n] = __builtin_amdgcn_mfma_f32_16x16x32_f16(al[m], bh[n], acc[m][n], 0, 0, 0);
        }
    } else {
#pragma unroll
      for (int m = 0; m < 2; ++m)
#pragma unroll
        for (int n = 0; n < 4; ++n)
          acc[m][n] = __builtin_amdgcn_mfma_f32_16x16x32_f16(ah[m], bh[n], acc[m][n], 0, 0, 0);
    }
    __syncthreads();
    cur ^= 1;
  }

#pragma unroll
  for (int n = 0; n < 4; ++n) {
    const int col = n0 + wc * 64 + n * 16 + llo;
#pragma unroll
    for (int m = 0; m < 2; ++m) {
      const int rbase = m0 + wr * 32 + m * 16 + lhi * 4;
#pragma unroll
      for (int j = 0; j < 4; ++j) {
        const float v = acc[m][n][j];
        const size_t idx = (size_t)(rbase + j) * Ee + col;
        if (sec == 0) {
          f16 h = (f16)v;
          Qh[idx] = h;
          Ql[idx] = (f16)(v - (float)h);
        } else if (sec == 1) {
          f16 h = (f16)v;
          Kh[idx] = h;
          Kl[idx] = (f16)(v - (float)h);
        } else {
          Vv[idx] = (f16)v;
        }
      }
    }
  }
}

// ---------------------------------------------------------------------------
// Split-f16 MFMA flash attention (PROVEN r11, byte-identical), causal.
// Q,K pre-split f16 (h,l); V plain f16. QK^T 3-pass; PV 1-pass.
// ---------------------------------------------------------------------------
__global__ __launch_bounds__(256)
void attn_ms(const f16* __restrict__ Qh_g, const f16* __restrict__ Ql_g,
             const f16* __restrict__ Kh_g, const f16* __restrict__ Kl_g,
             const f16* __restrict__ Vv_g, float* __restrict__ O)
{
  __shared__ f16 Ksh[64][72], Ksl[64][72];   // [s][d]
  __shared__ f16 Vs[64][72];                 // [d][s] (transposed)
  __shared__ f16 Pw[4][16][72];              // per-wave P [q_local][s]
  const int tid = threadIdx.x;
  const int lane = tid & 63, w = tid >> 6;
  const int lhi = lane >> 4, llo = lane & 15;
  const int q0 = blockIdx.x * 64;
  const int bh = blockIdx.y;
  const size_t base = (size_t)(bh >> 4) * Tt * Ee + (size_t)(bh & 15) * Dd;

  f16x8 qfh[2], qfl[2];
#pragma unroll
  for (int ks = 0; ks < 2; ++ks) {
    const size_t qoff = base + (size_t)(q0 + w * 16 + llo) * Ee + ks * 32 + lhi * 8;
    qfh[ks] = *(const f16x8*)&Qh_g[qoff];
    qfl[ks] = *(const f16x8*)&Ql_g[qoff];
  }

  f32x4 oacc[4] = {};
  float m_run[4], l_run[4];
#pragma unroll
  for (int j = 0; j < 4; ++j) { m_run[j] = -INFINITY; l_run[j] = 0.f; }

  for (int s0 = 0; s0 <= q0; s0 += 64) {
#pragma unroll
    for (int pass = 0; pass < 2; ++pass) {
      int c = tid + 256 * pass;
      int row = c >> 3, d0 = (c & 7) * 8;
      const size_t g = base + (size_t)(s0 + row) * Ee + d0;
      f16x8 kh = *(const f16x8*)&Kh_g[g];
      f16x8 kl = *(const f16x8*)&Kl_g[g];
      f16x8 vf = *(const f16x8*)&Vv_g[g];
      *(f16x8*)&Ksh[row][d0] = kh;
      *(f16x8*)&Ksl[row][d0] = kl;
#pragma unroll
      for (int j = 0; j < 8; ++j) Vs[d0 + j][row] = vf[j];
    }
    __syncthreads();

    f32x4 sacc[4] = {};
#pragma unroll
    for (int ks = 0; ks < 2; ++ks)
#pragma unroll
      for (int n = 0; n < 4; ++n) {
        f16x8 kfh = *(const f16x8*)&Ksh[n * 16 + llo][ks * 32 + lhi * 8];
        f16x8 kfl = *(const f16x8*)&Ksl[n * 16 + llo][ks * 32 + lhi * 8];
        sacc[n] = __builtin_amdgcn_mfma_f32_16x16x32_f16(qfh[ks], kfh, sacc[n], 0, 0, 0);
        sacc[n] = __builtin_amdgcn_mfma_f32_16x16x32_f16(qfh[ks], kfl, sacc[n], 0, 0, 0);
        sacc[n] = __builtin_amdgcn_mfma_f32_16x16x32_f16(qfl[ks], kfh, sacc[n], 0, 0, 0);
      }

    if (s0 == q0) {
#pragma unroll
      for (int n = 0; n < 4; ++n)
#pragma unroll
        for (int j = 0; j < 4; ++j)
          if (n * 16 + llo > w * 16 + lhi * 4 + j) sacc[n][j] = -INFINITY;
    }

    float scj[4];
#pragma unroll
    for (int j = 0; j < 4; ++j) {
      float mt = fmaxf(fmaxf(sacc[0][j], sacc[1][j]), fmaxf(sacc[2][j], sacc[3][j]));
#pragma unroll
      for (int off = 1; off < 16; off <<= 1) mt = fmaxf(mt, __shfl_xor(mt, off));
      float mn = fmaxf(m_run[j], mt);
      scj[j] = __expf(m_run[j] - mn);
      m_run[j] = mn;
      float rs = 0.f;
#pragma unroll
      for (int n = 0; n < 4; ++n) {
        float pp = __expf(sacc[n][j] - mn);
        sacc[n][j] = pp;
        rs += pp;
      }
#pragma unroll
      for (int off = 1; off < 16; off <<= 1) rs += __shfl_xor(rs, off);
      l_run[j] = l_run[j] * scj[j] + rs;
    }

#pragma unroll
    for (int n = 0; n < 4; ++n)
#pragma unroll
      for (int j = 0; j < 4; ++j)
        Pw[w][lhi * 4 + j][n * 16 + llo] = (f16)sacc[n][j];
#pragma unroll
    for (int df = 0; df < 4; ++df)
#pragma unroll
      for (int j = 0; j < 4; ++j)
        oacc[df][j] *= scj[j];

#pragma unroll
    for (int ks = 0; ks < 2; ++ks) {
      f16x8 pf = *(const f16x8*)&Pw[w][llo][ks * 32 + lhi * 8];
#pragma unroll
      for (int df = 0; df < 4; ++df) {
        f16x8 vfr = *(const f16x8*)&Vs[df * 16 + llo][ks * 32 + lhi * 8];
        oacc[df] = __builtin_amdgcn_mfma_f32_16x16x32_f16(pf, vfr, oacc[df], 0, 0, 0);
      }
    }
    __syncthreads();
  }

#pragma unroll
  for (int j = 0; j < 4; ++j) {
    float inv = 1.f / l_run[j];
#pragma unroll
    for (int df = 0; df < 4; ++df)
      O[base + (size_t)(q0 + w * 16 + lhi * 4 + j) * Ee + df * 16 + llo] =
          oacc[df][j] * inv;
  }
}

// ---------------------------------------------------------------------------
// Per-head LN over D=64 + residual (PROVEN r11); fp32 + (h,l) f16 streams.
// ---------------------------------------------------------------------------
__global__ __launch_bounds__(256)
void attn_ln_res(const float* __restrict__ O, const float* Yin,
                 const float* __restrict__ g, const float* __restrict__ bta,
                 float* Yout, f16* __restrict__ Yh, f16* __restrict__ Yl)
{
  const int tid = threadIdx.x;
  const int w = (blockIdx.x << 2) + (tid >> 6);
  const int lane = tid & 63;
  const int m = w >> 4;
  const int h = w & 15;
  const size_t idx = (size_t)m * Ee + h * Dd + lane;
  float x = O[idx];
  float s = x, s2 = x * x;
#pragma unroll
  for (int off = 1; off < 64; off <<= 1) {
    s  += __shfl_xor(s, off);
    s2 += __shfl_xor(s2, off);
  }
  float mean = s * (1.f / 64.f);
  float var  = s2 * (1.f / 64.f) - mean * mean;
  float inv  = rsqrtf(var + EPS);
  float r = Yin[idx] + (x - mean) * inv * g[h * Dd + lane] + bta[h * Dd + lane];
  Yout[idx] = r;
  f16 hh = (f16)r;
  Yh[idx] = hh;
  Yl[idx] = (f16)(r - (float)hh);
}

// ---------------------------------------------------------------------------
// Row LN over E=1024 + residual (PROVEN r11). Input = T0 + T1 + bias.
// ---------------------------------------------------------------------------
__global__ __launch_bounds__(256)
void ff_ln_res(const float* __restrict__ T0, const float* __restrict__ T1,
               const float* __restrict__ b2,
               const float* Yin, const float* __restrict__ g,
               const float* __restrict__ bb,
               float* Yout, f16* __restrict__ Yh, f16* __restrict__ Yl)
{
  __shared__ float red[8];
  const int m = blockIdx.x;
  const int tid = threadIdx.x;
  const size_t basep = (size_t)m * Ee;
  float4 xa = *(const float4*)&T0[basep + (tid << 2)];
  float4 xb = *(const float4*)&T1[basep + (tid << 2)];
  float4 bv2 = *(const float4*)&b2[tid << 2];
  float xv[4] = {xa.x + xb.x + bv2.x, xa.y + xb.y + bv2.y,
                 xa.z + xb.z + bv2.z, xa.w + xb.w + bv2.w};
  float s  = xv[0] + xv[1] + xv[2] + xv[3];
  float s2 = xv[0]*xv[0] + xv[1]*xv[1] + xv[2]*xv[2] + xv[3]*xv[3];
#pragma unroll
  for (int off = 1; off < 64; off <<= 1) {
    s  += __shfl_xor(s, off);
    s2 += __shfl_xor(s2, off);
  }
  const int wid = tid >> 6;
  if ((tid & 63) == 0) { red[wid] = s; red[4 + wid] = s2; }
  __syncthreads();
  s  = red[0] + red[1] + red[2] + red[3];
  s2 = red[4] + red[5] + red[6] + red[7];
  float mean = s * (1.f / Ee);
  float var  = s2 * (1.f / Ee) - mean * mean;
  float inv  = rsqrtf(var + EPS);
  float4 y  = *(const float4*)&Yin[basep + (tid << 2)];
  float4 gg = *(const float4*)&g[tid << 2];
  float4 bv = *(const float4*)&bb[tid << 2];
  float gga[4] = {gg.x, gg.y, gg.z, gg.w};
  float bva[4] = {bv.x, bv.y, bv.z, bv.w};
  float ya[4] = {y.x, y.y, y.z, y.w};
  float o[4];
#pragma unroll
  for (int j = 0; j < 4; ++j) {
    o[j] = ya[j] + (xv[j] - mean) * inv * gga[j] + bva[j];
    f16 hh = (f16)o[j];
    Yh[basep + (tid << 2) + j] = hh;
    Yl[basep + (tid << 2) + j] = (f16)(o[j] - (float)hh);
  }
  *(float4*)&Yout[basep + (tid << 2)] = *(float4*)o;
}

// out = p0 + p1 + bias (final linear reduce)
__global__ __launch_bounds__(256)
void add2_bias(const float* __restrict__ p0, const float* __restrict__ p1,
               const float* __restrict__ b, float* __restrict__ out)
{
  const size_t i = ((size_t)blockIdx.x * 256 + threadIdx.x) * 4;
  const int col = (int)(i & (Ee - 1));
  float4 a = *(const float4*)&p0[i];
  float4 c = *(const float4*)&p1[i];
  float4 bb = *(const float4*)&b[col];
  float4 o;
  o.x = a.x + c.x + bb.x; o.y = a.y + c.y + bb.y;
  o.z = a.z + c.z + bb.z; o.w = a.w + c.w + bb.w;
  *(float4*)&out[i] = o;
}

// fp32 -> (hi,lo) f16 split for BOTH branches in one launch.
// grid = 2 * (ME/1024); lower half writes (oh1,ol1), upper half (oh2,ol2).
__global__ __launch_bounds__(256)
void split_act2(const float* __restrict__ in,
                f16* __restrict__ oh1, f16* __restrict__ ol1,
                f16* __restrict__ oh2, f16* __restrict__ ol2)
{
  const size_t nb = gridDim.x >> 1;
  size_t bid = blockIdx.x;
  f16 *oh, *ol;
  if (bid < nb) { oh = oh1; ol = ol1; }
  else { bid -= nb; oh = oh2; ol = ol2; }
  const size_t i = (bid * 256 + threadIdx.x) * 4;
  float4 v = *(const float4*)&in[i];
  float f[4] = {v.x, v.y, v.z, v.w};
#pragma unroll
  for (int j = 0; j < 4; ++j) {
    f16 h = (f16)f[j];
    oh[i + j] = h;
    ol[i + j] = (f16)(f[j] - (float)h);
  }
}

// fp32 [R][C] -> f16 [C][R] transpose (final linear weight).
__global__ __launch_bounds__(256)
void cvtT_f16(const float* __restrict__ in, f16* __restrict__ outp, int R, int C)
{
  __shared__ float tile[32][33];
  const int c0 = blockIdx.x * 32, r0 = blockIdx.y * 32;
  const int tid = threadIdx.x;
  const int ir = tid >> 3, ic = (tid & 7) * 4;
  float4 v = *(const float4*)&in[(size_t)(r0 + ir) * C + c0 + ic];
  tile[ir][ic] = v.x; tile[ir][ic + 1] = v.y;
  tile[ir][ic + 2] = v.z; tile[ir][ic + 3] = v.w;
  __syncthreads();
  const int oc = tid >> 3, orr = (tid & 7) * 4;
  const size_t ob = (size_t)(c0 + oc) * R + r0 + orr;
#pragma unroll
  for (int j = 0; j < 4; ++j)
    outp[ob + j] = (f16)tile[orr + j][oc];
}

// Fused FF weight transpose: ONE launch converts w1 [Ee][Ff]->o1 [Ff][Ee]
// and w2 [Ff][Ee]->o2 [Ee][Ff]. Flat grid: first (Ff/32)*(Ee/32) blocks = w1.
__global__ __launch_bounds__(256)
void cvtT_ff(const float* __restrict__ w1, const float* __restrict__ w2,
             f16* __restrict__ o1, f16* __restrict__ o2)
{
  __shared__ float tile[32][33];
  constexpr int NT1 = (Ff / 32) * (Ee / 32);   // 4096
  int id = blockIdx.x;
  const float* in; f16* outp; int R, C, tx, ty;
  if (id < NT1) {
    in = w1; outp = o1; R = Ee; C = Ff;
    tx = id & (Ff / 32 - 1); ty = id >> 7;          // Ff/32 = 128
  } else {
    id -= NT1;
    in = w2; outp = o2; R = Ff; C = Ee;
    tx = id & (Ee / 32 - 1); ty = id >> 5;          // Ee/32 = 32
  }
  const int c0 = tx * 32, r0 = ty * 32;
  const int tid = threadIdx.x;
  const int ir = tid >> 3, ic = (tid & 7) * 4;
  float4 v = *(const float4*)&in[(size_t)(r0 + ir) * C + c0 + ic];
  tile[ir][ic] = v.x; tile[ir][ic + 1] = v.y;
  tile[ir][ic + 2] = v.z; tile[ir][ic + 3] = v.w;
  __syncthreads();
  const int oc = tid >> 3, orr = (tid & 7) * 4;
  const size_t ob = (size_t)(c0 + oc) * R + r0 + orr;
#pragma unroll
  for (int j = 0; j < 4; ++j)
    outp[ob + j] = (f16)tile[orr + j][oc];
}

// Fused QKV weight transpose-split (PROVEN r11): z = sec*16 + head.
__global__ __launch_bounds__(256)
void cvtT_qkv(const float* __restrict__ wq, const float* __restrict__ wk,
              const float* __restrict__ wv, f16* __restrict__ out_h,
              f16* __restrict__ out_l)
{
  __shared__ float tile[32][33];
  const int z = blockIdx.z, sec = z >> 4, hh = z & 15;
  const float* in = (sec == 0) ? wq : (sec == 1) ? wk : wv;
  const size_t zi = (size_t)hh * Ee * Dd;
  const size_t zo = ((size_t)sec << 20) + (size_t)hh * Ee * Dd;
  const int c0 = blockIdx.x * 32, r0 = blockIdx.y * 32;
  const int tid = threadIdx.x;
  const int ir = tid >> 3, ic = (tid & 7) * 4;
  float4 v = *(const float4*)&in[zi + (size_t)(r0 + ir) * Dd + c0 + ic];
  tile[ir][ic] = v.x; tile[ir][ic + 1] = v.y;
  tile[ir][ic + 2] = v.z; tile[ir][ic + 3] = v.w;
  __syncthreads();
  const int oc = tid >> 3, orr = (tid & 7) * 4;
  const size_t ob = zo + (size_t)(c0 + oc) * Ee + r0 + orr;
#pragma unroll
  for (int j = 0; j < 4; ++j) {
    float f = tile[orr + j][oc];
    f16 h = (f16)f;
    out_h[ob + j] = h;
    out_l[ob + j] = (f16)(f - (float)h);
  }
}

// ---------------------------------------------------------------------------
extern "C" void kernel_launch(void* const* d_in, const int* in_sizes, int n_in,
                              void* d_out, int out_size, void* d_ws, size_t ws_size,
                              hipStream_t stream)
{
  const float* x     = (const float*)d_in[0];
  const float* mh_wq = (const float*)d_in[1];
  const float* mh_wk = (const float*)d_in[2];
  const float* mh_wv = (const float*)d_in[3];
  const float* mh_g  = (const float*)d_in[4];
  const float* mh_b  = (const float*)d_in[5];
  const float* ff_w1 = (const float*)d_in[6];
  const float* ff_b1 = (const float*)d_in[7];
  const float* ff_w2 = (const float*)d_in[8];
  const float* ff_b2 = (const float*)d_in[9];
  const float* ff_g  = (const float*)d_in[10];
  const float* ff_bb = (const float*)d_in[11];
  const float* lt_w  = (const float*)d_in[12];
  const float* lt_b  = (const float*)d_in[13];
  float* out = (float*)d_out;

  // ===== EXACT r11 buffer layout (proven). 88 MB. =====
  const size_t ME = (size_t)Mm * Ee;   // 2M elements
  char* p = (char*)d_ws;
  auto alloc = [&](size_t bytes) { void* r = (void*)p; p += (bytes + 255) & ~(size_t)255; return r; };
  float* bufA  = (float*)alloc(ME * 4);                // 8 MB
  f16*   bufAh = (f16*)alloc(ME * 2);                  // 4 MB
  f16*   bufAl = (f16*)alloc(ME * 2);                  // 4 MB
  float* bufB  = (float*)alloc(ME * 4);                // 8 MB
  f16*   bufBh = (f16*)alloc(ME * 2);                  // 4 MB
  f16*   bufBl = (f16*)alloc(ME * 2);                  // 4 MB
  f16*   wt_h  = (f16*)alloc((size_t)Ff * Ee * 2);     // 8 MB (w1 / qkv-h / lt)
  f16*   wt_l  = (f16*)alloc((size_t)Ff * Ee * 2);     // 8 MB (w2 / qkv-l)
  float* reg   = (float*)alloc((size_t)10 * 1024 * 1024 * 4);  // 40 MB union
  f16*   qh_   = (f16*)reg;
  f16*   ql_   = qh_ + ME;
  f16*   kh_   = qh_ + 2 * ME;
  f16*   kl_   = qh_ + 3 * ME;
  f16*   vv_   = qh_ + 4 * ME;
  float* ob    = reg + 5 * 1024 * 1024;        // attn out (20..28 MB)
  f16*   hid   = (f16*)reg;                    // ff phase: [M,F] f16 = 16 MB
  float* tmp   = reg + 8 * 1024 * 1024;        // fp32 partial (32..40 MB)

  // mh: byte-identical to r11 (separate attn_ln_res kernel).
  auto mh = [&](int i, const float* srcF, const f16* srcH, const f16* srcL,
                float* dstF, f16* dstH, f16* dstL) {
    const size_t wo = (size_t)i * Hh * Ee * Dd;
    cvtT_qkv<<<dim3(Dd / 32, Ee / 32, 48), 256, 0, stream>>>(
        mh_wq + wo, mh_wk + wo, mh_wv + wo, wt_h, wt_l);
    gemm_qkv<<<dim3(24, Mm / 64), 256, 0, stream>>>(
        srcH, srcL, wt_h, wt_l, qh_, ql_, kh_, kl_, vv_);
    attn_ms<<<dim3(Tt / 64, Bb * Hh), 256, 0, stream>>>(qh_, ql_, kh_, kl_, vv_, ob);
    attn_ln_res<<<dim3(Mm * Hh / 4), 256, 0, stream>>>(
        ob, srcF, mh_g + (size_t)i * Hh * Dd, mh_b + (size_t)i * Hh * Dd, dstF, dstH, dstL);
  };
  // ff: r11 dataflow with fused weight conversion (w1->wt_h, w2->wt_l in one
  // launch; wt_l written strictly before its only reader, FF2).
  auto ff = [&](int i, const float* srcF, const f16* srcH,
                float* dstF, f16* dstH, f16* dstL, float* tmp1) {
    cvtT_ff<<<dim3(2 * (Ff / 32) * (Ee / 32)), 256, 0, stream>>>(
        ff_w1 + (size_t)i * Ee * Ff, ff_w2 + (size_t)i * Ff * Ee, wt_h, wt_l);
    gemm_f16_128<<<dim3(Ff / 128, Mm / 128), 256, 0, stream>>>(
        srcH, wt_h, ff_b1 + (size_t)i * Ff, hid, Ff, Ee);
    gemm_f16_1p<false><<<dim3(Ee / 128, Mm / 64, 2), 256, 0, stream>>>(
        hid, nullptr, wt_l, tmp, tmp1, Ee, Ff);
    ff_ln_res<<<dim3(Mm), 256, 0, stream>>>(
        tmp, tmp1, ff_b2 + (size_t)i * Ee,
        srcF, ff_g + (size_t)i * Ee, ff_bb + (size_t)i * Ee, dstF, dstH, dstL);
  };

  // both branches' x-split in one launch
  split_act2<<<dim3(2 * ME / 1024), 256, 0, stream>>>(x, bufAh, bufAl, bufBh, bufBl);

  // out_one branch: ff(3, mh(4, mh(0, x)))   [bufB fp32 dead -> tmp1]
  mh(0, x, bufAh, bufAl, bufA, bufAh, bufAl);
  mh(4, bufA, bufAh, bufAl, bufA, bufAh, bufAl);
  ff(3, bufA, bufAh, bufA, bufAh, bufAl, bufB);

  // out_two branch: 3 encoder blocks then decoder  [bufA fp32 dead -> tmp1]
  mh(1, x, bufBh, bufBl, bufB, bufBh, bufBl);
  ff(0, bufB, bufBh, bufB, bufBh, bufBl, bufA);
  mh(2, bufB, bufBh, bufBl, bufB, bufBh, bufBl);
  ff(1, bufB, bufBh, bufB, bufBh, bufBl, bufA);
  mh(3, bufB, bufBh, bufBl, bufB, bufBh, bufBl);
  ff(2, bufB, bufBh, bufB, bufBh, bufBl, bufA);
  mh(4, bufB, bufBh, bufBl, bufB, bufBh, bufBl);
  ff(3, bufB, bufBh, bufB, bufBh, bufBl, bufA);

  // final: out = concat(A,B)@lt_w + lt_b, 1-pass f16, split-K=2 into dead bufs
  cvtT_f16<<<dim3(Ee / 32, 2 * Ee / 32), 256, 0, stream>>>(lt_w, wt_h, 2 * Ee, Ee);
  gemm_f16_1p<true><<<dim3(Ee / 128, Mm / 64, 2), 256, 0, stream>>>(
      bufAh, bufBh, wt_h, bufA, bufB, Ee, 2 * Ee);
  add2_bias<<<dim3(ME / 1024), 256, 0, stream>>>(bufA, bufB, lt_b, out);
}

// Round 16
// 998.745 us; speedup vs baseline: 4.6843x; 1.0378x over previous
//
#include <hip/hip_runtime.h>
#include <math.h>

#define Bb 4
#define Tt 512
#define Ee 1024
#define Hh 16
#define Dd 64
#define Ff 4096
#define Mm (Bb*Tt)   // 2048
static constexpr float EPS = 1e-5f;

typedef __attribute__((ext_vector_type(4))) float f32x4;
typedef _Float16 f16;
typedef __attribute__((ext_vector_type(8))) _Float16 f16x8;

// async global->LDS, 16B per lane. LDS dest must be lane-linear.
__device__ __forceinline__ void gload16(const void* g, void* l) {
  __builtin_amdgcn_global_load_lds(
      (const __attribute__((address_space(1))) unsigned int*)g,
      (__attribute__((address_space(3))) unsigned int*)l, 16, 0, 0);
}

// ---------------------------------------------------------------------------
// FF1: 1-pass fp16 GEMM, m97 structure (PROVEN r10-r15). 128x128, BK=32,
// single-buffer 16KB LDS, gload_lds staging. Bias+ReLU, f16 out.
// ---------------------------------------------------------------------------
__global__ __launch_bounds__(256)
void gemm_f16_128(const f16* __restrict__ A, const f16* __restrict__ W,
                  const float* __restrict__ bias,
                  f16* __restrict__ C, int ldc, int K)
{
  __shared__ f16 AS[128][32], BS[128][32];
  const int tid = threadIdx.x;
  const int lane = tid & 63, w = tid >> 6;
  const int wr = w >> 1, wc = w & 1;
  const int lhi = lane >> 4, llo = lane & 15;
  const int n0 = blockIdx.x * 128, m0 = blockIdx.y * 128;
  const int s_row = tid >> 2, s_ko = (tid & 3) * 8;

  f32x4 acc[4][4] = {};

  for (int k0 = 0; k0 < K; k0 += 32) {
#pragma unroll
    for (int i = 0; i < 2; ++i) {
      const int row = s_row + i * 64;
      gload16(&A[(size_t)(m0 + row) * K + k0 + s_ko], &AS[row][s_ko]);
      gload16(&W[(size_t)(n0 + row) * K + k0 + s_ko], &BS[row][s_ko]);
    }
    __syncthreads();
    f16x8 af[4], bf[4];
#pragma unroll
    for (int f = 0; f < 4; ++f) {
      af[f] = *(const f16x8*)&AS[wr * 64 + f * 16 + llo][lhi * 8];
      bf[f] = *(const f16x8*)&BS[wc * 64 + f * 16 + llo][lhi * 8];
    }
#pragma unroll
    for (int m = 0; m < 4; ++m)
#pragma unroll
      for (int n = 0; n < 4; ++n)
        acc[m][n] = __builtin_amdgcn_mfma_f32_16x16x32_f16(af[m], bf[n], acc[m][n], 0, 0, 0);
    __syncthreads();
  }

#pragma unroll
  for (int n = 0; n < 4; ++n) {
    const int col = n0 + wc * 64 + n * 16 + llo;
    const float bv = bias[col];
#pragma unroll
    for (int m = 0; m < 4; ++m) {
      const int rbase = m0 + wr * 64 + m * 16 + lhi * 4;
#pragma unroll
      for (int j = 0; j < 4; ++j) {
        float v = fmaxf(acc[m][n][j] + bv, 0.f);
        C[(size_t)(rbase + j) * ldc + col] = (f16)v;
      }
    }
  }
}

// ---------------------------------------------------------------------------
// 1-pass fp16 GEMM, 64x128 dbuf (PROVEN r10-r15): FF2 (SPLITK) / final.
// ---------------------------------------------------------------------------
template<bool CONCAT>
__global__ __launch_bounds__(256)
void gemm_f16_1p(const f16* __restrict__ A, const f16* __restrict__ A2,
                 const f16* __restrict__ W,
                 float* __restrict__ Cf, float* __restrict__ Cf1,
                 int ldc, int K)
{
  __shared__ f16 AS[2][64][32], BS[2][128][32];
  const int tid = threadIdx.x;
  const int lane = tid & 63, w = tid >> 6;
  const int wr = w >> 1, wc = w & 1;
  const int lhi = lane >> 4, llo = lane & 15;
  const int n0 = blockIdx.x * 128;
  const int m0 = blockIdx.y * 64;
  const int half = K >> 1;
  const int kbeg = blockIdx.z * half;
  const int nt = half / 32;
  if (blockIdx.z == 1) Cf = Cf1;

  const int s_row = tid >> 2, s_ko = (tid & 3) * 8;

  auto stage = [&](int k0, int buf) {
    const int gk = k0 + s_ko;
    const f16* s = A;
    size_t g;
    if (CONCAT) {
      if (gk < Ee) { g = (size_t)(m0 + s_row) * Ee + gk; }
      else { g = (size_t)(m0 + s_row) * Ee + (gk - Ee); s = A2; }
    } else {
      g = (size_t)(m0 + s_row) * K + gk;
    }
    gload16(&s[g], &AS[buf][s_row][s_ko]);
#pragma unroll
    for (int i = 0; i < 2; ++i)
      gload16(&W[(size_t)(n0 + s_row + i * 64) * K + gk], &BS[buf][s_row + i * 64][s_ko]);
  };

  f32x4 acc[2][4] = {};
  stage(kbeg, 0);
  __syncthreads();
  int cur = 0;
  for (int t = 0; t < nt; ++t) {
    if (t + 1 < nt) stage(kbeg + (t + 1) * 32, cur ^ 1);
    f16x8 af[2], bf[4];
#pragma unroll
    for (int m = 0; m < 2; ++m)
      af[m] = *(const f16x8*)&AS[cur][wr * 32 + m * 16 + llo][lhi * 8];
#pragma unroll
    for (int n = 0; n < 4; ++n)
      bf[n] = *(const f16x8*)&BS[cur][wc * 64 + n * 16 + llo][lhi * 8];
#pragma unroll
    for (int m = 0; m < 2; ++m)
#pragma unroll
      for (int n = 0; n < 4; ++n)
        acc[m][n] = __builtin_amdgcn_mfma_f32_16x16x32_f16(af[m], bf[n], acc[m][n], 0, 0, 0);
    __syncthreads();
    cur ^= 1;
  }

#pragma unroll
  for (int n = 0; n < 4; ++n) {
    const int col = n0 + wc * 64 + n * 16 + llo;
#pragma unroll
    for (int m = 0; m < 2; ++m) {
      const int rbase = m0 + wr * 32 + m * 16 + lhi * 4;
#pragma unroll
      for (int j = 0; j < 4; ++j)
        Cf[(size_t)(rbase + j) * ldc + col] = acc[m][n][j];
    }
  }
}

// ---------------------------------------------------------------------------
// QKV projection (PROVEN r11-r15): 64x128 dbuf, grid.x=24, sec = bx>>3.
// Q,K: 3-pass f16 (h,l) -> split (h,l) out. V: 1-pass -> plain f16 out.
// ---------------------------------------------------------------------------
__global__ __launch_bounds__(256)
void gemm_qkv(const f16* __restrict__ Ah_g, const f16* __restrict__ Al_g,
              const f16* __restrict__ Wh, const f16* __restrict__ Wl,
              f16* __restrict__ Qh, f16* __restrict__ Ql,
              f16* __restrict__ Kh, f16* __restrict__ Kl,
              f16* __restrict__ Vv)
{
  __shared__ f16 AhS[2][64][32], AlS[2][64][32];
  __shared__ f16 BhS[2][128][32], BlS[2][128][32];
  const int tid = threadIdx.x;
  const int lane = tid & 63, w = tid >> 6;
  const int wr = w >> 1, wc = w & 1;
  const int lhi = lane >> 4, llo = lane & 15;
  const int sec = blockIdx.x >> 3;
  const bool three = (sec < 2);
  const int n0 = (blockIdx.x & 7) * 128;
  Wh += (size_t)sec << 20;
  Wl += (size_t)sec << 20;
  const int m0 = blockIdx.y * 64;
  const int s_row = tid >> 2, s_ko = (tid & 3) * 8;

  auto stage = [&](int k0, int buf) {
    const size_t g = (size_t)(m0 + s_row) * Ee + k0 + s_ko;
    gload16(&Ah_g[g], &AhS[buf][s_row][s_ko]);
    if (three) gload16(&Al_g[g], &AlS[buf][s_row][s_ko]);
#pragma unroll
    for (int i = 0; i < 2; ++i) {
      size_t gb = (size_t)(n0 + s_row + i * 64) * Ee + k0 + s_ko;
      gload16(&Wh[gb], &BhS[buf][s_row + i * 64][s_ko]);
      if (three) gload16(&Wl[gb], &BlS[buf][s_row + i * 64][s_ko]);
    }
  };

  f32x4 acc[2][4] = {};
  stage(0, 0);
  __syncthreads();
  int cur = 0;
  for (int t = 0; t < Ee / 32; ++t) {
    if (t + 1 < Ee / 32) stage((t + 1) * 32, cur ^ 1);
    f16x8 ah[2], bh[4];
#pragma unroll
    for (int m = 0; m < 2; ++m)
      ah[m] = *(const f16x8*)&AhS[cur][wr * 32 + m * 16 + llo][lhi * 8];
#pragma unroll
    for (int n = 0; n < 4; ++n)
      bh[n] = *(const f16x8*)&BhS[cur][wc * 64 + n * 16 + llo][lhi * 8];
    if (three) {
      f16x8 al[2], bl[4];
#pragma unroll
      for (int m = 0; m < 2; ++m)
        al[m] = *(const f16x8*)&AlS[cur][wr * 32 + m * 16 + llo][lhi * 8];
#pragma unroll
      for (int n = 0; n < 4; ++n)
        bl[n] = *(const f16x8*)&BlS[cur][wc * 64 + n * 16 + llo][lhi * 8];
#pragma unroll
      for (int m = 0; m < 2; ++m)
#pragma unroll
        for (int n = 0; n < 4; ++n) {
          acc[m][n] = __builtin_amdgcn_mfma_f32_16x16x32_f16(ah[m], bh[n], acc[m][n], 0, 0, 0);
          acc[m][n] = __builtin_amdgcn_mfma_f32_16x16x32_f16(ah[m], bl[n], acc[m][n], 0, 0, 0);
          acc[m][n] = __builtin_amdgcn_mfma_f32_16x16x32_f16(al[m], bh[n], acc[m][n], 0, 0, 0);
        }
    } else {
#pragma unroll
      for (int m = 0; m < 2; ++m)
#pragma unroll
        for (int n = 0; n < 4; ++n)
          acc[m][n] = __builtin_amdgcn_mfma_f32_16x16x32_f16(ah[m], bh[n], acc[m][n], 0, 0, 0);
    }
    __syncthreads();
    cur ^= 1;
  }

#pragma unroll
  for (int n = 0; n < 4; ++n) {
    const int col = n0 + wc * 64 + n * 16 + llo;
#pragma unroll
    for (int m = 0; m < 2; ++m) {
      const int rbase = m0 + wr * 32 + m * 16 + lhi * 4;
#pragma unroll
      for (int j = 0; j < 4; ++j) {
        const float v = acc[m][n][j];
        const size_t idx = (size_t)(rbase + j) * Ee + col;
        if (sec == 0) {
          f16 h = (f16)v;
          Qh[idx] = h;
          Ql[idx] = (f16)(v - (float)h);
        } else if (sec == 1) {
          f16 h = (f16)v;
          Kh[idx] = h;
          Kl[idx] = (f16)(v - (float)h);
        } else {
          Vv[idx] = (f16)v;
        }
      }
    }
  }
}

// ---------------------------------------------------------------------------
// Split-f16 MFMA flash attention (PROVEN r11-r15, byte-identical), causal.
// Q,K pre-split f16 (h,l); V plain f16. QK^T 3-pass; PV 1-pass.
// ---------------------------------------------------------------------------
__global__ __launch_bounds__(256)
void attn_ms(const f16* __restrict__ Qh_g, const f16* __restrict__ Ql_g,
             const f16* __restrict__ Kh_g, const f16* __restrict__ Kl_g,
             const f16* __restrict__ Vv_g, float* __restrict__ O)
{
  __shared__ f16 Ksh[64][72], Ksl[64][72];   // [s][d]
  __shared__ f16 Vs[64][72];                 // [d][s] (transposed)
  __shared__ f16 Pw[4][16][72];              // per-wave P [q_local][s]
  const int tid = threadIdx.x;
  const int lane = tid & 63, w = tid >> 6;
  const int lhi = lane >> 4, llo = lane & 15;
  const int q0 = blockIdx.x * 64;
  const int bh = blockIdx.y;
  const size_t base = (size_t)(bh >> 4) * Tt * Ee + (size_t)(bh & 15) * Dd;

  f16x8 qfh[2], qfl[2];
#pragma unroll
  for (int ks = 0; ks < 2; ++ks) {
    const size_t qoff = base + (size_t)(q0 + w * 16 + llo) * Ee + ks * 32 + lhi * 8;
    qfh[ks] = *(const f16x8*)&Qh_g[qoff];
    qfl[ks] = *(const f16x8*)&Ql_g[qoff];
  }

  f32x4 oacc[4] = {};
  float m_run[4], l_run[4];
#pragma unroll
  for (int j = 0; j < 4; ++j) { m_run[j] = -INFINITY; l_run[j] = 0.f; }

  for (int s0 = 0; s0 <= q0; s0 += 64) {
#pragma unroll
    for (int pass = 0; pass < 2; ++pass) {
      int c = tid + 256 * pass;
      int row = c >> 3, d0 = (c & 7) * 8;
      const size_t g = base + (size_t)(s0 + row) * Ee + d0;
      f16x8 kh = *(const f16x8*)&Kh_g[g];
      f16x8 kl = *(const f16x8*)&Kl_g[g];
      f16x8 vf = *(const f16x8*)&Vv_g[g];
      *(f16x8*)&Ksh[row][d0] = kh;
      *(f16x8*)&Ksl[row][d0] = kl;
#pragma unroll
      for (int j = 0; j < 8; ++j) Vs[d0 + j][row] = vf[j];
    }
    __syncthreads();

    f32x4 sacc[4] = {};
#pragma unroll
    for (int ks = 0; ks < 2; ++ks)
#pragma unroll
      for (int n = 0; n < 4; ++n) {
        f16x8 kfh = *(const f16x8*)&Ksh[n * 16 + llo][ks * 32 + lhi * 8];
        f16x8 kfl = *(const f16x8*)&Ksl[n * 16 + llo][ks * 32 + lhi * 8];
        sacc[n] = __builtin_amdgcn_mfma_f32_16x16x32_f16(qfh[ks], kfh, sacc[n], 0, 0, 0);
        sacc[n] = __builtin_amdgcn_mfma_f32_16x16x32_f16(qfh[ks], kfl, sacc[n], 0, 0, 0);
        sacc[n] = __builtin_amdgcn_mfma_f32_16x16x32_f16(qfl[ks], kfh, sacc[n], 0, 0, 0);
      }

    if (s0 == q0) {
#pragma unroll
      for (int n = 0; n < 4; ++n)
#pragma unroll
        for (int j = 0; j < 4; ++j)
          if (n * 16 + llo > w * 16 + lhi * 4 + j) sacc[n][j] = -INFINITY;
    }

    float scj[4];
#pragma unroll
    for (int j = 0; j < 4; ++j) {
      float mt = fmaxf(fmaxf(sacc[0][j], sacc[1][j]), fmaxf(sacc[2][j], sacc[3][j]));
#pragma unroll
      for (int off = 1; off < 16; off <<= 1) mt = fmaxf(mt, __shfl_xor(mt, off));
      float mn = fmaxf(m_run[j], mt);
      scj[j] = __expf(m_run[j] - mn);
      m_run[j] = mn;
      float rs = 0.f;
#pragma unroll
      for (int n = 0; n < 4; ++n) {
        float pp = __expf(sacc[n][j] - mn);
        sacc[n][j] = pp;
        rs += pp;
      }
#pragma unroll
      for (int off = 1; off < 16; off <<= 1) rs += __shfl_xor(rs, off);
      l_run[j] = l_run[j] * scj[j] + rs;
    }

#pragma unroll
    for (int n = 0; n < 4; ++n)
#pragma unroll
      for (int j = 0; j < 4; ++j)
        Pw[w][lhi * 4 + j][n * 16 + llo] = (f16)sacc[n][j];
#pragma unroll
    for (int df = 0; df < 4; ++df)
#pragma unroll
      for (int j = 0; j < 4; ++j)
        oacc[df][j] *= scj[j];

#pragma unroll
    for (int ks = 0; ks < 2; ++ks) {
      f16x8 pf = *(const f16x8*)&Pw[w][llo][ks * 32 + lhi * 8];
#pragma unroll
      for (int df = 0; df < 4; ++df) {
        f16x8 vfr = *(const f16x8*)&Vs[df * 16 + llo][ks * 32 + lhi * 8];
        oacc[df] = __builtin_amdgcn_mfma_f32_16x16x32_f16(pf, vfr, oacc[df], 0, 0, 0);
      }
    }
    __syncthreads();
  }

#pragma unroll
  for (int j = 0; j < 4; ++j) {
    float inv = 1.f / l_run[j];
#pragma unroll
    for (int df = 0; df < 4; ++df)
      O[base + (size_t)(q0 + w * 16 + lhi * 4 + j) * Ee + df * 16 + llo] =
          oacc[df][j] * inv;
  }
}

// ---------------------------------------------------------------------------
// Per-head LN over D=64 + residual (PROVEN r11-r15); fp32 + (h,l) f16.
// ---------------------------------------------------------------------------
__global__ __launch_bounds__(256)
void attn_ln_res(const float* __restrict__ O, const float* Yin,
                 const float* __restrict__ g, const float* __restrict__ bta,
                 float* Yout, f16* __restrict__ Yh, f16* __restrict__ Yl)
{
  const int tid = threadIdx.x;
  const int w = (blockIdx.x << 2) + (tid >> 6);
  const int lane = tid & 63;
  const int m = w >> 4;
  const int h = w & 15;
  const size_t idx = (size_t)m * Ee + h * Dd + lane;
  float x = O[idx];
  float s = x, s2 = x * x;
#pragma unroll
  for (int off = 1; off < 64; off <<= 1) {
    s  += __shfl_xor(s, off);
    s2 += __shfl_xor(s2, off);
  }
  float mean = s * (1.f / 64.f);
  float var  = s2 * (1.f / 64.f) - mean * mean;
  float inv  = rsqrtf(var + EPS);
  float r = Yin[idx] + (x - mean) * inv * g[h * Dd + lane] + bta[h * Dd + lane];
  Yout[idx] = r;
  f16 hh = (f16)r;
  Yh[idx] = hh;
  Yl[idx] = (f16)(r - (float)hh);
}

// ---------------------------------------------------------------------------
// Row LN over E=1024 + residual (PROVEN r11-r15). Input = T0 + T1 + bias.
// ---------------------------------------------------------------------------
__global__ __launch_bounds__(256)
void ff_ln_res(const float* __restrict__ T0, const float* __restrict__ T1,
               const float* __restrict__ b2,
               const float* Yin, const float* __restrict__ g,
               const float* __restrict__ bb,
               float* Yout, f16* __restrict__ Yh, f16* __restrict__ Yl)
{
  __shared__ float red[8];
  const int m = blockIdx.x;
  const int tid = threadIdx.x;
  const size_t basep = (size_t)m * Ee;
  float4 xa = *(const float4*)&T0[basep + (tid << 2)];
  float4 xb = *(const float4*)&T1[basep + (tid << 2)];
  float4 bv2 = *(const float4*)&b2[tid << 2];
  float xv[4] = {xa.x + xb.x + bv2.x, xa.y + xb.y + bv2.y,
                 xa.z + xb.z + bv2.z, xa.w + xb.w + bv2.w};
  float s  = xv[0] + xv[1] + xv[2] + xv[3];
  float s2 = xv[0]*xv[0] + xv[1]*xv[1] + xv[2]*xv[2] + xv[3]*xv[3];
#pragma unroll
  for (int off = 1; off < 64; off <<= 1) {
    s  += __shfl_xor(s, off);
    s2 += __shfl_xor(s2, off);
  }
  const int wid = tid >> 6;
  if ((tid & 63) == 0) { red[wid] = s; red[4 + wid] = s2; }
  __syncthreads();
  s  = red[0] + red[1] + red[2] + red[3];
  s2 = red[4] + red[5] + red[6] + red[7];
  float mean = s * (1.f / Ee);
  float var  = s2 * (1.f / Ee) - mean * mean;
  float inv  = rsqrtf(var + EPS);
  float4 y  = *(const float4*)&Yin[basep + (tid << 2)];
  float4 gg = *(const float4*)&g[tid << 2];
  float4 bv = *(const float4*)&bb[tid << 2];
  float gga[4] = {gg.x, gg.y, gg.z, gg.w};
  float bva[4] = {bv.x, bv.y, bv.z, bv.w};
  float ya[4] = {y.x, y.y, y.z, y.w};
  float o[4];
#pragma unroll
  for (int j = 0; j < 4; ++j) {
    o[j] = ya[j] + (xv[j] - mean) * inv * gga[j] + bva[j];
    f16 hh = (f16)o[j];
    Yh[basep + (tid << 2) + j] = hh;
    Yl[basep + (tid << 2) + j] = (f16)(o[j] - (float)hh);
  }
  *(float4*)&Yout[basep + (tid << 2)] = *(float4*)o;
}

// out = p0 + p1 + bias (final linear reduce)
__global__ __launch_bounds__(256)
void add2_bias(const float* __restrict__ p0, const float* __restrict__ p1,
               const float* __restrict__ b, float* __restrict__ out)
{
  const size_t i = ((size_t)blockIdx.x * 256 + threadIdx.x) * 4;
  const int col = (int)(i & (Ee - 1));
  float4 a = *(const float4*)&p0[i];
  float4 c = *(const float4*)&p1[i];
  float4 bb = *(const float4*)&b[col];
  float4 o;
  o.x = a.x + c.x + bb.x; o.y = a.y + c.y + bb.y;
  o.z = a.z + c.z + bb.z; o.w = a.w + c.w + bb.w;
  *(float4*)&out[i] = o;
}

// fp32 -> (hi,lo) f16 split for BOTH branches in one launch (PROVEN r15).
__global__ __launch_bounds__(256)
void split_act2(const float* __restrict__ in,
                f16* __restrict__ oh1, f16* __restrict__ ol1,
                f16* __restrict__ oh2, f16* __restrict__ ol2)
{
  const size_t nb = gridDim.x >> 1;
  size_t bid = blockIdx.x;
  f16 *oh, *ol;
  if (bid < nb) { oh = oh1; ol = ol1; }
  else { bid -= nb; oh = oh2; ol = ol2; }
  const size_t i = (bid * 256 + threadIdx.x) * 4;
  float4 v = *(const float4*)&in[i];
  float f[4] = {v.x, v.y, v.z, v.w};
#pragma unroll
  for (int j = 0; j < 4; ++j) {
    f16 h = (f16)f[j];
    oh[i + j] = h;
    ol[i + j] = (f16)(f[j] - (float)h);
  }
}

// ---------------------------------------------------------------------------
// FAST transpose-convert: fp32 [R][C] -> f16 [C][R]. 64(row)x32(col) tile,
// fp32 LDS [64][33] (2-way bank alias = free). Coalesced f16x8 (16B) stores:
// thread reads an 8-elem tile column, 8 threads/out-row = 128B contiguous.
// Flat 1-D grid: nx = C/32 tiles along C, id = ty*nx + tx.
// ---------------------------------------------------------------------------
__device__ __forceinline__ void cvtT_tile(const float* in, f16* outp,
                                          int R, int C, int tx, int ty, int tid)
{
  __shared__ float tile[64][33];
  const int c0 = tx * 32, r0 = ty * 64;
  const int r = tid >> 2, c8 = (tid & 3) * 8;
  const float* src = &in[(size_t)(r0 + r) * C + c0 + c8];
  float4 a = *(const float4*)src;
  float4 b = *(const float4*)(src + 4);
  tile[r][c8 + 0] = a.x; tile[r][c8 + 1] = a.y;
  tile[r][c8 + 2] = a.z; tile[r][c8 + 3] = a.w;
  tile[r][c8 + 4] = b.x; tile[r][c8 + 5] = b.y;
  tile[r][c8 + 6] = b.z; tile[r][c8 + 7] = b.w;
  __syncthreads();
  const int oc = tid >> 3, rr = (tid & 7) * 8;
  f16x8 o;
#pragma unroll
  for (int j = 0; j < 8; ++j) o[j] = (f16)tile[rr + j][oc];
  *(f16x8*)&outp[(size_t)(c0 + oc) * R + r0 + rr] = o;
}

__global__ __launch_bounds__(256)
void cvtT_f16(const float* __restrict__ in, f16* __restrict__ outp, int R, int C)
{
  const int nx = C >> 5;
  cvtT_tile(in, outp, R, C, blockIdx.x % nx, blockIdx.x / nx, threadIdx.x);
}

// Fused FF weight transpose (fast): w1 [Ee][Ff]->o1 [Ff][Ee] and
// w2 [Ff][Ee]->o2 [Ee][Ff] in one flat-grid launch.
__global__ __launch_bounds__(256)
void cvtT_ff(const float* __restrict__ w1, const float* __restrict__ w2,
             f16* __restrict__ o1, f16* __restrict__ o2)
{
  constexpr int NT1 = (Ff / 32) * (Ee / 64);   // 128*16 = 2048
  int id = blockIdx.x;
  const float* in; f16* outp; int R, C;
  if (id < NT1) { in = w1; outp = o1; R = Ee; C = Ff; }
  else { id -= NT1; in = w2; outp = o2; R = Ff; C = Ee; }
  const int nx = C >> 5;
  cvtT_tile(in, outp, R, C, id % nx, id / nx, threadIdx.x);
}

// Fast fused QKV weight transpose-split: grid (Dd/32, Ee/64, 48);
// z = sec*16 + head. [Ee][Dd] fp32 -> [Dd][Ee] f16 h + l at slab sec<<20.
__global__ __launch_bounds__(256)
void cvtT_qkv(const float* __restrict__ wq, const float* __restrict__ wk,
              const float* __restrict__ wv, f16* __restrict__ out_h,
              f16* __restrict__ out_l)
{
  __shared__ float tile[64][33];
  const int z = blockIdx.z, sec = z >> 4, hh = z & 15;
  const float* in = (sec == 0) ? wq : (sec == 1) ? wk : wv;
  const size_t zi = (size_t)hh * Ee * Dd;
  const size_t zo = ((size_t)sec << 20) + (size_t)hh * Ee * Dd;
  const int c0 = blockIdx.x * 32, r0 = blockIdx.y * 64;
  const int tid = threadIdx.x;
  const int r = tid >> 2, c8 = (tid & 3) * 8;
  const float* src = &in[zi + (size_t)(r0 + r) * Dd + c0 + c8];
  float4 a = *(const float4*)src;
  float4 b = *(const float4*)(src + 4);
  tile[r][c8 + 0] = a.x; tile[r][c8 + 1] = a.y;
  tile[r][c8 + 2] = a.z; tile[r][c8 + 3] = a.w;
  tile[r][c8 + 4] = b.x; tile[r][c8 + 5] = b.y;
  tile[r][c8 + 6] = b.z; tile[r][c8 + 7] = b.w;
  __syncthreads();
  const int oc = tid >> 3, rr = (tid & 7) * 8;
  f16x8 oh, ol;
#pragma unroll
  for (int j = 0; j < 8; ++j) {
    float f = tile[rr + j][oc];
    f16 h = (f16)f;
    oh[j] = h;
    ol[j] = (f16)(f - (float)h);
  }
  const size_t ob = zo + (size_t)(c0 + oc) * Ee + r0 + rr;
  *(f16x8*)&out_h[ob] = oh;
  *(f16x8*)&out_l[ob] = ol;
}

// ---------------------------------------------------------------------------
extern "C" void kernel_launch(void* const* d_in, const int* in_sizes, int n_in,
                              void* d_out, int out_size, void* d_ws, size_t ws_size,
                              hipStream_t stream)
{
  const float* x     = (const float*)d_in[0];
  const float* mh_wq = (const float*)d_in[1];
  const float* mh_wk = (const float*)d_in[2];
  const float* mh_wv = (const float*)d_in[3];
  const float* mh_g  = (const float*)d_in[4];
  const float* mh_b  = (const float*)d_in[5];
  const float* ff_w1 = (const float*)d_in[6];
  const float* ff_b1 = (const float*)d_in[7];
  const float* ff_w2 = (const float*)d_in[8];
  const float* ff_b2 = (const float*)d_in[9];
  const float* ff_g  = (const float*)d_in[10];
  const float* ff_bb = (const float*)d_in[11];
  const float* lt_w  = (const float*)d_in[12];
  const float* lt_b  = (const float*)d_in[13];
  float* out = (float*)d_out;

  // ===== EXACT r11/r15 buffer layout (proven). 88 MB. =====
  const size_t ME = (size_t)Mm * Ee;   // 2M elements
  char* p = (char*)d_ws;
  auto alloc = [&](size_t bytes) { void* r = (void*)p; p += (bytes + 255) & ~(size_t)255; return r; };
  float* bufA  = (float*)alloc(ME * 4);                // 8 MB
  f16*   bufAh = (f16*)alloc(ME * 2);                  // 4 MB
  f16*   bufAl = (f16*)alloc(ME * 2);                  // 4 MB
  float* bufB  = (float*)alloc(ME * 4);                // 8 MB
  f16*   bufBh = (f16*)alloc(ME * 2);                  // 4 MB
  f16*   bufBl = (f16*)alloc(ME * 2);                  // 4 MB
  f16*   wt_h  = (f16*)alloc((size_t)Ff * Ee * 2);     // 8 MB (w1 / qkv-h / lt)
  f16*   wt_l  = (f16*)alloc((size_t)Ff * Ee * 2);     // 8 MB (w2 / qkv-l)
  float* reg   = (float*)alloc((size_t)10 * 1024 * 1024 * 4);  // 40 MB union
  f16*   qh_   = (f16*)reg;
  f16*   ql_   = qh_ + ME;
  f16*   kh_   = qh_ + 2 * ME;
  f16*   kl_   = qh_ + 3 * ME;
  f16*   vv_   = qh_ + 4 * ME;
  float* ob    = reg + 5 * 1024 * 1024;        // attn out (20..28 MB)
  f16*   hid   = (f16*)reg;                    // ff phase: [M,F] f16 = 16 MB
  float* tmp   = reg + 8 * 1024 * 1024;        // fp32 partial (32..40 MB)

  // mh: byte-identical dataflow to r11/r15 (separate attn_ln_res kernel).
  auto mh = [&](int i, const float* srcF, const f16* srcH, const f16* srcL,
                float* dstF, f16* dstH, f16* dstL) {
    const size_t wo = (size_t)i * Hh * Ee * Dd;
    cvtT_qkv<<<dim3(Dd / 32, Ee / 64, 48), 256, 0, stream>>>(
        mh_wq + wo, mh_wk + wo, mh_wv + wo, wt_h, wt_l);
    gemm_qkv<<<dim3(24, Mm / 64), 256, 0, stream>>>(
        srcH, srcL, wt_h, wt_l, qh_, ql_, kh_, kl_, vv_);
    attn_ms<<<dim3(Tt / 64, Bb * Hh), 256, 0, stream>>>(qh_, ql_, kh_, kl_, vv_, ob);
    attn_ln_res<<<dim3(Mm * Hh / 4), 256, 0, stream>>>(
        ob, srcF, mh_g + (size_t)i * Hh * Dd, mh_b + (size_t)i * Hh * Dd, dstF, dstH, dstL);
  };
  // ff: r15 dataflow (fused w1/w2 conversion, now fast-coalesced).
  auto ff = [&](int i, const float* srcF, const f16* srcH,
                float* dstF, f16* dstH, f16* dstL, float* tmp1) {
    cvtT_ff<<<dim3((Ff / 32) * (Ee / 64) + (Ee / 32) * (Ff / 64)), 256, 0, stream>>>(
        ff_w1 + (size_t)i * Ee * Ff, ff_w2 + (size_t)i * Ff * Ee, wt_h, wt_l);
    gemm_f16_128<<<dim3(Ff / 128, Mm / 128), 256, 0, stream>>>(
        srcH, wt_h, ff_b1 + (size_t)i * Ff, hid, Ff, Ee);
    gemm_f16_1p<false><<<dim3(Ee / 128, Mm / 64, 2), 256, 0, stream>>>(
        hid, nullptr, wt_l, tmp, tmp1, Ee, Ff);
    ff_ln_res<<<dim3(Mm), 256, 0, stream>>>(
        tmp, tmp1, ff_b2 + (size_t)i * Ee,
        srcF, ff_g + (size_t)i * Ee, ff_bb + (size_t)i * Ee, dstF, dstH, dstL);
  };

  // both branches' x-split in one launch
  split_act2<<<dim3(2 * ME / 1024), 256, 0, stream>>>(x, bufAh, bufAl, bufBh, bufBl);

  // out_one branch: ff(3, mh(4, mh(0, x)))   [bufB fp32 dead -> tmp1]
  mh(0, x, bufAh, bufAl, bufA, bufAh, bufAl);
  mh(4, bufA, bufAh, bufAl, bufA, bufAh, bufAl);
  ff(3, bufA, bufAh, bufA, bufAh, bufAl, bufB);

  // out_two branch: 3 encoder blocks then decoder  [bufA fp32 dead -> tmp1]
  mh(1, x, bufBh, bufBl, bufB, bufBh, bufBl);
  ff(0, bufB, bufBh, bufB, bufBh, bufBl, bufA);
  mh(2, bufB, bufBh, bufBl, bufB, bufBh, bufBl);
  ff(1, bufB, bufBh, bufB, bufBh, bufBl, bufA);
  mh(3, bufB, bufBh, bufBl, bufB, bufBh, bufBl);
  ff(2, bufB, bufBh, bufB, bufBh, bufBl, bufA);
  mh(4, bufB, bufBh, bufBl, bufB, bufBh, bufBl);
  ff(3, bufB, bufBh, bufB, bufBh, bufBl, bufA);

  // final: out = concat(A,B)@lt_w + lt_b, 1-pass f16, split-K=2 into dead bufs
  cvtT_f16<<<dim3((Ee / 32) * (2 * Ee / 64)), 256, 0, stream>>>(lt_w, wt_h, 2 * Ee, Ee);
  gemm_f16_1p<true><<<dim3(Ee / 128, Mm / 64, 2), 256, 0, stream>>>(
      bufAh, bufBh, wt_h, bufA, bufB, Ee, 2 * Ee);
  add2_bias<<<dim3(ME / 1024), 256, 0, stream>>>(bufA, bufB, lt_b, out);
}